// Round 1
// baseline (3405.479 us; speedup 1.0000x reference)
//
#include <hip/hip_runtime.h>
#include <math.h>

constexpr int B_ = 4, S_ = 512, D_ = 768, H_ = 12, M_ = 4, DFF_ = 3072, HD_ = 64;
constexpr float EPS_ = 1e-6f;
constexpr float SCALE_ = 0.125f;  // HD^-0.5
constexpr int BS_ = B_ * S_;                    // 2048 rows
constexpr long long BSD_ = (long long)BS_ * D_; // 1,572,864
constexpr long long BS3D_ = (long long)BS_ * 3 * D_;
constexpr long long ATT_ = (long long)B_ * H_ * S_ * S_;
constexpr long long BSF_ = (long long)BS_ * DFF_;

// ---------------- block reductions (256 threads = 4 waves) ----------------
__device__ __forceinline__ float block_sum(float v) {
    __shared__ float red[4];
    int tid = threadIdx.x;
#pragma unroll
    for (int off = 32; off > 0; off >>= 1) v += __shfl_down(v, off, 64);
    __syncthreads();
    if ((tid & 63) == 0) red[tid >> 6] = v;
    __syncthreads();
    return red[0] + red[1] + red[2] + red[3];
}

__device__ __forceinline__ float block_max(float v) {
    __shared__ float red[4];
    int tid = threadIdx.x;
#pragma unroll
    for (int off = 32; off > 0; off >>= 1) v = fmaxf(v, __shfl_down(v, off, 64));
    __syncthreads();
    if ((tid & 63) == 0) red[tid >> 6] = v;
    __syncthreads();
    return fmaxf(fmaxf(red[0], red[1]), fmaxf(red[2], red[3]));
}

// ---------------- LayerNorm forward: x -> xhat, h, rstd ----------------
__global__ __launch_bounds__(256) void ln_fwd(const float* __restrict__ x,
                                              const float* __restrict__ g,
                                              const float* __restrict__ bta,
                                              float* __restrict__ xhat,
                                              float* __restrict__ h,
                                              float* __restrict__ rstd) {
    int row = blockIdx.x;
    const float* xr = x + (size_t)row * D_;
    int tid = threadIdx.x;
    float v[3];
    float s = 0.f;
#pragma unroll
    for (int i = 0; i < 3; i++) { v[i] = xr[tid + i * 256]; s += v[i]; }
    s = block_sum(s);
    float mu = s * (1.0f / D_);
    float vs = 0.f;
#pragma unroll
    for (int i = 0; i < 3; i++) { float c = v[i] - mu; vs += c * c; }
    vs = block_sum(vs);
    float rs = rsqrtf(vs * (1.0f / D_) + EPS_);
#pragma unroll
    for (int i = 0; i < 3; i++) {
        int c = tid + i * 256;
        float xh = (v[i] - mu) * rs;
        xhat[(size_t)row * D_ + c] = xh;
        h[(size_t)row * D_ + c] = xh * g[c] + bta[c];
    }
    if (tid == 0) rstd[row] = rs;
}

// ---------------- LayerNorm JVP: t -> dh = g*rstd*(t - mean(t) - xhat*mean(xhat*t)) ----
__global__ __launch_bounds__(256) void ln_jvp(const float* __restrict__ t,
                                              const float* __restrict__ xhat,
                                              const float* __restrict__ rstd,
                                              const float* __restrict__ g,
                                              float* __restrict__ dh) {
    int row = blockIdx.x;
    size_t base = (size_t)row * D_;
    int tid = threadIdx.x;
    float tv[3], xh[3];
    float s1 = 0.f, s2 = 0.f;
#pragma unroll
    for (int i = 0; i < 3; i++) {
        int c = tid + i * 256;
        tv[i] = t[base + c];
        xh[i] = xhat[base + c];
        s1 += tv[i];
        s2 += tv[i] * xh[i];
    }
    s1 = block_sum(s1);
    s2 = block_sum(s2);
    float mt = s1 * (1.0f / D_);
    float mx = s2 * (1.0f / D_);
    float rs = rstd[row];
#pragma unroll
    for (int i = 0; i < 3; i++) {
        int c = tid + i * 256;
        dh[base + c] = g[c] * rs * (tv[i] - mt - xh[i] * mx);
    }
}

// ---------------- generic tiled GEMM: C[M,N] = A[M,K]@B[K,N] + bias + res, epilogues ----
// EPI 0: C = acc + bias? + res?
// EPI 1: u = acc + bias; C = gelu(u); C2 = gelu'(u)
// EPI 2: C = acc * mul   (elementwise gate, e.g. da = (dh2@W1) * gelu'(u))
template <int EPI>
__global__ __launch_bounds__(256) void gemm64(const float* __restrict__ A,
                                              const float* __restrict__ Bm,
                                              const float* __restrict__ bias,
                                              const float* __restrict__ res,
                                              const float* __restrict__ mul,
                                              float* __restrict__ C,
                                              float* __restrict__ C2,
                                              int Mr, int Nc, int Kd) {
    __shared__ float As[16][68];  // [k][m] (transposed for b128 reads)
    __shared__ float Bs[16][68];  // [k][n]
    int tid = threadIdx.x;
    int tx = tid & 15, ty = tid >> 4;
    int row0 = blockIdx.y * 64, col0 = blockIdx.x * 64;
    float acc[4][4] = {};
    int ar = tid >> 2, ac4 = (tid & 3) * 4;
    int br = tid >> 4, bc4 = (tid & 15) * 4;
    const float* ap = A + (size_t)(row0 + ar) * Kd + ac4;
    const float* bp = Bm + (size_t)br * Nc + col0 + bc4;
    for (int k0 = 0; k0 < Kd; k0 += 16) {
        float4 av = *(const float4*)(ap + k0);
        float4 bv = *(const float4*)(bp + (size_t)k0 * Nc);
        As[ac4 + 0][ar] = av.x;
        As[ac4 + 1][ar] = av.y;
        As[ac4 + 2][ar] = av.z;
        As[ac4 + 3][ar] = av.w;
        *(float4*)&Bs[br][bc4] = bv;
        __syncthreads();
#pragma unroll
        for (int kk = 0; kk < 16; kk++) {
            float4 a4 = *(const float4*)&As[kk][ty * 4];
            float4 b4 = *(const float4*)&Bs[kk][tx * 4];
            float aa[4] = {a4.x, a4.y, a4.z, a4.w};
            float bb[4] = {b4.x, b4.y, b4.z, b4.w};
#pragma unroll
            for (int i = 0; i < 4; i++)
#pragma unroll
                for (int j = 0; j < 4; j++) acc[i][j] += aa[i] * bb[j];
        }
        __syncthreads();
    }
#pragma unroll
    for (int i = 0; i < 4; i++) {
        int r = row0 + ty * 4 + i;
        size_t rowoff = (size_t)r * Nc + col0 + tx * 4;
#pragma unroll
        for (int j = 0; j < 4; j++) {
            float v = acc[i][j];
            int c = col0 + tx * 4 + j;
            if (EPI == 0) {
                if (bias) v += bias[c];
                if (res) v += res[rowoff + j];
                C[rowoff + j] = v;
            } else if (EPI == 1) {
                v += bias[c];
                float cdf = 0.5f * (1.0f + erff(v * 0.70710678118654752f));
                C[rowoff + j] = v * cdf;
                C2[rowoff + j] = cdf + v * 0.39894228040143267f * expf(-0.5f * v * v);
            } else {
                C[rowoff + j] = v * mul[rowoff + j];
            }
        }
    }
}

// ---------------- attention scores: sc[bh,q,k] = scale * (q.k)  (TAN: dq.k + q.dk) ----
template <bool TAN>
__global__ __launch_bounds__(256) void attn_qk(const float* __restrict__ qkv,
                                               const float* __restrict__ dqkv,
                                               float* __restrict__ sc) {
    int bh = blockIdx.z;
    int b = bh / H_, hh = bh - b * H_;
    const size_t qoff = (size_t)b * S_ * 3 * D_ + hh * HD_;
    const float* Q = qkv + qoff;
    const float* Kp = qkv + qoff + D_;
    int q0 = blockIdx.y * 64, k0 = blockIdx.x * 64;
    __shared__ float sm[TAN ? 4 : 2][64][68];  // [0]=Qs[d][q] [1]=Ks[d][k] [2]=dQs [3]=dKs
    int tid = threadIdx.x;
    int tx = tid & 15, ty = tid >> 4;
    int lr = tid >> 4;
    int lc4 = (tid & 15) * 4;
#pragma unroll
    for (int i = 0; i < 4; i++) {
        int r = lr + i * 16;
        float4 qv = *(const float4*)&Q[(size_t)(q0 + r) * 3 * D_ + lc4];
        sm[0][lc4 + 0][r] = qv.x; sm[0][lc4 + 1][r] = qv.y;
        sm[0][lc4 + 2][r] = qv.z; sm[0][lc4 + 3][r] = qv.w;
        float4 kv = *(const float4*)&Kp[(size_t)(k0 + r) * 3 * D_ + lc4];
        sm[1][lc4 + 0][r] = kv.x; sm[1][lc4 + 1][r] = kv.y;
        sm[1][lc4 + 2][r] = kv.z; sm[1][lc4 + 3][r] = kv.w;
        if (TAN) {
            float4 dq = *(const float4*)&dqkv[qoff + (size_t)(q0 + r) * 3 * D_ + lc4];
            sm[2][lc4 + 0][r] = dq.x; sm[2][lc4 + 1][r] = dq.y;
            sm[2][lc4 + 2][r] = dq.z; sm[2][lc4 + 3][r] = dq.w;
            float4 dk = *(const float4*)&dqkv[qoff + D_ + (size_t)(k0 + r) * 3 * D_ + lc4];
            sm[3][lc4 + 0][r] = dk.x; sm[3][lc4 + 1][r] = dk.y;
            sm[3][lc4 + 2][r] = dk.z; sm[3][lc4 + 3][r] = dk.w;
        }
    }
    __syncthreads();
    float acc[4][4] = {};
#pragma unroll 8
    for (int d = 0; d < HD_; ++d) {
        float4 qa = *(const float4*)&sm[0][d][ty * 4];
        float4 kb = *(const float4*)&sm[1][d][tx * 4];
        float qq[4] = {qa.x, qa.y, qa.z, qa.w};
        float kk[4] = {kb.x, kb.y, kb.z, kb.w};
        if (!TAN) {
#pragma unroll
            for (int i = 0; i < 4; i++)
#pragma unroll
                for (int j = 0; j < 4; j++) acc[i][j] += qq[i] * kk[j];
        } else {
            float4 dqa = *(const float4*)&sm[2][d][ty * 4];
            float4 dkb = *(const float4*)&sm[3][d][tx * 4];
            float dq[4] = {dqa.x, dqa.y, dqa.z, dqa.w};
            float dk[4] = {dkb.x, dkb.y, dkb.z, dkb.w};
#pragma unroll
            for (int i = 0; i < 4; i++)
#pragma unroll
                for (int j = 0; j < 4; j++) acc[i][j] += dq[i] * kk[j] + qq[i] * dk[j];
        }
    }
#pragma unroll
    for (int i = 0; i < 4; i++) {
        size_t rowoff = ((size_t)bh * S_ + q0 + ty * 4 + i) * S_ + k0 + tx * 4;
        float4 o;
        o.x = acc[i][0] * SCALE_; o.y = acc[i][1] * SCALE_;
        o.z = acc[i][2] * SCALE_; o.w = acc[i][3] * SCALE_;
        *(float4*)&sc[rowoff] = o;
    }
}

// ---------------- softmax over rows of length S ----------------
__global__ __launch_bounds__(256) void softmax_rows(float* __restrict__ sc) {
    size_t row = blockIdx.x;
    float* p = sc + row * S_;
    int tid = threadIdx.x;
    float2 v = *(const float2*)&p[tid * 2];
    float mx = block_max(fmaxf(v.x, v.y));
    float e0 = expf(v.x - mx), e1 = expf(v.y - mx);
    float s = block_sum(e0 + e1);
    float inv = 1.0f / s;
    float2 o; o.x = e0 * inv; o.y = e1 * inv;
    *(float2*)&p[tid * 2] = o;
}

// ---------------- dattn = attn*(dsc - rowsum(attn*dsc)), in place on dsc ----------------
__global__ __launch_bounds__(256) void dattn_rows(const float* __restrict__ attn,
                                                  float* __restrict__ dsc) {
    size_t row = blockIdx.x;
    const float* a = attn + row * S_;
    float* d = dsc + row * S_;
    int tid = threadIdx.x;
    float2 av = *(const float2*)&a[tid * 2];
    float2 dv = *(const float2*)&d[tid * 2];
    float s = block_sum(av.x * dv.x + av.y * dv.y);
    float2 o; o.x = av.x * (dv.x - s); o.y = av.y * (dv.y - s);
    *(float2*)&d[tid * 2] = o;
}

// ---------------- o = attn@v (TAN: do = dattn@v + attn@dv) ----------------
template <bool TAN>
__global__ __launch_bounds__(256) void attn_av(const float* __restrict__ attn,
                                               const float* __restrict__ dattn,
                                               const float* __restrict__ qkv,
                                               const float* __restrict__ dqkv,
                                               float* __restrict__ outp) {
    int bh = blockIdx.y;
    int b = bh / H_, hh = bh - b * H_;
    const size_t voff = (size_t)b * S_ * 3 * D_ + 2 * D_ + hh * HD_;
    const float* V = qkv + voff;
    int q0 = blockIdx.x * 64;
    __shared__ float sm[TAN ? 4 : 2][64][68];  // [0]=Ps[k][q] [1]=Vs[k][d] [2]=dPs [3]=dVs
    int tid = threadIdx.x;
    int tx = tid & 15, ty = tid >> 4;
    float acc[4][4] = {};
    for (int k0 = 0; k0 < S_; k0 += 64) {
#pragma unroll
        for (int i = 0; i < 4; i++) {
            int r = (tid >> 4) + i * 16;
            int c4 = (tid & 15) * 4;
            float4 pv = *(const float4*)&attn[((size_t)bh * S_ + q0 + r) * S_ + k0 + c4];
            sm[0][c4 + 0][r] = pv.x; sm[0][c4 + 1][r] = pv.y;
            sm[0][c4 + 2][r] = pv.z; sm[0][c4 + 3][r] = pv.w;
            float4 vv = *(const float4*)&V[(size_t)(k0 + r) * 3 * D_ + c4];
            *(float4*)&sm[1][r][c4] = vv;
            if (TAN) {
                float4 dp = *(const float4*)&dattn[((size_t)bh * S_ + q0 + r) * S_ + k0 + c4];
                sm[2][c4 + 0][r] = dp.x; sm[2][c4 + 1][r] = dp.y;
                sm[2][c4 + 2][r] = dp.z; sm[2][c4 + 3][r] = dp.w;
                float4 dv = *(const float4*)&dqkv[voff + (size_t)(k0 + r) * 3 * D_ + c4];
                *(float4*)&sm[3][r][c4] = dv;
            }
        }
        __syncthreads();
#pragma unroll 8
        for (int kk = 0; kk < 64; kk++) {
            float4 pa = *(const float4*)&sm[0][kk][ty * 4];
            float4 vb = *(const float4*)&sm[1][kk][tx * 4];
            float pp[4] = {pa.x, pa.y, pa.z, pa.w};
            float vv[4] = {vb.x, vb.y, vb.z, vb.w};
            if (!TAN) {
#pragma unroll
                for (int i = 0; i < 4; i++)
#pragma unroll
                    for (int j = 0; j < 4; j++) acc[i][j] += pp[i] * vv[j];
            } else {
                float4 dpa = *(const float4*)&sm[2][kk][ty * 4];
                float4 dvb = *(const float4*)&sm[3][kk][tx * 4];
                float dp[4] = {dpa.x, dpa.y, dpa.z, dpa.w};
                float dv[4] = {dvb.x, dvb.y, dvb.z, dvb.w};
#pragma unroll
                for (int i = 0; i < 4; i++)
#pragma unroll
                    for (int j = 0; j < 4; j++) acc[i][j] += dp[i] * vv[j] + pp[i] * dv[j];
            }
        }
        __syncthreads();
    }
#pragma unroll
    for (int i = 0; i < 4; i++) {
        size_t rowoff = ((size_t)b * S_ + q0 + ty * 4 + i) * D_ + hh * HD_ + tx * 4;
        float4 o; o.x = acc[i][0]; o.y = acc[i][1]; o.z = acc[i][2]; o.w = acc[i][3];
        *(float4*)&outp[rowoff] = o;
    }
}

// ---------------- tangent slice gather/scatter ([B,M,S,D] <-> contiguous [B,S,D]) ----
__global__ __launch_bounds__(256) void gather_t(const float* __restrict__ src,
                                                float* __restrict__ dst, int m) {
    size_t i = (size_t)blockIdx.x * 256 + threadIdx.x;  // over BSD/4 float4s
    size_t per_b = (size_t)S_ * D_ / 4;
    size_t b = i / per_b, rem = i - b * per_b;
    ((float4*)dst)[i] = ((const float4*)src)[(b * M_ + m) * per_b + rem];
}

__global__ __launch_bounds__(256) void scatter_t(const float* __restrict__ src,
                                                 float* __restrict__ dst, int m) {
    size_t i = (size_t)blockIdx.x * 256 + threadIdx.x;
    size_t per_b = (size_t)S_ * D_ / 4;
    size_t b = i / per_b, rem = i - b * per_b;
    ((float4*)dst)[(b * M_ + m) * per_b + rem] = ((const float4*)src)[i];
}

// ---------------- host ----------------
extern "C" void kernel_launch(void* const* d_in, const int* in_sizes, int n_in,
                              void* d_out, int out_size, void* d_ws, size_t ws_size,
                              hipStream_t stream) {
    const float* x = (const float*)d_in[0];
    const float* xt = (const float*)d_in[1];
    const float* g1 = (const float*)d_in[2];
    const float* b1 = (const float*)d_in[3];
    const float* Wqkv = (const float*)d_in[4];
    const float* Wproj = (const float*)d_in[5];
    const float* bproj = (const float*)d_in[6];
    const float* g2 = (const float*)d_in[7];
    const float* b2 = (const float*)d_in[8];
    const float* W1 = (const float*)d_in[9];
    const float* bf1 = (const float*)d_in[10];
    const float* W2 = (const float*)d_in[11];
    const float* bf2 = (const float*)d_in[12];
    float* out = (float*)d_out;       // [B,S,D]
    float* out_t = out + BSD_;        // [B,M,S,D]

    float* w = (float*)d_ws;
    float* xhat1 = w; w += BSD_;
    float* hbuf = w; w += BSD_;   // h, then dh
    float* obuf = w; w += BSD_;   // o, then do, then dout tmp
    float* x2 = w; w += BSD_;
    float* xhat2 = w; w += BSD_;
    float* h2buf = w; w += BSD_;  // h2, then dh2
    float* dx2 = w; w += BSD_;
    float* tbuf = w; w += BSD_;
    float* qkv = w; w += BS3D_;
    float* dqkv = w; w += BS3D_;
    float* attn = w; w += ATT_;
    float* dsc = w; w += ATT_;
    float* abuf = w; w += BSF_;   // a=gelu(u), then da
    float* gp = w; w += BSF_;     // gelu'(u)
    float* rstd1 = w; w += BS_;
    float* rstd2 = w; w += BS_;

    // ---- primal ----
    ln_fwd<<<BS_, 256, 0, stream>>>(x, g1, b1, xhat1, hbuf, rstd1);
    gemm64<0><<<dim3(3 * D_ / 64, BS_ / 64), 256, 0, stream>>>(
        hbuf, Wqkv, nullptr, nullptr, nullptr, qkv, nullptr, BS_, 3 * D_, D_);
    attn_qk<false><<<dim3(S_ / 64, S_ / 64, B_ * H_), 256, 0, stream>>>(qkv, nullptr, attn);
    softmax_rows<<<B_ * H_ * S_, 256, 0, stream>>>(attn);
    attn_av<false><<<dim3(S_ / 64, B_ * H_), 256, 0, stream>>>(attn, nullptr, qkv, nullptr, obuf);
    gemm64<0><<<dim3(D_ / 64, BS_ / 64), 256, 0, stream>>>(
        obuf, Wproj, bproj, x, nullptr, x2, nullptr, BS_, D_, D_);
    ln_fwd<<<BS_, 256, 0, stream>>>(x2, g2, b2, xhat2, h2buf, rstd2);
    gemm64<1><<<dim3(DFF_ / 64, BS_ / 64), 256, 0, stream>>>(
        h2buf, W1, bf1, nullptr, nullptr, abuf, gp, BS_, DFF_, D_);
    gemm64<0><<<dim3(D_ / 64, BS_ / 64), 256, 0, stream>>>(
        abuf, W2, bf2, x2, nullptr, out, nullptr, BS_, D_, DFF_);

    // ---- tangents, sequential (buffers reused; stream order serializes) ----
    for (int m = 0; m < M_; m++) {
        gather_t<<<(int)(BSD_ / 4 / 256), 256, 0, stream>>>(xt, tbuf, m);
        ln_jvp<<<BS_, 256, 0, stream>>>(tbuf, xhat1, rstd1, g1, hbuf);  // dh
        gemm64<0><<<dim3(3 * D_ / 64, BS_ / 64), 256, 0, stream>>>(
            hbuf, Wqkv, nullptr, nullptr, nullptr, dqkv, nullptr, BS_, 3 * D_, D_);
        attn_qk<true><<<dim3(S_ / 64, S_ / 64, B_ * H_), 256, 0, stream>>>(qkv, dqkv, dsc);
        dattn_rows<<<B_ * H_ * S_, 256, 0, stream>>>(attn, dsc);
        attn_av<true><<<dim3(S_ / 64, B_ * H_), 256, 0, stream>>>(attn, dsc, qkv, dqkv, obuf);
        gemm64<0><<<dim3(D_ / 64, BS_ / 64), 256, 0, stream>>>(
            obuf, Wproj, nullptr, tbuf, nullptr, dx2, nullptr, BS_, D_, D_);
        ln_jvp<<<BS_, 256, 0, stream>>>(dx2, xhat2, rstd2, g2, h2buf);  // dh2
        gemm64<2><<<dim3(DFF_ / 64, BS_ / 64), 256, 0, stream>>>(
            h2buf, W1, nullptr, nullptr, gp, abuf, nullptr, BS_, DFF_, D_);  // da
        gemm64<0><<<dim3(D_ / 64, BS_ / 64), 256, 0, stream>>>(
            abuf, W2, nullptr, dx2, nullptr, obuf, nullptr, BS_, D_, DFF_);  // dout tmp
        scatter_t<<<(int)(BSD_ / 4 / 256), 256, 0, stream>>>(obuf, out_t, m);
    }
}

// Round 2
// 1832.252 us; speedup vs baseline: 1.8586x; 1.8586x over previous
//
#include <hip/hip_runtime.h>
#include <math.h>

constexpr int B_ = 4, S_ = 512, D_ = 768, H_ = 12, M_ = 4, DFF_ = 3072, HD_ = 64;
constexpr float EPS_ = 1e-6f;
constexpr float SCALE_ = 0.125f;  // HD^-0.5
constexpr int BS_ = B_ * S_;                    // 2048 rows
constexpr long long BSD_ = (long long)BS_ * D_;
constexpr long long BS3D_ = (long long)BS_ * 3 * D_;
constexpr long long ATT_ = (long long)B_ * H_ * S_ * S_;
constexpr long long BSF_ = (long long)BS_ * DFF_;

typedef __attribute__((ext_vector_type(8))) short bf16x8;
typedef __attribute__((ext_vector_type(4))) float f32x4;

__device__ __forceinline__ ushort f2bf(float f) {
    uint32_t u = __float_as_uint(f);
    u += 0x7FFF + ((u >> 16) & 1);  // round-to-nearest-even
    return (ushort)(u >> 16);
}

// ---------------- block reductions (256 threads = 4 waves) ----------------
__device__ __forceinline__ float block_sum(float v) {
    __shared__ float red[4];
    int tid = threadIdx.x;
#pragma unroll
    for (int off = 32; off > 0; off >>= 1) v += __shfl_down(v, off, 64);
    __syncthreads();
    if ((tid & 63) == 0) red[tid >> 6] = v;
    __syncthreads();
    return red[0] + red[1] + red[2] + red[3];
}

__device__ __forceinline__ float block_max(float v) {
    __shared__ float red[4];
    int tid = threadIdx.x;
#pragma unroll
    for (int off = 32; off > 0; off >>= 1) v = fmaxf(v, __shfl_down(v, off, 64));
    __syncthreads();
    if ((tid & 63) == 0) red[tid >> 6] = v;
    __syncthreads();
    return fmaxf(fmaxf(red[0], red[1]), fmaxf(red[2], red[3]));
}

// ---------------- weight transpose+convert: W[K][N] f32 -> WT[N][K] bf16 ----------------
__global__ __launch_bounds__(256) void transpose_f2b(const float* __restrict__ W,
                                                     ushort* __restrict__ WT,
                                                     int K, int N) {
    __shared__ float t[32][33];
    int n0 = blockIdx.x * 32, k0 = blockIdx.y * 32;
    int tx = threadIdx.x & 31, ty = threadIdx.x >> 5;  // 32x8
#pragma unroll
    for (int i = 0; i < 4; i++)
        t[ty + i * 8][tx] = W[(size_t)(k0 + ty + i * 8) * N + n0 + tx];
    __syncthreads();
#pragma unroll
    for (int i = 0; i < 4; i++)
        WT[(size_t)(n0 + ty + i * 8) * K + k0 + tx] = f2bf(t[tx][ty + i * 8]);
}

// ---------------- LayerNorm forward: x -> xhat(f32), h(bf16), rstd ----------------
__global__ __launch_bounds__(256) void ln_fwd(const float* __restrict__ x,
                                              const float* __restrict__ g,
                                              const float* __restrict__ bta,
                                              float* __restrict__ xhat,
                                              ushort* __restrict__ h,
                                              float* __restrict__ rstd) {
    int row = blockIdx.x;
    const float* xr = x + (size_t)row * D_;
    int tid = threadIdx.x;
    float v[3];
    float s = 0.f;
#pragma unroll
    for (int i = 0; i < 3; i++) { v[i] = xr[tid + i * 256]; s += v[i]; }
    s = block_sum(s);
    float mu = s * (1.0f / D_);
    float vs = 0.f;
#pragma unroll
    for (int i = 0; i < 3; i++) { float c = v[i] - mu; vs += c * c; }
    vs = block_sum(vs);
    float rs = rsqrtf(vs * (1.0f / D_) + EPS_);
#pragma unroll
    for (int i = 0; i < 3; i++) {
        int c = tid + i * 256;
        float xh = (v[i] - mu) * rs;
        xhat[(size_t)row * D_ + c] = xh;
        h[(size_t)row * D_ + c] = f2bf(xh * g[c] + bta[c]);
    }
    if (tid == 0) rstd[row] = rs;
}

// ---------------- LayerNorm JVP: dh(bf16) = g*rstd*(t - mean(t) - xhat*mean(xhat*t)) ----
__global__ __launch_bounds__(256) void ln_jvp(const float* __restrict__ t,
                                              const float* __restrict__ xhat,
                                              const float* __restrict__ rstd,
                                              const float* __restrict__ g,
                                              ushort* __restrict__ dh) {
    int row = blockIdx.x;
    size_t base = (size_t)row * D_;
    int tid = threadIdx.x;
    float tv[3], xh[3];
    float s1 = 0.f, s2 = 0.f;
#pragma unroll
    for (int i = 0; i < 3; i++) {
        int c = tid + i * 256;
        tv[i] = t[base + c];
        xh[i] = xhat[base + c];
        s1 += tv[i];
        s2 += tv[i] * xh[i];
    }
    s1 = block_sum(s1);
    s2 = block_sum(s2);
    float mt = s1 * (1.0f / D_);
    float mx = s2 * (1.0f / D_);
    float rs = rstd[row];
#pragma unroll
    for (int i = 0; i < 3; i++) {
        int c = tid + i * 256;
        dh[base + c] = f2bf(g[c] * rs * (tv[i] - mt - xh[i] * mx));
    }
}

// ---------------- bf16 MFMA GEMM (m97 structure): C[M,N] = A[M,K] @ BT[N,K]^T ----------------
// 128x128 tile, BK=32, 4 waves (2x2), each wave 64x64 = 4x4 x (16x16x32 mfma).
// EPI 0: Cf = acc + bias? + res?
// EPI 1: u = acc + bias; Cb = bf16(gelu(u)); Cf = gelu'(u)
// EPI 2: Cb = bf16(acc * mul)
template <int EPI>
__global__ __launch_bounds__(256) void gemm_mfma(const ushort* __restrict__ A,
                                                 const ushort* __restrict__ BT,
                                                 const float* __restrict__ bias,
                                                 const float* __restrict__ res,
                                                 const float* __restrict__ mul,
                                                 float* __restrict__ Cf,
                                                 ushort* __restrict__ Cb,
                                                 int Mr, int Nc, int Kd) {
    __shared__ ushort As[128 * 32];  // [row][k], row-major, 8 KB
    __shared__ ushort Bs[128 * 32];  // [n][k]
    int tid = threadIdx.x;
    int wave = tid >> 6, lane = tid & 63;
    int wr = wave >> 1, wc = wave & 1;
    int row0 = blockIdx.y * 128, col0 = blockIdx.x * 128;

    // staging address components (chunk c: rows c*16 + lane/4, k-elems (lane&3)*8)
    int srow = (lane >> 2);
    int skel = (lane & 3) * 8;
    const ushort* Ag0 = A + (size_t)(row0 + srow) * Kd + skel;
    const ushort* Bg0 = BT + (size_t)(col0 + srow) * Kd + skel;

    // fragment LDS offsets (constant per lane)
    int frow = lane & 15, fk = (lane >> 4) * 8;
    int aoff[4], boff[4];
#pragma unroll
    for (int i = 0; i < 4; i++) {
        aoff[i] = (wr * 64 + i * 16 + frow) * 32 + fk;
        boff[i] = (wc * 64 + i * 16 + frow) * 32 + fk;
    }

    f32x4 acc[4][4] = {};

    for (int k0 = 0; k0 < Kd; k0 += 32) {
#pragma unroll
        for (int cc = 0; cc < 2; cc++) {
            int c = wave * 2 + cc;
            __builtin_amdgcn_global_load_lds(
                (const __attribute__((address_space(1))) void*)(Ag0 + (size_t)(c * 16) * Kd + k0),
                (__attribute__((address_space(3))) void*)(As + c * 512), 16, 0, 0);
            __builtin_amdgcn_global_load_lds(
                (const __attribute__((address_space(1))) void*)(Bg0 + (size_t)(c * 16) * Kd + k0),
                (__attribute__((address_space(3))) void*)(Bs + c * 512), 16, 0, 0);
        }
        __syncthreads();
        bf16x8 af[4], bf[4];
#pragma unroll
        for (int i = 0; i < 4; i++) af[i] = *(const bf16x8*)(As + aoff[i]);
#pragma unroll
        for (int j = 0; j < 4; j++) bf[j] = *(const bf16x8*)(Bs + boff[j]);
#pragma unroll
        for (int i = 0; i < 4; i++)
#pragma unroll
            for (int j = 0; j < 4; j++)
                acc[i][j] = __builtin_amdgcn_mfma_f32_16x16x32_bf16(af[i], bf[j], acc[i][j], 0, 0, 0);
        __syncthreads();
    }

    // C/D layout: col = lane&15, row = (lane>>4)*4 + reg  [m89/m91 verified]
#pragma unroll
    for (int i = 0; i < 4; i++) {
        int rbase = row0 + wr * 64 + i * 16 + (lane >> 4) * 4;
#pragma unroll
        for (int j = 0; j < 4; j++) {
            int c = col0 + wc * 64 + j * 16 + (lane & 15);
#pragma unroll
            for (int r = 0; r < 4; r++) {
                size_t off = (size_t)(rbase + r) * Nc + c;
                float v = acc[i][j][r];
                if (EPI == 0) {
                    if (bias) v += bias[c];
                    if (res) v += res[off];
                    Cf[off] = v;
                } else if (EPI == 1) {
                    v += bias[c];
                    float cdf = 0.5f * (1.0f + erff(v * 0.70710678118654752f));
                    Cb[off] = f2bf(v * cdf);
                    Cf[off] = cdf + v * 0.39894228040143267f * expf(-0.5f * v * v);
                } else {
                    Cb[off] = f2bf(v * mul[off]);
                }
            }
        }
    }
}

// ---------------- attention scores: sc[bh,q,k] = scale * (q.k)  (TAN: dq.k + q.dk) ----
template <bool TAN>
__global__ __launch_bounds__(256) void attn_qk(const float* __restrict__ qkv,
                                               const float* __restrict__ dqkv,
                                               float* __restrict__ sc) {
    int bh = blockIdx.z;
    int b = bh / H_, hh = bh - b * H_;
    const size_t qoff = (size_t)b * S_ * 3 * D_ + hh * HD_;
    const float* Q = qkv + qoff;
    const float* Kp = qkv + qoff + D_;
    int q0 = blockIdx.y * 64, k0 = blockIdx.x * 64;
    __shared__ float sm[TAN ? 4 : 2][64][68];
    int tid = threadIdx.x;
    int tx = tid & 15, ty = tid >> 4;
    int lr = tid >> 4;
    int lc4 = (tid & 15) * 4;
#pragma unroll
    for (int i = 0; i < 4; i++) {
        int r = lr + i * 16;
        float4 qv = *(const float4*)&Q[(size_t)(q0 + r) * 3 * D_ + lc4];
        sm[0][lc4 + 0][r] = qv.x; sm[0][lc4 + 1][r] = qv.y;
        sm[0][lc4 + 2][r] = qv.z; sm[0][lc4 + 3][r] = qv.w;
        float4 kv = *(const float4*)&Kp[(size_t)(k0 + r) * 3 * D_ + lc4];
        sm[1][lc4 + 0][r] = kv.x; sm[1][lc4 + 1][r] = kv.y;
        sm[1][lc4 + 2][r] = kv.z; sm[1][lc4 + 3][r] = kv.w;
        if (TAN) {
            float4 dq = *(const float4*)&dqkv[qoff + (size_t)(q0 + r) * 3 * D_ + lc4];
            sm[2][lc4 + 0][r] = dq.x; sm[2][lc4 + 1][r] = dq.y;
            sm[2][lc4 + 2][r] = dq.z; sm[2][lc4 + 3][r] = dq.w;
            float4 dk = *(const float4*)&dqkv[qoff + D_ + (size_t)(k0 + r) * 3 * D_ + lc4];
            sm[3][lc4 + 0][r] = dk.x; sm[3][lc4 + 1][r] = dk.y;
            sm[3][lc4 + 2][r] = dk.z; sm[3][lc4 + 3][r] = dk.w;
        }
    }
    __syncthreads();
    float acc[4][4] = {};
#pragma unroll 8
    for (int d = 0; d < HD_; ++d) {
        float4 qa = *(const float4*)&sm[0][d][ty * 4];
        float4 kb = *(const float4*)&sm[1][d][tx * 4];
        float qq[4] = {qa.x, qa.y, qa.z, qa.w};
        float kk[4] = {kb.x, kb.y, kb.z, kb.w};
        if (!TAN) {
#pragma unroll
            for (int i = 0; i < 4; i++)
#pragma unroll
                for (int j = 0; j < 4; j++) acc[i][j] += qq[i] * kk[j];
        } else {
            float4 dqa = *(const float4*)&sm[2][d][ty * 4];
            float4 dkb = *(const float4*)&sm[3][d][tx * 4];
            float dq[4] = {dqa.x, dqa.y, dqa.z, dqa.w};
            float dk[4] = {dkb.x, dkb.y, dkb.z, dkb.w};
#pragma unroll
            for (int i = 0; i < 4; i++)
#pragma unroll
                for (int j = 0; j < 4; j++) acc[i][j] += dq[i] * kk[j] + qq[i] * dk[j];
        }
    }
#pragma unroll
    for (int i = 0; i < 4; i++) {
        size_t rowoff = ((size_t)bh * S_ + q0 + ty * 4 + i) * S_ + k0 + tx * 4;
        float4 o;
        o.x = acc[i][0] * SCALE_; o.y = acc[i][1] * SCALE_;
        o.z = acc[i][2] * SCALE_; o.w = acc[i][3] * SCALE_;
        *(float4*)&sc[rowoff] = o;
    }
}

// ---------------- softmax over rows of length S ----------------
__global__ __launch_bounds__(256) void softmax_rows(float* __restrict__ sc) {
    size_t row = blockIdx.x;
    float* p = sc + row * S_;
    int tid = threadIdx.x;
    float2 v = *(const float2*)&p[tid * 2];
    float mx = block_max(fmaxf(v.x, v.y));
    float e0 = expf(v.x - mx), e1 = expf(v.y - mx);
    float s = block_sum(e0 + e1);
    float inv = 1.0f / s;
    float2 o; o.x = e0 * inv; o.y = e1 * inv;
    *(float2*)&p[tid * 2] = o;
}

// ---------------- dattn = attn*(dsc - rowsum(attn*dsc)), in place on dsc ----------------
__global__ __launch_bounds__(256) void dattn_rows(const float* __restrict__ attn,
                                                  float* __restrict__ dsc) {
    size_t row = blockIdx.x;
    const float* a = attn + row * S_;
    float* d = dsc + row * S_;
    int tid = threadIdx.x;
    float2 av = *(const float2*)&a[tid * 2];
    float2 dv = *(const float2*)&d[tid * 2];
    float s = block_sum(av.x * dv.x + av.y * dv.y);
    float2 o; o.x = av.x * (dv.x - s); o.y = av.y * (dv.y - s);
    *(float2*)&d[tid * 2] = o;
}

// ---------------- o = attn@v (TAN: do = dattn@v + attn@dv), bf16 output ----------------
template <bool TAN>
__global__ __launch_bounds__(256) void attn_av(const float* __restrict__ attn,
                                               const float* __restrict__ dattn,
                                               const float* __restrict__ qkv,
                                               const float* __restrict__ dqkv,
                                               ushort* __restrict__ outp) {
    int bh = blockIdx.y;
    int b = bh / H_, hh = bh - b * H_;
    const size_t voff = (size_t)b * S_ * 3 * D_ + 2 * D_ + hh * HD_;
    const float* V = qkv + voff;
    int q0 = blockIdx.x * 64;
    __shared__ float sm[TAN ? 4 : 2][64][68];
    int tid = threadIdx.x;
    int tx = tid & 15, ty = tid >> 4;
    float acc[4][4] = {};
    for (int k0 = 0; k0 < S_; k0 += 64) {
#pragma unroll
        for (int i = 0; i < 4; i++) {
            int r = (tid >> 4) + i * 16;
            int c4 = (tid & 15) * 4;
            float4 pv = *(const float4*)&attn[((size_t)bh * S_ + q0 + r) * S_ + k0 + c4];
            sm[0][c4 + 0][r] = pv.x; sm[0][c4 + 1][r] = pv.y;
            sm[0][c4 + 2][r] = pv.z; sm[0][c4 + 3][r] = pv.w;
            float4 vv = *(const float4*)&V[(size_t)(k0 + r) * 3 * D_ + c4];
            *(float4*)&sm[1][r][c4] = vv;
            if (TAN) {
                float4 dp = *(const float4*)&dattn[((size_t)bh * S_ + q0 + r) * S_ + k0 + c4];
                sm[2][c4 + 0][r] = dp.x; sm[2][c4 + 1][r] = dp.y;
                sm[2][c4 + 2][r] = dp.z; sm[2][c4 + 3][r] = dp.w;
                float4 dv = *(const float4*)&dqkv[voff + (size_t)(k0 + r) * 3 * D_ + c4];
                *(float4*)&sm[3][r][c4] = dv;
            }
        }
        __syncthreads();
#pragma unroll 8
        for (int kk = 0; kk < 64; kk++) {
            float4 pa = *(const float4*)&sm[0][kk][ty * 4];
            float4 vb = *(const float4*)&sm[1][kk][tx * 4];
            float pp[4] = {pa.x, pa.y, pa.z, pa.w};
            float vv[4] = {vb.x, vb.y, vb.z, vb.w};
            if (!TAN) {
#pragma unroll
                for (int i = 0; i < 4; i++)
#pragma unroll
                    for (int j = 0; j < 4; j++) acc[i][j] += pp[i] * vv[j];
            } else {
                float4 dpa = *(const float4*)&sm[2][kk][ty * 4];
                float4 dvb = *(const float4*)&sm[3][kk][tx * 4];
                float dp[4] = {dpa.x, dpa.y, dpa.z, dpa.w};
                float dv[4] = {dvb.x, dvb.y, dvb.z, dvb.w};
#pragma unroll
                for (int i = 0; i < 4; i++)
#pragma unroll
                    for (int j = 0; j < 4; j++) acc[i][j] += dp[i] * vv[j] + pp[i] * dv[j];
            }
        }
        __syncthreads();
    }
#pragma unroll
    for (int i = 0; i < 4; i++) {
        size_t rowoff = ((size_t)b * S_ + q0 + ty * 4 + i) * D_ + hh * HD_ + tx * 4;
        ushort4 o;
        o.x = f2bf(acc[i][0]); o.y = f2bf(acc[i][1]);
        o.z = f2bf(acc[i][2]); o.w = f2bf(acc[i][3]);
        *(ushort4*)&outp[rowoff] = o;
    }
}

// ---------------- tangent slice gather/scatter ([B,M,S,D] <-> contiguous [B,S,D]) ----
__global__ __launch_bounds__(256) void gather_t(const float* __restrict__ src,
                                                float* __restrict__ dst, int m) {
    size_t i = (size_t)blockIdx.x * 256 + threadIdx.x;
    size_t per_b = (size_t)S_ * D_ / 4;
    size_t b = i / per_b, rem = i - b * per_b;
    ((float4*)dst)[i] = ((const float4*)src)[(b * M_ + m) * per_b + rem];
}

__global__ __launch_bounds__(256) void scatter_t(const float* __restrict__ src,
                                                 float* __restrict__ dst, int m) {
    size_t i = (size_t)blockIdx.x * 256 + threadIdx.x;
    size_t per_b = (size_t)S_ * D_ / 4;
    size_t b = i / per_b, rem = i - b * per_b;
    ((float4*)dst)[(b * M_ + m) * per_b + rem] = ((const float4*)src)[i];
}

// ---------------- host ----------------
extern "C" void kernel_launch(void* const* d_in, const int* in_sizes, int n_in,
                              void* d_out, int out_size, void* d_ws, size_t ws_size,
                              hipStream_t stream) {
    const float* x = (const float*)d_in[0];
    const float* xt = (const float*)d_in[1];
    const float* g1 = (const float*)d_in[2];
    const float* b1 = (const float*)d_in[3];
    const float* Wqkv = (const float*)d_in[4];
    const float* Wproj = (const float*)d_in[5];
    const float* bproj = (const float*)d_in[6];
    const float* g2 = (const float*)d_in[7];
    const float* b2 = (const float*)d_in[8];
    const float* W1 = (const float*)d_in[9];
    const float* bf1 = (const float*)d_in[10];
    const float* W2 = (const float*)d_in[11];
    const float* bf2 = (const float*)d_in[12];
    float* out = (float*)d_out;       // [B,S,D]
    float* out_t = out + BSD_;        // [B,M,S,D]

    char* wp = (char*)d_ws;
    auto alloc = [&](size_t bytes) { void* p = wp; wp += (bytes + 255) & ~(size_t)255; return p; };
    float* xhat1 = (float*)alloc(BSD_ * 4);
    ushort* hb = (ushort*)alloc(BSD_ * 2);     // h, then dh (bf16)
    ushort* obb = (ushort*)alloc(BSD_ * 2);    // o, then do (bf16)
    float* x2 = (float*)alloc(BSD_ * 4);
    float* xhat2 = (float*)alloc(BSD_ * 4);
    ushort* h2b = (ushort*)alloc(BSD_ * 2);    // h2, then dh2 (bf16)
    float* dx2 = (float*)alloc(BSD_ * 4);
    float* tbuf = (float*)alloc(BSD_ * 4);
    float* doutt = (float*)alloc(BSD_ * 4);
    float* qkv = (float*)alloc(BS3D_ * 4);
    float* dqkv = (float*)alloc(BS3D_ * 4);
    float* attn = (float*)alloc(ATT_ * 4);
    float* dsc = (float*)alloc(ATT_ * 4);
    ushort* ab = (ushort*)alloc(BSF_ * 2);     // a, then da (bf16)
    float* gp = (float*)alloc(BSF_ * 4);       // gelu'(u)
    float* rstd1 = (float*)alloc(BS_ * 4);
    float* rstd2 = (float*)alloc(BS_ * 4);
    ushort* WqkvT = (ushort*)alloc((size_t)D_ * 3 * D_ * 2);   // [3D][D]
    ushort* WprojT = (ushort*)alloc((size_t)D_ * D_ * 2);      // [D][D]
    ushort* W1T = (ushort*)alloc((size_t)DFF_ * D_ * 2);       // [DFF][D]
    ushort* W2T = (ushort*)alloc((size_t)D_ * DFF_ * 2);       // [D][DFF]

    // ---- weights -> bf16 transposed [N][K] ----
    transpose_f2b<<<dim3(3 * D_ / 32, D_ / 32), 256, 0, stream>>>(Wqkv, WqkvT, D_, 3 * D_);
    transpose_f2b<<<dim3(D_ / 32, D_ / 32), 256, 0, stream>>>(Wproj, WprojT, D_, D_);
    transpose_f2b<<<dim3(DFF_ / 32, D_ / 32), 256, 0, stream>>>(W1, W1T, D_, DFF_);
    transpose_f2b<<<dim3(D_ / 32, DFF_ / 32), 256, 0, stream>>>(W2, W2T, DFF_, D_);

    // ---- primal ----
    ln_fwd<<<BS_, 256, 0, stream>>>(x, g1, b1, xhat1, hb, rstd1);
    gemm_mfma<0><<<dim3(3 * D_ / 128, BS_ / 128), 256, 0, stream>>>(
        hb, WqkvT, nullptr, nullptr, nullptr, qkv, nullptr, BS_, 3 * D_, D_);
    attn_qk<false><<<dim3(S_ / 64, S_ / 64, B_ * H_), 256, 0, stream>>>(qkv, nullptr, attn);
    softmax_rows<<<B_ * H_ * S_, 256, 0, stream>>>(attn);
    attn_av<false><<<dim3(S_ / 64, B_ * H_), 256, 0, stream>>>(attn, nullptr, qkv, nullptr, obb);
    gemm_mfma<0><<<dim3(D_ / 128, BS_ / 128), 256, 0, stream>>>(
        obb, WprojT, bproj, x, nullptr, x2, nullptr, BS_, D_, D_);
    ln_fwd<<<BS_, 256, 0, stream>>>(x2, g2, b2, xhat2, h2b, rstd2);
    gemm_mfma<1><<<dim3(DFF_ / 128, BS_ / 128), 256, 0, stream>>>(
        h2b, W1T, bf1, nullptr, nullptr, gp, ab, BS_, DFF_, D_);   // a(bf16)+gelu'(f32)
    gemm_mfma<0><<<dim3(D_ / 128, BS_ / 128), 256, 0, stream>>>(
        ab, W2T, bf2, x2, nullptr, out, nullptr, BS_, D_, DFF_);

    // ---- tangents, sequential (buffers reused; stream order serializes) ----
    for (int m = 0; m < M_; m++) {
        gather_t<<<(int)(BSD_ / 4 / 256), 256, 0, stream>>>(xt, tbuf, m);
        ln_jvp<<<BS_, 256, 0, stream>>>(tbuf, xhat1, rstd1, g1, hb);  // dh
        gemm_mfma<0><<<dim3(3 * D_ / 128, BS_ / 128), 256, 0, stream>>>(
            hb, WqkvT, nullptr, nullptr, nullptr, dqkv, nullptr, BS_, 3 * D_, D_);
        attn_qk<true><<<dim3(S_ / 64, S_ / 64, B_ * H_), 256, 0, stream>>>(qkv, dqkv, dsc);
        dattn_rows<<<B_ * H_ * S_, 256, 0, stream>>>(attn, dsc);
        attn_av<true><<<dim3(S_ / 64, B_ * H_), 256, 0, stream>>>(attn, dsc, qkv, dqkv, obb);
        gemm_mfma<0><<<dim3(D_ / 128, BS_ / 128), 256, 0, stream>>>(
            obb, WprojT, nullptr, tbuf, nullptr, dx2, nullptr, BS_, D_, D_);
        ln_jvp<<<BS_, 256, 0, stream>>>(dx2, xhat2, rstd2, g2, h2b);  // dh2
        gemm_mfma<2><<<dim3(DFF_ / 128, BS_ / 128), 256, 0, stream>>>(
            h2b, W1T, nullptr, nullptr, gp, nullptr, ab, BS_, DFF_, D_);  // da(bf16)
        gemm_mfma<0><<<dim3(D_ / 128, BS_ / 128), 256, 0, stream>>>(
            ab, W2T, nullptr, dx2, nullptr, doutt, nullptr, BS_, D_, DFF_);
        scatter_t<<<(int)(BSD_ / 4 / 256), 256, 0, stream>>>(doutt, out_t, m);
    }
}

// Round 5
// 1214.575 us; speedup vs baseline: 2.8038x; 1.5086x over previous
//
#include <hip/hip_runtime.h>
#include <math.h>

constexpr int B_ = 4, S_ = 512, D_ = 768, H_ = 12, M_ = 4, DFF_ = 3072, HD_ = 64;
constexpr float EPS_ = 1e-6f;
constexpr float SCALE_ = 0.125f;  // HD^-0.5
constexpr int BS_ = B_ * S_;
constexpr long long BSD_ = (long long)BS_ * D_;
constexpr long long ATT_ = (long long)B_ * H_ * S_ * S_;
constexpr long long BSF_ = (long long)BS_ * DFF_;

typedef __attribute__((ext_vector_type(8))) short bf16x8;
typedef __attribute__((ext_vector_type(4))) float f32x4;

__device__ __forceinline__ ushort f2bf(float f) {
    uint32_t u = __float_as_uint(f);
    u += 0x7FFF + ((u >> 16) & 1);
    return (ushort)(u >> 16);
}
__device__ __forceinline__ float bf2f(ushort u) {
    return __uint_as_float((uint32_t)u << 16);
}

__device__ __forceinline__ void gll16(const ushort* g, ushort* l) {
    __builtin_amdgcn_global_load_lds((const __attribute__((address_space(1))) void*)g,
                                     (__attribute__((address_space(3))) void*)l, 16, 0, 0);
}

// ---------------- block reductions (256 threads = 4 waves) ----------------
__device__ __forceinline__ float block_sum(float v) {
    __shared__ float red[4];
    int tid = threadIdx.x;
#pragma unroll
    for (int off = 32; off > 0; off >>= 1) v += __shfl_down(v, off, 64);
    __syncthreads();
    if ((tid & 63) == 0) red[tid >> 6] = v;
    __syncthreads();
    return red[0] + red[1] + red[2] + red[3];
}

__device__ __forceinline__ float block_max(float v) {
    __shared__ float red[4];
    int tid = threadIdx.x;
#pragma unroll
    for (int off = 32; off > 0; off >>= 1) v = fmaxf(v, __shfl_down(v, off, 64));
    __syncthreads();
    if ((tid & 63) == 0) red[tid >> 6] = v;
    __syncthreads();
    return fmaxf(fmaxf(red[0], red[1]), fmaxf(red[2], red[3]));
}

// ---------------- weight transpose+convert: W[K][N] f32 -> WT[N][K] bf16 ----------------
__global__ __launch_bounds__(256) void transpose_f2b(const float* __restrict__ W,
                                                     ushort* __restrict__ WT,
                                                     int K, int N) {
    __shared__ float t[32][33];
    int n0 = blockIdx.x * 32, k0 = blockIdx.y * 32;
    int tx = threadIdx.x & 31, ty = threadIdx.x >> 5;
#pragma unroll
    for (int i = 0; i < 4; i++)
        t[ty + i * 8][tx] = W[(size_t)(k0 + ty + i * 8) * N + n0 + tx];
    __syncthreads();
#pragma unroll
    for (int i = 0; i < 4; i++)
        WT[(size_t)(n0 + ty + i * 8) * K + k0 + tx] = f2bf(t[tx][ty + i * 8]);
}

// ---------------- V transpose: qkvb[B,S,3D] bf16 -> Vt[bh][HD][S] bf16 ----------------
__global__ __launch_bounds__(256) void transpose_v(const ushort* __restrict__ qkvb,
                                                   ushort* __restrict__ Vt) {
    int bh = blockIdx.z;
    int b = bh / H_, hh = bh - b * H_;
    int s0 = blockIdx.x * 32, d0 = blockIdx.y * 32;
    __shared__ ushort t[32][33];
    int tx = threadIdx.x & 31, ty = threadIdx.x >> 5;
#pragma unroll
    for (int i = 0; i < 4; i++)
        t[ty + i * 8][tx] = qkvb[(size_t)(b * S_ + s0 + ty + i * 8) * 3 * D_ + 2 * D_ + hh * HD_ + d0 + tx];
    __syncthreads();
#pragma unroll
    for (int i = 0; i < 4; i++)
        Vt[(size_t)bh * HD_ * S_ + (size_t)(d0 + ty + i * 8) * S_ + s0 + tx] = t[tx][ty + i * 8];
}

// ---------------- LayerNorm forward ----------------
__global__ __launch_bounds__(256) void ln_fwd(const float* __restrict__ x,
                                              const float* __restrict__ g,
                                              const float* __restrict__ bta,
                                              float* __restrict__ xhat,
                                              ushort* __restrict__ h,
                                              float* __restrict__ rstd) {
    int row = blockIdx.x;
    const float* xr = x + (size_t)row * D_;
    int tid = threadIdx.x;
    float v[3];
    float s = 0.f;
#pragma unroll
    for (int i = 0; i < 3; i++) { v[i] = xr[tid + i * 256]; s += v[i]; }
    s = block_sum(s);
    float mu = s * (1.0f / D_);
    float vs = 0.f;
#pragma unroll
    for (int i = 0; i < 3; i++) { float c = v[i] - mu; vs += c * c; }
    vs = block_sum(vs);
    float rs = rsqrtf(vs * (1.0f / D_) + EPS_);
#pragma unroll
    for (int i = 0; i < 3; i++) {
        int c = tid + i * 256;
        float xh = (v[i] - mu) * rs;
        xhat[(size_t)row * D_ + c] = xh;
        h[(size_t)row * D_ + c] = f2bf(xh * g[c] + bta[c]);
    }
    if (tid == 0) rstd[row] = rs;
}

// ---------------- LayerNorm JVP: optionally strided tangent input ([B,M,S,D], slice tm) ----
__global__ __launch_bounds__(256) void ln_jvp(const float* __restrict__ t, int tm,
                                              const float* __restrict__ xhat,
                                              const float* __restrict__ rstd,
                                              const float* __restrict__ g,
                                              ushort* __restrict__ dh) {
    int row = blockIdx.x;
    size_t base = (size_t)row * D_;
    size_t tbase;
    if (tm >= 0) {
        int b = row >> 9, s = row & (S_ - 1);
        tbase = ((size_t)(b * M_ + tm) * S_ + s) * D_;
    } else {
        tbase = base;
    }
    int tid = threadIdx.x;
    float tv[3], xh[3];
    float s1 = 0.f, s2 = 0.f;
#pragma unroll
    for (int i = 0; i < 3; i++) {
        int c = tid + i * 256;
        tv[i] = t[tbase + c];
        xh[i] = xhat[base + c];
        s1 += tv[i];
        s2 += tv[i] * xh[i];
    }
    s1 = block_sum(s1);
    s2 = block_sum(s2);
    float mt = s1 * (1.0f / D_);
    float mx = s2 * (1.0f / D_);
    float rs = rstd[row];
#pragma unroll
    for (int i = 0; i < 3; i++) {
        int c = tid + i * 256;
        dh[base + c] = f2bf(g[c] * rs * (tv[i] - mt - xh[i] * mx));
    }
}

// ---------------- bf16 MFMA GEMM (m97): C[M,N] = A[M,K] @ BT[N,K]^T ----------------
// EPI 0: Cf = acc + bias? + res?   (resm/outm >= 0: strided [B,M,S,N] slice access)
// EPI 1: u = acc + bias; Cb = bf16(gelu(u)); Cf = gelu'(u)
// EPI 2: Cb = bf16(acc * mul)
// EPI 3: Cb = bf16(acc)
template <int EPI>
__global__ __launch_bounds__(256) void gemm_mfma(const ushort* __restrict__ A,
                                                 const ushort* __restrict__ BT,
                                                 const float* __restrict__ bias,
                                                 const float* __restrict__ res,
                                                 const float* __restrict__ mul,
                                                 float* __restrict__ Cf,
                                                 ushort* __restrict__ Cb,
                                                 int Nc, int Kd, int resm, int outm) {
    __shared__ ushort As[128 * 32];
    __shared__ ushort Bs[128 * 32];
    int tid = threadIdx.x;
    int wave = tid >> 6, lane = tid & 63;
    int wr = wave >> 1, wc = wave & 1;
    int row0 = blockIdx.y * 128, col0 = blockIdx.x * 128;

    int srow = (lane >> 2);
    int skel = (lane & 3) * 8;
    const ushort* Ag0 = A + (size_t)(row0 + srow) * Kd + skel;
    const ushort* Bg0 = BT + (size_t)(col0 + srow) * Kd + skel;

    int frow = lane & 15, fk = (lane >> 4) * 8;
    int aoff[4], boff[4];
#pragma unroll
    for (int i = 0; i < 4; i++) {
        aoff[i] = (wr * 64 + i * 16 + frow) * 32 + fk;
        boff[i] = (wc * 64 + i * 16 + frow) * 32 + fk;
    }

    f32x4 acc[4][4] = {};

    for (int k0 = 0; k0 < Kd; k0 += 32) {
#pragma unroll
        for (int cc = 0; cc < 2; cc++) {
            int c = wave * 2 + cc;
            gll16(Ag0 + (size_t)(c * 16) * Kd + k0, As + c * 512);
            gll16(Bg0 + (size_t)(c * 16) * Kd + k0, Bs + c * 512);
        }
        __syncthreads();
        bf16x8 af[4], bfv[4];
#pragma unroll
        for (int i = 0; i < 4; i++) af[i] = *(const bf16x8*)(As + aoff[i]);
#pragma unroll
        for (int j = 0; j < 4; j++) bfv[j] = *(const bf16x8*)(Bs + boff[j]);
#pragma unroll
        for (int i = 0; i < 4; i++)
#pragma unroll
            for (int j = 0; j < 4; j++)
                acc[i][j] = __builtin_amdgcn_mfma_f32_16x16x32_bf16(af[i], bfv[j], acc[i][j], 0, 0, 0);
        __syncthreads();
    }

#pragma unroll
    for (int i = 0; i < 4; i++) {
        int rbase = row0 + wr * 64 + i * 16 + (lane >> 4) * 4;
#pragma unroll
        for (int j = 0; j < 4; j++) {
            int c = col0 + wc * 64 + j * 16 + (lane & 15);
#pragma unroll
            for (int r = 0; r < 4; r++) {
                int rg = rbase + r;
                size_t off = (size_t)rg * Nc + c;
                float v = acc[i][j][r];
                if (EPI == 0) {
                    if (bias) v += bias[c];
                    if (res) {
                        size_t roff = off;
                        if (resm >= 0) {
                            int bb = rg >> 9, ss = rg & (S_ - 1);
                            roff = ((size_t)(bb * M_ + resm) * S_ + ss) * Nc + c;
                        }
                        v += res[roff];
                    }
                    size_t ooff = off;
                    if (outm >= 0) {
                        int bb = rg >> 9, ss = rg & (S_ - 1);
                        ooff = ((size_t)(bb * M_ + outm) * S_ + ss) * Nc + c;
                    }
                    Cf[ooff] = v;
                } else if (EPI == 1) {
                    v += bias[c];
                    float cdf = 0.5f * (1.0f + erff(v * 0.70710678118654752f));
                    Cb[off] = f2bf(v * cdf);
                    Cf[off] = cdf + v * 0.39894228040143267f * expf(-0.5f * v * v);
                } else if (EPI == 2) {
                    Cb[off] = f2bf(v * mul[off]);
                } else {
                    Cb[off] = f2bf(v);
                }
            }
        }
    }
}

// ---------------- MFMA QK^T: sc[bh,q,k] = scale*(Q.K)  (TAN: dQ.K + Q.dK) ----------------
template <bool TAN>
__global__ __launch_bounds__(256) void attn_qk_mfma(const ushort* __restrict__ qkvb,
                                                    const ushort* __restrict__ dqkvb,
                                                    float* __restrict__ sc) {
    int bh = blockIdx.z;
    int b = bh / H_, hh = bh - b * H_;
    const size_t qoff = (size_t)b * S_ * 3 * D_ + hh * HD_;
    const ushort* Q = qkvb + qoff;
    const ushort* Kp = qkvb + qoff + D_;
    int q0 = blockIdx.y * 128, kc0 = blockIdx.x * 128;
    __shared__ ushort As[128 * 32];
    __shared__ ushort Bs[128 * 32];
    __shared__ ushort dAs[TAN ? 128 * 32 : 1];
    __shared__ ushort dBs[TAN ? 128 * 32 : 1];
    int tid = threadIdx.x;
    int wave = tid >> 6, lane = tid & 63;
    int wr = wave >> 1, wc = wave & 1;
    const int ld = 3 * D_;

    int srow = (lane >> 2);
    int skel = (lane & 3) * 8;
    const ushort* Ag0 = Q + (size_t)(q0 + srow) * ld + skel;
    const ushort* Bg0 = Kp + (size_t)(kc0 + srow) * ld + skel;

    int frow = lane & 15, fk = (lane >> 4) * 8;
    int aoff[4], boff[4];
#pragma unroll
    for (int i = 0; i < 4; i++) {
        aoff[i] = (wr * 64 + i * 16 + frow) * 32 + fk;
        boff[i] = (wc * 64 + i * 16 + frow) * 32 + fk;
    }

    f32x4 acc[4][4] = {};

    for (int k0 = 0; k0 < HD_; k0 += 32) {
#pragma unroll
        for (int cc = 0; cc < 2; cc++) {
            int c = wave * 2 + cc;
            size_t goff = (size_t)(c * 16) * ld + k0;
            gll16(Ag0 + goff, As + c * 512);
            gll16(Bg0 + goff, Bs + c * 512);
            if (TAN) {
                gll16(dqkvb + qoff + (size_t)(q0 + srow) * ld + skel + goff, dAs + c * 512);
                gll16(dqkvb + qoff + D_ + (size_t)(kc0 + srow) * ld + skel + goff, dBs + c * 512);
            }
        }
        __syncthreads();
        bf16x8 af[4], bfv[4];
#pragma unroll
        for (int i = 0; i < 4; i++) af[i] = *(const bf16x8*)(As + aoff[i]);
#pragma unroll
        for (int j = 0; j < 4; j++) bfv[j] = *(const bf16x8*)(Bs + boff[j]);
        if (!TAN) {
#pragma unroll
            for (int i = 0; i < 4; i++)
#pragma unroll
                for (int j = 0; j < 4; j++)
                    acc[i][j] = __builtin_amdgcn_mfma_f32_16x16x32_bf16(af[i], bfv[j], acc[i][j], 0, 0, 0);
        } else {
            bf16x8 daf[4], dbf[4];
#pragma unroll
            for (int i = 0; i < 4; i++) daf[i] = *(const bf16x8*)(dAs + aoff[i]);
#pragma unroll
            for (int j = 0; j < 4; j++) dbf[j] = *(const bf16x8*)(dBs + boff[j]);
#pragma unroll
            for (int i = 0; i < 4; i++)
#pragma unroll
                for (int j = 0; j < 4; j++) {
                    acc[i][j] = __builtin_amdgcn_mfma_f32_16x16x32_bf16(daf[i], bfv[j], acc[i][j], 0, 0, 0);
                    acc[i][j] = __builtin_amdgcn_mfma_f32_16x16x32_bf16(af[i], dbf[j], acc[i][j], 0, 0, 0);
                }
        }
        __syncthreads();
    }

#pragma unroll
    for (int i = 0; i < 4; i++) {
        int rbase = q0 + wr * 64 + i * 16 + (lane >> 4) * 4;
#pragma unroll
        for (int j = 0; j < 4; j++) {
            int c = kc0 + wc * 64 + j * 16 + (lane & 15);
#pragma unroll
            for (int r = 0; r < 4; r++)
                sc[((size_t)bh * S_ + rbase + r) * S_ + c] = acc[i][j][r] * SCALE_;
        }
    }
}

// ---------------- MFMA P@V: o[q][d] (TAN: dP@V + P@dV), bf16 out into [B,S,D] ----------------
template <bool TAN>
__global__ __launch_bounds__(256) void attn_av_mfma(const ushort* __restrict__ Pb,
                                                    const ushort* __restrict__ dPb,
                                                    const ushort* __restrict__ Vt,
                                                    const ushort* __restrict__ dVt,
                                                    ushort* __restrict__ outp) {
    int bh = blockIdx.y;
    int b = bh / H_, hh = bh - b * H_;
    int q0 = blockIdx.x * 128;
    const ushort* Pg = Pb + (size_t)bh * S_ * S_;
    const ushort* Vg = Vt + (size_t)bh * HD_ * S_;
    __shared__ ushort As[128 * 32];   // P rows
    __shared__ ushort Bs[64 * 32];    // Vt rows (d)
    __shared__ ushort dAs[TAN ? 128 * 32 : 1];
    __shared__ ushort dBs[TAN ? 64 * 32 : 1];
    int tid = threadIdx.x;
    int wave = tid >> 6, lane = tid & 63;
    int wr = wave >> 1, wc = wave & 1;

    int srow = (lane >> 2);
    int skel = (lane & 3) * 8;

    int frow = lane & 15, fk = (lane >> 4) * 8;
    int aoff[4], boff[2];
#pragma unroll
    for (int i = 0; i < 4; i++) aoff[i] = (wr * 64 + i * 16 + frow) * 32 + fk;
#pragma unroll
    for (int j = 0; j < 2; j++) boff[j] = (wc * 32 + j * 16 + frow) * 32 + fk;

    f32x4 acc[4][2] = {};

    for (int k0 = 0; k0 < S_; k0 += 32) {
#pragma unroll
        for (int cc = 0; cc < 2; cc++) {
            int c = wave * 2 + cc;
            gll16(Pg + (size_t)(q0 + c * 16 + srow) * S_ + k0 + skel, As + c * 512);
            if (TAN) gll16(dPb + (size_t)bh * S_ * S_ + (size_t)(q0 + c * 16 + srow) * S_ + k0 + skel,
                           dAs + c * 512);
        }
        {
            int c = wave;
            gll16(Vg + (size_t)(c * 16 + srow) * S_ + k0 + skel, Bs + c * 512);
            if (TAN) gll16(dVt + (size_t)bh * HD_ * S_ + (size_t)(c * 16 + srow) * S_ + k0 + skel,
                           dBs + c * 512);
        }
        __syncthreads();
        bf16x8 af[4], bfv[2];
#pragma unroll
        for (int i = 0; i < 4; i++) af[i] = *(const bf16x8*)(As + aoff[i]);
#pragma unroll
        for (int j = 0; j < 2; j++) bfv[j] = *(const bf16x8*)(Bs + boff[j]);
        if (!TAN) {
#pragma unroll
            for (int i = 0; i < 4; i++)
#pragma unroll
                for (int j = 0; j < 2; j++)
                    acc[i][j] = __builtin_amdgcn_mfma_f32_16x16x32_bf16(af[i], bfv[j], acc[i][j], 0, 0, 0);
        } else {
            bf16x8 daf[4], dbf[2];
#pragma unroll
            for (int i = 0; i < 4; i++) daf[i] = *(const bf16x8*)(dAs + aoff[i]);
#pragma unroll
            for (int j = 0; j < 2; j++) dbf[j] = *(const bf16x8*)(dBs + boff[j]);
#pragma unroll
            for (int i = 0; i < 4; i++)
#pragma unroll
                for (int j = 0; j < 2; j++) {
                    acc[i][j] = __builtin_amdgcn_mfma_f32_16x16x32_bf16(daf[i], bfv[j], acc[i][j], 0, 0, 0);
                    acc[i][j] = __builtin_amdgcn_mfma_f32_16x16x32_bf16(af[i], dbf[j], acc[i][j], 0, 0, 0);
                }
        }
        __syncthreads();
    }

#pragma unroll
    for (int i = 0; i < 4; i++) {
        int rbase = q0 + wr * 64 + i * 16 + (lane >> 4) * 4;
#pragma unroll
        for (int j = 0; j < 2; j++) {
            int c = hh * HD_ + wc * 32 + j * 16 + (lane & 15);
#pragma unroll
            for (int r = 0; r < 4; r++)
                outp[(size_t)(b * S_ + rbase + r) * D_ + c] = f2bf(acc[i][j][r]);
        }
    }
}

// ---------------- softmax over rows: f32 scores in -> bf16 probs out ----------------
__global__ __launch_bounds__(256) void softmax_rows(const float* __restrict__ sc,
                                                    ushort* __restrict__ scb) {
    size_t row = blockIdx.x;
    const float* p = sc + row * S_;
    int tid = threadIdx.x;
    float2 v = *(const float2*)&p[tid * 2];
    float mx = block_max(fmaxf(v.x, v.y));
    float e0 = expf(v.x - mx), e1 = expf(v.y - mx);
    float s = block_sum(e0 + e1);
    float inv = 1.0f / s;
    ushort2 ob; ob.x = f2bf(e0 * inv); ob.y = f2bf(e1 * inv);
    *(ushort2*)&scb[row * S_ + tid * 2] = ob;
}

// ---------------- dattn(bf16) = attn*(dsc - rowsum(attn*dsc)), attn in bf16 ----------------
__global__ __launch_bounds__(256) void dattn_rows(const ushort* __restrict__ attnb,
                                                  const float* __restrict__ dsc,
                                                  ushort* __restrict__ dPb) {
    size_t row = blockIdx.x;
    const ushort* a = attnb + row * S_;
    const float* d = dsc + row * S_;
    int tid = threadIdx.x;
    ushort2 au = *(const ushort2*)&a[tid * 2];
    float2 dv = *(const float2*)&d[tid * 2];
    float a0 = bf2f(au.x), a1 = bf2f(au.y);
    float s = block_sum(a0 * dv.x + a1 * dv.y);
    ushort2 o;
    o.x = f2bf(a0 * (dv.x - s));
    o.y = f2bf(a1 * (dv.y - s));
    *(ushort2*)&dPb[row * S_ + tid * 2] = o;
}

// ---------------- host ----------------
extern "C" void kernel_launch(void* const* d_in, const int* in_sizes, int n_in,
                              void* d_out, int out_size, void* d_ws, size_t ws_size,
                              hipStream_t stream) {
    const float* x = (const float*)d_in[0];
    const float* xt = (const float*)d_in[1];
    const float* g1 = (const float*)d_in[2];
    const float* b1 = (const float*)d_in[3];
    const float* Wqkv = (const float*)d_in[4];
    const float* Wproj = (const float*)d_in[5];
    const float* bproj = (const float*)d_in[6];
    const float* g2 = (const float*)d_in[7];
    const float* b2 = (const float*)d_in[8];
    const float* W1 = (const float*)d_in[9];
    const float* bf1 = (const float*)d_in[10];
    const float* W2 = (const float*)d_in[11];
    const float* bf2 = (const float*)d_in[12];
    float* out = (float*)d_out;
    float* out_t = out + BSD_;   // [B,M,S,D]

    char* wp = (char*)d_ws;
    auto alloc = [&](size_t bytes) { void* p = wp; wp += (bytes + 255) & ~(size_t)255; return p; };
    float* xhat1 = (float*)alloc(BSD_ * 4);
    ushort* hb = (ushort*)alloc(BSD_ * 2);
    ushort* obb = (ushort*)alloc(BSD_ * 2);
    float* x2 = (float*)alloc(BSD_ * 4);
    float* xhat2 = (float*)alloc(BSD_ * 4);
    ushort* h2b = (ushort*)alloc(BSD_ * 2);
    float* dx2 = (float*)alloc(BSD_ * 4);
    ushort* qkvb = (ushort*)alloc(BSD_ * 3 * 2);
    ushort* dqkvb = (ushort*)alloc(BSD_ * 3 * 2);
    float* dsc = (float*)alloc(ATT_ * 4);      // primal scores, then per-tangent dscores
    ushort* attnb = (ushort*)alloc(ATT_ * 2);  // probs bf16
    ushort* dPb = (ushort*)alloc(ATT_ * 2);
    ushort* Vt = (ushort*)alloc(BSD_ * 2);
    ushort* dVt = (ushort*)alloc(BSD_ * 2);
    ushort* ab = (ushort*)alloc(BSF_ * 2);
    float* gp = (float*)alloc(BSF_ * 4);
    float* rstd1 = (float*)alloc(BS_ * 4);
    float* rstd2 = (float*)alloc(BS_ * 4);
    ushort* WqkvT = (ushort*)alloc((size_t)D_ * 3 * D_ * 2);
    ushort* WprojT = (ushort*)alloc((size_t)D_ * D_ * 2);
    ushort* W1T = (ushort*)alloc((size_t)DFF_ * D_ * 2);
    ushort* W2T = (ushort*)alloc((size_t)D_ * DFF_ * 2);

    // ---- weights -> bf16 transposed [N][K] ----
    transpose_f2b<<<dim3(3 * D_ / 32, D_ / 32), 256, 0, stream>>>(Wqkv, WqkvT, D_, 3 * D_);
    transpose_f2b<<<dim3(D_ / 32, D_ / 32), 256, 0, stream>>>(Wproj, WprojT, D_, D_);
    transpose_f2b<<<dim3(DFF_ / 32, D_ / 32), 256, 0, stream>>>(W1, W1T, D_, DFF_);
    transpose_f2b<<<dim3(D_ / 32, DFF_ / 32), 256, 0, stream>>>(W2, W2T, DFF_, D_);

    // ---- primal ----
    ln_fwd<<<BS_, 256, 0, stream>>>(x, g1, b1, xhat1, hb, rstd1);
    gemm_mfma<3><<<dim3(3 * D_ / 128, BS_ / 128), 256, 0, stream>>>(
        hb, WqkvT, nullptr, nullptr, nullptr, nullptr, qkvb, 3 * D_, D_, -1, -1);
    transpose_v<<<dim3(S_ / 32, HD_ / 32, B_ * H_), 256, 0, stream>>>(qkvb, Vt);
    attn_qk_mfma<false><<<dim3(S_ / 128, S_ / 128, B_ * H_), 256, 0, stream>>>(qkvb, nullptr, dsc);
    softmax_rows<<<B_ * H_ * S_, 256, 0, stream>>>(dsc, attnb);
    attn_av_mfma<false><<<dim3(S_ / 128, B_ * H_), 256, 0, stream>>>(attnb, nullptr, Vt, nullptr, obb);
    gemm_mfma<0><<<dim3(D_ / 128, BS_ / 128), 256, 0, stream>>>(
        obb, WprojT, bproj, x, nullptr, x2, nullptr, D_, D_, -1, -1);
    ln_fwd<<<BS_, 256, 0, stream>>>(x2, g2, b2, xhat2, h2b, rstd2);
    gemm_mfma<1><<<dim3(DFF_ / 128, BS_ / 128), 256, 0, stream>>>(
        h2b, W1T, bf1, nullptr, nullptr, gp, ab, DFF_, D_, -1, -1);
    gemm_mfma<0><<<dim3(D_ / 128, BS_ / 128), 256, 0, stream>>>(
        ab, W2T, bf2, x2, nullptr, out, nullptr, D_, DFF_, -1, -1);

    // ---- tangents ----
    for (int m = 0; m < M_; m++) {
        ln_jvp<<<BS_, 256, 0, stream>>>(xt, m, xhat1, rstd1, g1, hb);
        gemm_mfma<3><<<dim3(3 * D_ / 128, BS_ / 128), 256, 0, stream>>>(
            hb, WqkvT, nullptr, nullptr, nullptr, nullptr, dqkvb, 3 * D_, D_, -1, -1);
        transpose_v<<<dim3(S_ / 32, HD_ / 32, B_ * H_), 256, 0, stream>>>(dqkvb, dVt);
        attn_qk_mfma<true><<<dim3(S_ / 128, S_ / 128, B_ * H_), 256, 0, stream>>>(qkvb, dqkvb, dsc);
        dattn_rows<<<B_ * H_ * S_, 256, 0, stream>>>(attnb, dsc, dPb);
        attn_av_mfma<true><<<dim3(S_ / 128, B_ * H_), 256, 0, stream>>>(attnb, dPb, Vt, dVt, obb);
        gemm_mfma<0><<<dim3(D_ / 128, BS_ / 128), 256, 0, stream>>>(
            obb, WprojT, nullptr, xt, nullptr, dx2, nullptr, D_, D_, m, -1);
        ln_jvp<<<BS_, 256, 0, stream>>>(dx2, -1, xhat2, rstd2, g2, h2b);
        gemm_mfma<2><<<dim3(DFF_ / 128, BS_ / 128), 256, 0, stream>>>(
            h2b, W1T, nullptr, nullptr, gp, nullptr, ab, DFF_, D_, -1, -1);
        gemm_mfma<0><<<dim3(D_ / 128, BS_ / 128), 256, 0, stream>>>(
            ab, W2T, nullptr, dx2, nullptr, out_t, nullptr, D_, DFF_, -1, m);
    }
}

// Round 6
// 736.484 us; speedup vs baseline: 4.6240x; 1.6492x over previous
//
#include <hip/hip_runtime.h>
#include <math.h>

constexpr int B_ = 4, S_ = 512, D_ = 768, H_ = 12, M_ = 4, DFF_ = 3072, HD_ = 64;
constexpr float EPS_ = 1e-6f;
constexpr float SCALE_ = 0.125f;  // HD^-0.5
constexpr int BS_ = B_ * S_;
constexpr long long BSD_ = (long long)BS_ * D_;
constexpr long long BS3D_ = (long long)BS_ * 3 * D_;
constexpr long long ATT_ = (long long)B_ * H_ * S_ * S_;
constexpr long long BSF_ = (long long)BS_ * DFF_;

typedef __attribute__((ext_vector_type(8))) short bf16x8;
typedef __attribute__((ext_vector_type(4))) float f32x4;

__device__ __forceinline__ ushort f2bf(float f) {
    uint32_t u = __float_as_uint(f);
    u += 0x7FFF + ((u >> 16) & 1);
    return (ushort)(u >> 16);
}
__device__ __forceinline__ float bf2f(ushort u) {
    return __uint_as_float((uint32_t)u << 16);
}

__device__ __forceinline__ void gll16(const ushort* g, ushort* l) {
    __builtin_amdgcn_global_load_lds((const __attribute__((address_space(1))) void*)g,
                                     (__attribute__((address_space(3))) void*)l, 16, 0, 0);
}

// batched-row (rg in [0,8192)) -> [B,M,S,Nc] offset
__device__ __forceinline__ size_t stroff(int rg, int c, int Nc) {
    int m = rg >> 11;
    int b = (rg >> 9) & (B_ - 1);
    int s = rg & (S_ - 1);
    return ((size_t)((b * M_ + m) * S_ + s)) * Nc + c;
}

// ---------------- block reductions (256 threads = 4 waves) ----------------
__device__ __forceinline__ float block_sum(float v) {
    __shared__ float red[4];
    int tid = threadIdx.x;
#pragma unroll
    for (int off = 32; off > 0; off >>= 1) v += __shfl_down(v, off, 64);
    __syncthreads();
    if ((tid & 63) == 0) red[tid >> 6] = v;
    __syncthreads();
    return red[0] + red[1] + red[2] + red[3];
}

__device__ __forceinline__ float block_max(float v) {
    __shared__ float red[4];
    int tid = threadIdx.x;
#pragma unroll
    for (int off = 32; off > 0; off >>= 1) v = fmaxf(v, __shfl_down(v, off, 64));
    __syncthreads();
    if ((tid & 63) == 0) red[tid >> 6] = v;
    __syncthreads();
    return fmaxf(fmaxf(red[0], red[1]), fmaxf(red[2], red[3]));
}

// ---------------- weight transpose+convert: W[K][N] f32 -> WT[N][K] bf16 ----------------
__global__ __launch_bounds__(256) void transpose_f2b(const float* __restrict__ W,
                                                     ushort* __restrict__ WT,
                                                     int K, int N) {
    __shared__ float t[32][33];
    int n0 = blockIdx.x * 32, k0 = blockIdx.y * 32;
    int tx = threadIdx.x & 31, ty = threadIdx.x >> 5;
#pragma unroll
    for (int i = 0; i < 4; i++)
        t[ty + i * 8][tx] = W[(size_t)(k0 + ty + i * 8) * N + n0 + tx];
    __syncthreads();
#pragma unroll
    for (int i = 0; i < 4; i++)
        WT[(size_t)(n0 + ty + i * 8) * K + k0 + tx] = f2bf(t[tx][ty + i * 8]);
}

// ---------------- V transpose: src[m][B,S,3D] bf16 -> dst[m][bh][HD][S] bf16 ----------------
__global__ __launch_bounds__(256) void transpose_v(const ushort* __restrict__ src0,
                                                   ushort* __restrict__ dst0) {
    int z = blockIdx.z;
    int m = z / (B_ * H_), bh = z % (B_ * H_);
    const ushort* qkvb = src0 + (size_t)m * BS3D_;
    ushort* Vt = dst0 + (size_t)m * BSD_;
    int b = bh / H_, hh = bh - b * H_;
    int s0 = blockIdx.x * 32, d0 = blockIdx.y * 32;
    __shared__ ushort t[32][33];
    int tx = threadIdx.x & 31, ty = threadIdx.x >> 5;
#pragma unroll
    for (int i = 0; i < 4; i++)
        t[ty + i * 8][tx] = qkvb[(size_t)(b * S_ + s0 + ty + i * 8) * 3 * D_ + 2 * D_ + hh * HD_ + d0 + tx];
    __syncthreads();
#pragma unroll
    for (int i = 0; i < 4; i++)
        Vt[(size_t)bh * HD_ * S_ + (size_t)(d0 + ty + i * 8) * S_ + s0 + tx] = t[tx][ty + i * 8];
}

// ---------------- LayerNorm forward: xhat bf16, h bf16 ----------------
__global__ __launch_bounds__(256) void ln_fwd(const float* __restrict__ x,
                                              const float* __restrict__ g,
                                              const float* __restrict__ bta,
                                              ushort* __restrict__ xhat,
                                              ushort* __restrict__ h,
                                              float* __restrict__ rstd) {
    int row = blockIdx.x;
    const float* xr = x + (size_t)row * D_;
    int tid = threadIdx.x;
    float v[3];
    float s = 0.f;
#pragma unroll
    for (int i = 0; i < 3; i++) { v[i] = xr[tid + i * 256]; s += v[i]; }
    s = block_sum(s);
    float mu = s * (1.0f / D_);
    float vs = 0.f;
#pragma unroll
    for (int i = 0; i < 3; i++) { float c = v[i] - mu; vs += c * c; }
    vs = block_sum(vs);
    float rs = rsqrtf(vs * (1.0f / D_) + EPS_);
#pragma unroll
    for (int i = 0; i < 3; i++) {
        int c = tid + i * 256;
        float xh = (v[i] - mu) * rs;
        xhat[(size_t)row * D_ + c] = f2bf(xh);
        h[(size_t)row * D_ + c] = f2bf(xh * g[c] + bta[c]);
    }
    if (tid == 0) rstd[row] = rs;
}

// ---------------- batched LayerNorm JVP: grid 4*BS_ rows ----------------
// mode 0: t = x_tangent [B,M,S,D] (strided per rg); mode 1: t contiguous [4*BS][D]
__global__ __launch_bounds__(256) void ln_jvp(const float* __restrict__ t, int mode,
                                              const ushort* __restrict__ xhat,
                                              const float* __restrict__ rstd,
                                              const float* __restrict__ g,
                                              ushort* __restrict__ dh) {
    int rg = blockIdx.x;
    int r = rg & (BS_ - 1);
    size_t tbase;
    if (mode == 0) {
        int m = rg >> 11;
        int b = r >> 9, s = r & (S_ - 1);
        tbase = ((size_t)((b * M_ + m) * S_ + s)) * D_;
    } else {
        tbase = (size_t)rg * D_;
    }
    size_t pbase = (size_t)r * D_;
    int tid = threadIdx.x;
    float tv[3], xh[3];
    float s1 = 0.f, s2 = 0.f;
#pragma unroll
    for (int i = 0; i < 3; i++) {
        int c = tid + i * 256;
        tv[i] = t[tbase + c];
        xh[i] = bf2f(xhat[pbase + c]);
        s1 += tv[i];
        s2 += tv[i] * xh[i];
    }
    s1 = block_sum(s1);
    s2 = block_sum(s2);
    float mt = s1 * (1.0f / D_);
    float mx = s2 * (1.0f / D_);
    float rs = rstd[r];
#pragma unroll
    for (int i = 0; i < 3; i++) {
        int c = tid + i * 256;
        dh[(size_t)rg * D_ + c] = f2bf(g[c] * rs * (tv[i] - mt - xh[i] * mx));
    }
}

// ---------------- bf16 MFMA GEMM, BK=64, XOR-swizzled LDS ----------------
// C[M,N] = A[M,K] @ BT[N,K]^T ; 128x128 tile, 4 waves, 32 MFMA/K-step.
// EPI 0: Cf[out] = acc + bias? + res?    (RS: res strided-m, OS: out strided-m)
// EPI 1: u = acc+bias; Cb = bf16(gelu(u)); aux = bf16(u)
// EPI 2: Cb = bf16(acc * gelu'(bf2f(aux[primal row])))
// EPI 3: Cb = bf16(acc)
template <int EPI, bool RS, bool OS>
__global__ __launch_bounds__(256) void gemm_mfma(const ushort* __restrict__ A,
                                                 const ushort* __restrict__ BT,
                                                 const float* __restrict__ bias,
                                                 const float* __restrict__ res,
                                                 float* __restrict__ Cf,
                                                 ushort* __restrict__ Cb,
                                                 ushort* __restrict__ aux,
                                                 int Nc, int Kd) {
    __shared__ ushort As[128 * 64];  // [row][k], rows 128B; content pre-swizzled
    __shared__ ushort Bs[128 * 64];
    int tid = threadIdx.x;
    int wave = tid >> 6, lane = tid & 63;
    int wr = wave >> 1, wc = wave & 1;
    int row0 = blockIdx.y * 128, col0 = blockIdx.x * 128;

    // staging: chunk c covers rows c*8..c*8+7 (1024B); lane l -> row c*8+(l>>3).
    // global k-offset pre-swizzled ((l&7)^(l>>3))*8 so LDS[r][kb] = G[r][kb ^ ((r&7)<<3)]
    int srow = lane >> 3;
    int skel = ((lane & 7) ^ (lane >> 3)) * 8;
    const ushort* Ag0 = A + (size_t)(row0 + srow) * Kd + skel;
    const ushort* Bg0 = BT + (size_t)(col0 + srow) * Kd + skel;

    // fragment read offsets: linear elem (fkb+ks*32) -> swizzled ^((row&7)*8)
    int frow = lane & 15, fkb = (lane >> 4) * 8;
    int aoff[2][4], boff[2][4];
#pragma unroll
    for (int ks = 0; ks < 2; ks++)
#pragma unroll
        for (int i = 0; i < 4; i++) {
            int sw = (fkb + ks * 32) ^ ((frow & 7) * 8);
            aoff[ks][i] = (wr * 64 + i * 16 + frow) * 64 + sw;
            boff[ks][i] = (wc * 64 + i * 16 + frow) * 64 + sw;
        }

    f32x4 acc[4][4] = {};

    for (int k0 = 0; k0 < Kd; k0 += 64) {
#pragma unroll
        for (int cc = 0; cc < 4; cc++) {
            int c = wave * 4 + cc;
            gll16(Ag0 + (size_t)(c * 8) * Kd + k0, As + c * 512);
            gll16(Bg0 + (size_t)(c * 8) * Kd + k0, Bs + c * 512);
        }
        __syncthreads();
        bf16x8 af[2][4], bfv[2][4];
#pragma unroll
        for (int ks = 0; ks < 2; ks++)
#pragma unroll
            for (int i = 0; i < 4; i++) {
                af[ks][i] = *(const bf16x8*)(As + aoff[ks][i]);
                bfv[ks][i] = *(const bf16x8*)(Bs + boff[ks][i]);
            }
#pragma unroll
        for (int ks = 0; ks < 2; ks++)
#pragma unroll
            for (int i = 0; i < 4; i++)
#pragma unroll
                for (int j = 0; j < 4; j++)
                    acc[i][j] = __builtin_amdgcn_mfma_f32_16x16x32_bf16(af[ks][i], bfv[ks][j], acc[i][j], 0, 0, 0);
        __syncthreads();
    }

    // C/D layout: col = lane&15, row = (lane>>4)*4 + reg
#pragma unroll
    for (int i = 0; i < 4; i++) {
        int rbase = row0 + wr * 64 + i * 16 + (lane >> 4) * 4;
#pragma unroll
        for (int j = 0; j < 4; j++) {
            int c = col0 + wc * 64 + j * 16 + (lane & 15);
#pragma unroll
            for (int r = 0; r < 4; r++) {
                int rg = rbase + r;
                size_t off = (size_t)rg * Nc + c;
                float v = acc[i][j][r];
                if (EPI == 0) {
                    if (bias) v += bias[c];
                    if (res) v += res[RS ? stroff(rg, c, Nc) : off];
                    if (OS) Cf[stroff(rg, c, Nc)] = v; else Cf[off] = v;
                } else if (EPI == 1) {
                    v += bias[c];
                    float cdf = 0.5f * (1.0f + erff(v * 0.70710678118654752f));
                    Cb[off] = f2bf(v * cdf);
                    aux[off] = f2bf(v);
                } else if (EPI == 2) {
                    float u = bf2f(aux[(size_t)(rg & (BS_ - 1)) * Nc + c]);
                    float cdf = 0.5f * (1.0f + erff(u * 0.70710678118654752f));
                    float gp = cdf + u * 0.39894228040143267f * expf(-0.5f * u * u);
                    Cb[off] = f2bf(v * gp);
                } else {
                    Cb[off] = f2bf(v);
                }
            }
        }
    }
}

// ---------------- MFMA QK^T (BK=32): scb bf16 = scale*(Q.K)  (TAN: dQ.K + Q.dK) ----------------
template <bool TAN>
__global__ __launch_bounds__(256) void attn_qk_mfma(const ushort* __restrict__ qkvb,
                                                    const ushort* __restrict__ dqkvb,
                                                    ushort* __restrict__ sc) {
    int bh = blockIdx.z;
    int b = bh / H_, hh = bh - b * H_;
    const size_t qoff = (size_t)b * S_ * 3 * D_ + hh * HD_;
    const ushort* Q = qkvb + qoff;
    const ushort* Kp = qkvb + qoff + D_;
    int q0 = blockIdx.y * 128, kc0 = blockIdx.x * 128;
    __shared__ ushort As[128 * 32];
    __shared__ ushort Bs[128 * 32];
    __shared__ ushort dAs[TAN ? 128 * 32 : 1];
    __shared__ ushort dBs[TAN ? 128 * 32 : 1];
    int tid = threadIdx.x;
    int wave = tid >> 6, lane = tid & 63;
    int wr = wave >> 1, wc = wave & 1;
    const int ld = 3 * D_;

    int srow = (lane >> 2);
    int skel = (lane & 3) * 8;
    const ushort* Ag0 = Q + (size_t)(q0 + srow) * ld + skel;
    const ushort* Bg0 = Kp + (size_t)(kc0 + srow) * ld + skel;

    int frow = lane & 15, fk = (lane >> 4) * 8;
    int aoff[4], boff[4];
#pragma unroll
    for (int i = 0; i < 4; i++) {
        aoff[i] = (wr * 64 + i * 16 + frow) * 32 + fk;
        boff[i] = (wc * 64 + i * 16 + frow) * 32 + fk;
    }

    f32x4 acc[4][4] = {};

    for (int k0 = 0; k0 < HD_; k0 += 32) {
#pragma unroll
        for (int cc = 0; cc < 2; cc++) {
            int c = wave * 2 + cc;
            size_t goff = (size_t)(c * 16) * ld + k0;
            gll16(Ag0 + goff, As + c * 512);
            gll16(Bg0 + goff, Bs + c * 512);
            if (TAN) {
                gll16(dqkvb + qoff + (size_t)(q0 + srow) * ld + skel + goff, dAs + c * 512);
                gll16(dqkvb + qoff + D_ + (size_t)(kc0 + srow) * ld + skel + goff, dBs + c * 512);
            }
        }
        __syncthreads();
        bf16x8 af[4], bfv[4];
#pragma unroll
        for (int i = 0; i < 4; i++) af[i] = *(const bf16x8*)(As + aoff[i]);
#pragma unroll
        for (int j = 0; j < 4; j++) bfv[j] = *(const bf16x8*)(Bs + boff[j]);
        if (!TAN) {
#pragma unroll
            for (int i = 0; i < 4; i++)
#pragma unroll
                for (int j = 0; j < 4; j++)
                    acc[i][j] = __builtin_amdgcn_mfma_f32_16x16x32_bf16(af[i], bfv[j], acc[i][j], 0, 0, 0);
        } else {
            bf16x8 daf[4], dbf[4];
#pragma unroll
            for (int i = 0; i < 4; i++) daf[i] = *(const bf16x8*)(dAs + aoff[i]);
#pragma unroll
            for (int j = 0; j < 4; j++) dbf[j] = *(const bf16x8*)(dBs + boff[j]);
#pragma unroll
            for (int i = 0; i < 4; i++)
#pragma unroll
                for (int j = 0; j < 4; j++) {
                    acc[i][j] = __builtin_amdgcn_mfma_f32_16x16x32_bf16(daf[i], bfv[j], acc[i][j], 0, 0, 0);
                    acc[i][j] = __builtin_amdgcn_mfma_f32_16x16x32_bf16(af[i], dbf[j], acc[i][j], 0, 0, 0);
                }
        }
        __syncthreads();
    }

#pragma unroll
    for (int i = 0; i < 4; i++) {
        int rbase = q0 + wr * 64 + i * 16 + (lane >> 4) * 4;
#pragma unroll
        for (int j = 0; j < 4; j++) {
            int c = kc0 + wc * 64 + j * 16 + (lane & 15);
#pragma unroll
            for (int r = 0; r < 4; r++)
                sc[((size_t)bh * S_ + rbase + r) * S_ + c] = f2bf(acc[i][j][r] * SCALE_);
        }
    }
}

// ---------------- MFMA P@V (BK=32): o[q][d] (TAN: dP@V + P@dV), bf16 out ----------------
template <bool TAN>
__global__ __launch_bounds__(256) void attn_av_mfma(const ushort* __restrict__ Pb,
                                                    const ushort* __restrict__ dPb,
                                                    const ushort* __restrict__ Vt,
                                                    const ushort* __restrict__ dVt,
                                                    ushort* __restrict__ outp) {
    int bh = blockIdx.y;
    int b = bh / H_, hh = bh - b * H_;
    int q0 = blockIdx.x * 128;
    const ushort* Pg = Pb + (size_t)bh * S_ * S_;
    const ushort* Vg = Vt + (size_t)bh * HD_ * S_;
    __shared__ ushort As[128 * 32];
    __shared__ ushort Bs[64 * 32];
    __shared__ ushort dAs[TAN ? 128 * 32 : 1];
    __shared__ ushort dBs[TAN ? 64 * 32 : 1];
    int tid = threadIdx.x;
    int wave = tid >> 6, lane = tid & 63;
    int wr = wave >> 1, wc = wave & 1;

    int srow = (lane >> 2);
    int skel = (lane & 3) * 8;

    int frow = lane & 15, fk = (lane >> 4) * 8;
    int aoff[4], boff[2];
#pragma unroll
    for (int i = 0; i < 4; i++) aoff[i] = (wr * 64 + i * 16 + frow) * 32 + fk;
#pragma unroll
    for (int j = 0; j < 2; j++) boff[j] = (wc * 32 + j * 16 + frow) * 32 + fk;

    f32x4 acc[4][2] = {};

    for (int k0 = 0; k0 < S_; k0 += 32) {
#pragma unroll
        for (int cc = 0; cc < 2; cc++) {
            int c = wave * 2 + cc;
            gll16(Pg + (size_t)(q0 + c * 16 + srow) * S_ + k0 + skel, As + c * 512);
            if (TAN) gll16(dPb + (size_t)bh * S_ * S_ + (size_t)(q0 + c * 16 + srow) * S_ + k0 + skel,
                           dAs + c * 512);
        }
        {
            int c = wave;
            gll16(Vg + (size_t)(c * 16 + srow) * S_ + k0 + skel, Bs + c * 512);
            if (TAN) gll16(dVt + (size_t)bh * HD_ * S_ + (size_t)(c * 16 + srow) * S_ + k0 + skel,
                           dBs + c * 512);
        }
        __syncthreads();
        bf16x8 af[4], bfv[2];
#pragma unroll
        for (int i = 0; i < 4; i++) af[i] = *(const bf16x8*)(As + aoff[i]);
#pragma unroll
        for (int j = 0; j < 2; j++) bfv[j] = *(const bf16x8*)(Bs + boff[j]);
        if (!TAN) {
#pragma unroll
            for (int i = 0; i < 4; i++)
#pragma unroll
                for (int j = 0; j < 2; j++)
                    acc[i][j] = __builtin_amdgcn_mfma_f32_16x16x32_bf16(af[i], bfv[j], acc[i][j], 0, 0, 0);
        } else {
            bf16x8 daf[4], dbf[2];
#pragma unroll
            for (int i = 0; i < 4; i++) daf[i] = *(const bf16x8*)(dAs + aoff[i]);
#pragma unroll
            for (int j = 0; j < 2; j++) dbf[j] = *(const bf16x8*)(dBs + boff[j]);
#pragma unroll
            for (int i = 0; i < 4; i++)
#pragma unroll
                for (int j = 0; j < 2; j++) {
                    acc[i][j] = __builtin_amdgcn_mfma_f32_16x16x32_bf16(daf[i], bfv[j], acc[i][j], 0, 0, 0);
                    acc[i][j] = __builtin_amdgcn_mfma_f32_16x16x32_bf16(af[i], dbf[j], acc[i][j], 0, 0, 0);
                }
        }
        __syncthreads();
    }

#pragma unroll
    for (int i = 0; i < 4; i++) {
        int rbase = q0 + wr * 64 + i * 16 + (lane >> 4) * 4;
#pragma unroll
        for (int j = 0; j < 2; j++) {
            int c = hh * HD_ + wc * 32 + j * 16 + (lane & 15);
#pragma unroll
            for (int r = 0; r < 4; r++)
                outp[(size_t)(b * S_ + rbase + r) * D_ + c] = f2bf(acc[i][j][r]);
        }
    }
}

// ---------------- softmax: bf16 scores -> bf16 probs ----------------
__global__ __launch_bounds__(256) void softmax_rows(const ushort* __restrict__ sc,
                                                    ushort* __restrict__ scb) {
    size_t row = blockIdx.x;
    const ushort* p = sc + row * S_;
    int tid = threadIdx.x;
    ushort2 vu = *(const ushort2*)&p[tid * 2];
    float v0 = bf2f(vu.x), v1 = bf2f(vu.y);
    float mx = block_max(fmaxf(v0, v1));
    float e0 = expf(v0 - mx), e1 = expf(v1 - mx);
    float s = block_sum(e0 + e1);
    float inv = 1.0f / s;
    ushort2 ob; ob.x = f2bf(e0 * inv); ob.y = f2bf(e1 * inv);
    *(ushort2*)&scb[row * S_ + tid * 2] = ob;
}

// ---------------- dattn(bf16) = attn*(dsc - rowsum(attn*dsc)), all bf16 ----------------
__global__ __launch_bounds__(256) void dattn_rows(const ushort* __restrict__ attnb,
                                                  const ushort* __restrict__ dscb,
                                                  ushort* __restrict__ dPb) {
    size_t row = blockIdx.x;
    const ushort* a = attnb + row * S_;
    const ushort* d = dscb + row * S_;
    int tid = threadIdx.x;
    ushort2 au = *(const ushort2*)&a[tid * 2];
    ushort2 du = *(const ushort2*)&d[tid * 2];
    float a0 = bf2f(au.x), a1 = bf2f(au.y);
    float d0 = bf2f(du.x), d1 = bf2f(du.y);
    float s = block_sum(a0 * d0 + a1 * d1);
    ushort2 o;
    o.x = f2bf(a0 * (d0 - s));
    o.y = f2bf(a1 * (d1 - s));
    *(ushort2*)&dPb[row * S_ + tid * 2] = o;
}

// ---------------- host ----------------
extern "C" void kernel_launch(void* const* d_in, const int* in_sizes, int n_in,
                              void* d_out, int out_size, void* d_ws, size_t ws_size,
                              hipStream_t stream) {
    const float* x = (const float*)d_in[0];
    const float* xt = (const float*)d_in[1];
    const float* g1 = (const float*)d_in[2];
    const float* b1 = (const float*)d_in[3];
    const float* Wqkv = (const float*)d_in[4];
    const float* Wproj = (const float*)d_in[5];
    const float* bproj = (const float*)d_in[6];
    const float* g2 = (const float*)d_in[7];
    const float* b2 = (const float*)d_in[8];
    const float* W1 = (const float*)d_in[9];
    const float* bf1 = (const float*)d_in[10];
    const float* W2 = (const float*)d_in[11];
    const float* bf2 = (const float*)d_in[12];
    float* out = (float*)d_out;
    float* out_t = out + BSD_;   // [B,M,S,D]

    char* wp = (char*)d_ws;
    auto alloc = [&](size_t bytes) { void* p = wp; wp += (bytes + 255) & ~(size_t)255; return p; };
    ushort* xhat1 = (ushort*)alloc(BSD_ * 2);
    ushort* hb = (ushort*)alloc(BSD_ * 2);
    ushort* obb = (ushort*)alloc(BSD_ * 2);
    float* x2 = (float*)alloc(BSD_ * 4);
    ushort* xhat2 = (ushort*)alloc(BSD_ * 2);
    ushort* h2b = (ushort*)alloc(BSD_ * 2);
    float* dx2 = (float*)alloc(4 * BSD_ * 4);     // [4*BS][D] f32
    ushort* qkvb = (ushort*)alloc(BS3D_ * 2);
    ushort* Vt = (ushort*)alloc(BSD_ * 2);
    ushort* scb = (ushort*)alloc(ATT_ * 2);       // scores bf16 (primal + per-m tangent)
    ushort* attnb = (ushort*)alloc(ATT_ * 2);     // primal probs bf16
    ushort* dPb = (ushort*)alloc(ATT_ * 2);       // per-m tangent dP bf16
    ushort* ub = (ushort*)alloc(BSF_ * 2);        // pre-activation u bf16
    ushort* dob4 = (ushort*)alloc(4 * BSD_ * 2);  // [4*BS][D] bf16
    float* rstd1 = (float*)alloc(BS_ * 4);
    float* rstd2 = (float*)alloc(BS_ * 4);
    ushort* WqkvT = (ushort*)alloc((size_t)D_ * 3 * D_ * 2);
    ushort* WprojT = (ushort*)alloc((size_t)D_ * D_ * 2);
    ushort* W1T = (ushort*)alloc((size_t)DFF_ * D_ * 2);
    ushort* W2T = (ushort*)alloc((size_t)D_ * DFF_ * 2);
    // Region A (50.3 MB): phase1 {dqkvb4 + dVt4}, phase2 {da4}
    char* regA = (char*)alloc(4 * BSF_ * 2);
    ushort* dqkvb4 = (ushort*)regA;                         // [4][B,S,3D]
    ushort* dVt4 = (ushort*)(regA + 4 * BS3D_ * 2);         // [4][bh][HD][S]
    ushort* da4 = (ushort*)regA;                            // [4*BS][DFF]
    // Region B (12.6 MB): {ab} -> {dh4} -> {dh2_4}
    char* regB = (char*)alloc(4 * BSD_ * 2);
    ushort* ab = (ushort*)regB;                             // [BS][DFF] bf16 (= BSF_*2 bytes = 4*BSD_*2)
    ushort* dh4 = (ushort*)regB;                            // [4*BS][D]
    ushort* dh2_4 = (ushort*)regB;                          // [4*BS][D]

    // ---- weights -> bf16 transposed [N][K] ----
    transpose_f2b<<<dim3(3 * D_ / 32, D_ / 32), 256, 0, stream>>>(Wqkv, WqkvT, D_, 3 * D_);
    transpose_f2b<<<dim3(D_ / 32, D_ / 32), 256, 0, stream>>>(Wproj, WprojT, D_, D_);
    transpose_f2b<<<dim3(DFF_ / 32, D_ / 32), 256, 0, stream>>>(W1, W1T, D_, DFF_);
    transpose_f2b<<<dim3(D_ / 32, DFF_ / 32), 256, 0, stream>>>(W2, W2T, DFF_, D_);

    // ---- primal ----
    ln_fwd<<<BS_, 256, 0, stream>>>(x, g1, b1, xhat1, hb, rstd1);
    gemm_mfma<3, false, false><<<dim3(3 * D_ / 128, BS_ / 128), 256, 0, stream>>>(
        hb, WqkvT, nullptr, nullptr, nullptr, qkvb, nullptr, 3 * D_, D_);
    transpose_v<<<dim3(S_ / 32, HD_ / 32, B_ * H_), 256, 0, stream>>>(qkvb, Vt);
    attn_qk_mfma<false><<<dim3(S_ / 128, S_ / 128, B_ * H_), 256, 0, stream>>>(qkvb, nullptr, scb);
    softmax_rows<<<B_ * H_ * S_, 256, 0, stream>>>(scb, attnb);
    attn_av_mfma<false><<<dim3(S_ / 128, B_ * H_), 256, 0, stream>>>(attnb, nullptr, Vt, nullptr, obb);
    gemm_mfma<0, false, false><<<dim3(D_ / 128, BS_ / 128), 256, 0, stream>>>(
        obb, WprojT, bproj, x, x2, nullptr, nullptr, D_, D_);
    ln_fwd<<<BS_, 256, 0, stream>>>(x2, g2, b2, xhat2, h2b, rstd2);
    gemm_mfma<1, false, false><<<dim3(DFF_ / 128, BS_ / 128), 256, 0, stream>>>(
        h2b, W1T, bf1, nullptr, nullptr, ab, ub, DFF_, D_);
    gemm_mfma<0, false, false><<<dim3(D_ / 128, BS_ / 128), 256, 0, stream>>>(
        ab, W2T, bf2, x2, out, nullptr, nullptr, D_, DFF_);

    // ---- tangents: batched linear stages (M = 4*BS = 8192), per-m attention ----
    ln_jvp<<<4 * BS_, 256, 0, stream>>>(xt, 0, xhat1, rstd1, g1, dh4);
    gemm_mfma<3, false, false><<<dim3(3 * D_ / 128, 4 * BS_ / 128), 256, 0, stream>>>(
        dh4, WqkvT, nullptr, nullptr, nullptr, dqkvb4, nullptr, 3 * D_, D_);
    transpose_v<<<dim3(S_ / 32, HD_ / 32, 4 * B_ * H_), 256, 0, stream>>>(dqkvb4, dVt4);
    for (int m = 0; m < M_; m++) {
        attn_qk_mfma<true><<<dim3(S_ / 128, S_ / 128, B_ * H_), 256, 0, stream>>>(
            qkvb, dqkvb4 + (size_t)m * BS3D_, scb);
        dattn_rows<<<B_ * H_ * S_, 256, 0, stream>>>(attnb, scb, dPb);
        attn_av_mfma<true><<<dim3(S_ / 128, B_ * H_), 256, 0, stream>>>(
            attnb, dPb, Vt, dVt4 + (size_t)m * BSD_, dob4 + (size_t)m * BSD_);
    }
    gemm_mfma<0, true, false><<<dim3(D_ / 128, 4 * BS_ / 128), 256, 0, stream>>>(
        dob4, WprojT, nullptr, xt, dx2, nullptr, nullptr, D_, D_);
    ln_jvp<<<4 * BS_, 256, 0, stream>>>(dx2, 1, xhat2, rstd2, g2, dh2_4);
    gemm_mfma<2, false, false><<<dim3(DFF_ / 128, 4 * BS_ / 128), 256, 0, stream>>>(
        dh2_4, W1T, nullptr, nullptr, nullptr, da4, ub, DFF_, D_);
    gemm_mfma<0, false, true><<<dim3(D_ / 128, 4 * BS_ / 128), 256, 0, stream>>>(
        da4, W2T, nullptr, dx2, out_t, nullptr, nullptr, D_, DFF_);
}

// Round 7
// 685.945 us; speedup vs baseline: 4.9647x; 1.0737x over previous
//
#include <hip/hip_runtime.h>
#include <math.h>

constexpr int B_ = 4, S_ = 512, D_ = 768, H_ = 12, M_ = 4, DFF_ = 3072, HD_ = 64;
constexpr float EPS_ = 1e-6f;
constexpr float SCALE_ = 0.125f;  // HD^-0.5
constexpr int BS_ = B_ * S_;
constexpr long long BSD_ = (long long)BS_ * D_;
constexpr long long BS3D_ = (long long)BS_ * 3 * D_;
constexpr long long ATT_ = (long long)B_ * H_ * S_ * S_;
constexpr long long BSF_ = (long long)BS_ * DFF_;

typedef __attribute__((ext_vector_type(8))) short bf16x8;
typedef __attribute__((ext_vector_type(4))) float f32x4;

__device__ __forceinline__ ushort f2bf(float f) {
    uint32_t u = __float_as_uint(f);
    u += 0x7FFF + ((u >> 16) & 1);
    return (ushort)(u >> 16);
}
__device__ __forceinline__ float bf2f(ushort u) {
    return __uint_as_float((uint32_t)u << 16);
}

__device__ __forceinline__ void gll16(const ushort* g, ushort* l) {
    __builtin_amdgcn_global_load_lds((const __attribute__((address_space(1))) void*)g,
                                     (__attribute__((address_space(3))) void*)l, 16, 0, 0);
}

// XCD-chunked bijective block remap (m204): hw id (round-robin over 8 XCDs)
// -> work id such that each XCD owns a contiguous chunk of the work space.
__device__ __forceinline__ int xcd_swz(int flat, int nwg) {
    int q = nwg >> 3, r = nwg & 7;
    int x = flat & 7, pos = flat >> 3;
    int base = (x < r) ? x * (q + 1) : r * (q + 1) + (x - r) * q;
    return base + pos;
}

// batched-row (rg in [0,8192)) -> [B,M,S,Nc] offset
__device__ __forceinline__ size_t stroff(int rg, int c, int Nc) {
    int m = rg >> 11;
    int b = (rg >> 9) & (B_ - 1);
    int s = rg & (S_ - 1);
    return ((size_t)((b * M_ + m) * S_ + s)) * Nc + c;
}

// ---------------- block reductions (256 threads = 4 waves) ----------------
__device__ __forceinline__ float block_sum(float v) {
    __shared__ float red[4];
    int tid = threadIdx.x;
#pragma unroll
    for (int off = 32; off > 0; off >>= 1) v += __shfl_down(v, off, 64);
    __syncthreads();
    if ((tid & 63) == 0) red[tid >> 6] = v;
    __syncthreads();
    return red[0] + red[1] + red[2] + red[3];
}

__device__ __forceinline__ float block_max(float v) {
    __shared__ float red[4];
    int tid = threadIdx.x;
#pragma unroll
    for (int off = 32; off > 0; off >>= 1) v = fmaxf(v, __shfl_down(v, off, 64));
    __syncthreads();
    if ((tid & 63) == 0) red[tid >> 6] = v;
    __syncthreads();
    return fmaxf(fmaxf(red[0], red[1]), fmaxf(red[2], red[3]));
}

// ---------------- weight transpose+convert: W[K][N] f32 -> WT[N][K] bf16 ----------------
__global__ __launch_bounds__(256) void transpose_f2b(const float* __restrict__ W,
                                                     ushort* __restrict__ WT,
                                                     int K, int N) {
    __shared__ float t[32][33];
    int n0 = blockIdx.x * 32, k0 = blockIdx.y * 32;
    int tx = threadIdx.x & 31, ty = threadIdx.x >> 5;
#pragma unroll
    for (int i = 0; i < 4; i++)
        t[ty + i * 8][tx] = W[(size_t)(k0 + ty + i * 8) * N + n0 + tx];
    __syncthreads();
#pragma unroll
    for (int i = 0; i < 4; i++)
        WT[(size_t)(n0 + ty + i * 8) * K + k0 + tx] = f2bf(t[tx][ty + i * 8]);
}

// ---------------- V transpose: src[m][B,S,3D] bf16 -> dst[m][bh][HD][S] bf16 ----------------
__global__ __launch_bounds__(256) void transpose_v(const ushort* __restrict__ src0,
                                                   ushort* __restrict__ dst0) {
    int z = blockIdx.z;
    int m = z / (B_ * H_), bh = z % (B_ * H_);
    const ushort* qkvb = src0 + (size_t)m * BS3D_;
    ushort* Vt = dst0 + (size_t)m * BSD_;
    int b = bh / H_, hh = bh - b * H_;
    int s0 = blockIdx.x * 32, d0 = blockIdx.y * 32;
    __shared__ ushort t[32][33];
    int tx = threadIdx.x & 31, ty = threadIdx.x >> 5;
#pragma unroll
    for (int i = 0; i < 4; i++)
        t[ty + i * 8][tx] = qkvb[(size_t)(b * S_ + s0 + ty + i * 8) * 3 * D_ + 2 * D_ + hh * HD_ + d0 + tx];
    __syncthreads();
#pragma unroll
    for (int i = 0; i < 4; i++)
        Vt[(size_t)bh * HD_ * S_ + (size_t)(d0 + ty + i * 8) * S_ + s0 + tx] = t[tx][ty + i * 8];
}

// ---------------- LayerNorm forward: xhat bf16, h bf16 ----------------
__global__ __launch_bounds__(256) void ln_fwd(const float* __restrict__ x,
                                              const float* __restrict__ g,
                                              const float* __restrict__ bta,
                                              ushort* __restrict__ xhat,
                                              ushort* __restrict__ h,
                                              float* __restrict__ rstd) {
    int row = blockIdx.x;
    const float* xr = x + (size_t)row * D_;
    int tid = threadIdx.x;
    float v[3];
    float s = 0.f;
#pragma unroll
    for (int i = 0; i < 3; i++) { v[i] = xr[tid + i * 256]; s += v[i]; }
    s = block_sum(s);
    float mu = s * (1.0f / D_);
    float vs = 0.f;
#pragma unroll
    for (int i = 0; i < 3; i++) { float c = v[i] - mu; vs += c * c; }
    vs = block_sum(vs);
    float rs = rsqrtf(vs * (1.0f / D_) + EPS_);
#pragma unroll
    for (int i = 0; i < 3; i++) {
        int c = tid + i * 256;
        float xh = (v[i] - mu) * rs;
        xhat[(size_t)row * D_ + c] = f2bf(xh);
        h[(size_t)row * D_ + c] = f2bf(xh * g[c] + bta[c]);
    }
    if (tid == 0) rstd[row] = rs;
}

// ---------------- batched LayerNorm JVP: grid 4*BS_ rows ----------------
// mode 0: t = x_tangent [B,M,S,D] (strided per rg); mode 1: t contiguous [4*BS][D]
__global__ __launch_bounds__(256) void ln_jvp(const float* __restrict__ t, int mode,
                                              const ushort* __restrict__ xhat,
                                              const float* __restrict__ rstd,
                                              const float* __restrict__ g,
                                              ushort* __restrict__ dh) {
    int rg = blockIdx.x;
    int r = rg & (BS_ - 1);
    size_t tbase;
    if (mode == 0) {
        int m = rg >> 11;
        int b = r >> 9, s = r & (S_ - 1);
        tbase = ((size_t)((b * M_ + m) * S_ + s)) * D_;
    } else {
        tbase = (size_t)rg * D_;
    }
    size_t pbase = (size_t)r * D_;
    int tid = threadIdx.x;
    float tv[3], xh[3];
    float s1 = 0.f, s2 = 0.f;
#pragma unroll
    for (int i = 0; i < 3; i++) {
        int c = tid + i * 256;
        tv[i] = t[tbase + c];
        xh[i] = bf2f(xhat[pbase + c]);
        s1 += tv[i];
        s2 += tv[i] * xh[i];
    }
    s1 = block_sum(s1);
    s2 = block_sum(s2);
    float mt = s1 * (1.0f / D_);
    float mx = s2 * (1.0f / D_);
    float rs = rstd[r];
#pragma unroll
    for (int i = 0; i < 3; i++) {
        int c = tid + i * 256;
        dh[(size_t)rg * D_ + c] = f2bf(g[c] * rs * (tv[i] - mt - xh[i] * mx));
    }
}

// ---------------- bf16 MFMA GEMM, BK=64, XOR-swizzled LDS, XCD-chunked blocks ----------------
// C[M,N] = A[M,K] @ BT[N,K]^T ; 128x128 tile, 4 waves, 32 MFMA/K-step.
// EPI 0: Cf[out] = acc + bias? + res?    (RS: res strided-m, OS: out strided-m)
// EPI 1: u = acc+bias; Cb = bf16(gelu(u)); aux = bf16(gelu'(u))
// EPI 2: Cb = bf16(acc * bf2f(aux[primal row]))
// EPI 3: Cb = bf16(acc)
template <int EPI, bool RS, bool OS>
__global__ __launch_bounds__(256) void gemm_mfma(const ushort* __restrict__ A,
                                                 const ushort* __restrict__ BT,
                                                 const float* __restrict__ bias,
                                                 const float* __restrict__ res,
                                                 float* __restrict__ Cf,
                                                 ushort* __restrict__ Cb,
                                                 ushort* __restrict__ aux,
                                                 int Nc, int Kd) {
    __shared__ ushort As[128 * 64];  // [row][k], rows 128B; content pre-swizzled
    __shared__ ushort Bs[128 * 64];
    int tid = threadIdx.x;
    int wave = tid >> 6, lane = tid & 63;
    int wr = wave >> 1, wc = wave & 1;
    // XCD-chunked remap: each XCD owns a contiguous range of row-panels (A-reuse in L2)
    int gx = gridDim.x, nwg = gx * gridDim.y;
    int work = xcd_swz(blockIdx.x + blockIdx.y * gx, nwg);
    int row0 = (work / gx) * 128, col0 = (work % gx) * 128;

    // staging: chunk c covers rows c*8..c*8+7 (1024B); lane l -> row c*8+(l>>3).
    // global k-offset pre-swizzled ((l&7)^(l>>3))*8 so LDS[r][kb] = G[r][kb ^ ((r&7)<<3)]
    int srow = lane >> 3;
    int skel = ((lane & 7) ^ (lane >> 3)) * 8;
    const ushort* Ag0 = A + (size_t)(row0 + srow) * Kd + skel;
    const ushort* Bg0 = BT + (size_t)(col0 + srow) * Kd + skel;

    // fragment read offsets: linear elem (fkb+ks*32) -> swizzled ^((row&7)*8)
    int frow = lane & 15, fkb = (lane >> 4) * 8;
    int aoff[2][4], boff[2][4];
#pragma unroll
    for (int ks = 0; ks < 2; ks++)
#pragma unroll
        for (int i = 0; i < 4; i++) {
            int sw = (fkb + ks * 32) ^ ((frow & 7) * 8);
            aoff[ks][i] = (wr * 64 + i * 16 + frow) * 64 + sw;
            boff[ks][i] = (wc * 64 + i * 16 + frow) * 64 + sw;
        }

    f32x4 acc[4][4] = {};

    for (int k0 = 0; k0 < Kd; k0 += 64) {
#pragma unroll
        for (int cc = 0; cc < 4; cc++) {
            int c = wave * 4 + cc;
            gll16(Ag0 + (size_t)(c * 8) * Kd + k0, As + c * 512);
            gll16(Bg0 + (size_t)(c * 8) * Kd + k0, Bs + c * 512);
        }
        __syncthreads();
        bf16x8 af[2][4], bfv[2][4];
#pragma unroll
        for (int ks = 0; ks < 2; ks++)
#pragma unroll
            for (int i = 0; i < 4; i++) {
                af[ks][i] = *(const bf16x8*)(As + aoff[ks][i]);
                bfv[ks][i] = *(const bf16x8*)(Bs + boff[ks][i]);
            }
#pragma unroll
        for (int ks = 0; ks < 2; ks++)
#pragma unroll
            for (int i = 0; i < 4; i++)
#pragma unroll
                for (int j = 0; j < 4; j++)
                    acc[i][j] = __builtin_amdgcn_mfma_f32_16x16x32_bf16(af[ks][i], bfv[ks][j], acc[i][j], 0, 0, 0);
        __syncthreads();
    }

    // C/D layout: col = lane&15, row = (lane>>4)*4 + reg
#pragma unroll
    for (int i = 0; i < 4; i++) {
        int rbase = row0 + wr * 64 + i * 16 + (lane >> 4) * 4;
#pragma unroll
        for (int j = 0; j < 4; j++) {
            int c = col0 + wc * 64 + j * 16 + (lane & 15);
#pragma unroll
            for (int r = 0; r < 4; r++) {
                int rg = rbase + r;
                size_t off = (size_t)rg * Nc + c;
                float v = acc[i][j][r];
                if (EPI == 0) {
                    if (bias) v += bias[c];
                    if (res) v += res[RS ? stroff(rg, c, Nc) : off];
                    if (OS) Cf[stroff(rg, c, Nc)] = v; else Cf[off] = v;
                } else if (EPI == 1) {
                    v += bias[c];
                    float cdf = 0.5f * (1.0f + erff(v * 0.70710678118654752f));
                    Cb[off] = f2bf(v * cdf);
                    aux[off] = f2bf(cdf + v * 0.39894228040143267f * expf(-0.5f * v * v));
                } else if (EPI == 2) {
                    Cb[off] = f2bf(v * bf2f(aux[(size_t)(rg & (BS_ - 1)) * Nc + c]));
                } else {
                    Cb[off] = f2bf(v);
                }
            }
        }
    }
}

// ---------------- MFMA QK^T (BK=32): scb bf16 = scale*(Q.K)  (TAN: dQ.K + Q.dK) ----------------
// 1D grid: work = bh*16 + qy*4 + kx, XCD-chunked (each XCD owns whole bh slices)
template <bool TAN>
__global__ __launch_bounds__(256) void attn_qk_mfma(const ushort* __restrict__ qkvb,
                                                    const ushort* __restrict__ dqkvb,
                                                    ushort* __restrict__ sc) {
    int work = xcd_swz(blockIdx.x, gridDim.x);
    constexpr int NT = S_ / 128;  // 4
    int bh = work / (NT * NT);
    int rem = work % (NT * NT);
    int q0 = (rem / NT) * 128, kc0 = (rem % NT) * 128;
    int b = bh / H_, hh = bh - b * H_;
    const size_t qoff = (size_t)b * S_ * 3 * D_ + hh * HD_;
    const ushort* Q = qkvb + qoff;
    const ushort* Kp = qkvb + qoff + D_;
    __shared__ ushort As[128 * 32];
    __shared__ ushort Bs[128 * 32];
    __shared__ ushort dAs[TAN ? 128 * 32 : 1];
    __shared__ ushort dBs[TAN ? 128 * 32 : 1];
    int tid = threadIdx.x;
    int wave = tid >> 6, lane = tid & 63;
    int wr = wave >> 1, wc = wave & 1;
    const int ld = 3 * D_;

    int srow = (lane >> 2);
    int skel = (lane & 3) * 8;
    const ushort* Ag0 = Q + (size_t)(q0 + srow) * ld + skel;
    const ushort* Bg0 = Kp + (size_t)(kc0 + srow) * ld + skel;

    int frow = lane & 15, fk = (lane >> 4) * 8;
    int aoff[4], boff[4];
#pragma unroll
    for (int i = 0; i < 4; i++) {
        aoff[i] = (wr * 64 + i * 16 + frow) * 32 + fk;
        boff[i] = (wc * 64 + i * 16 + frow) * 32 + fk;
    }

    f32x4 acc[4][4] = {};

    for (int k0 = 0; k0 < HD_; k0 += 32) {
#pragma unroll
        for (int cc = 0; cc < 2; cc++) {
            int c = wave * 2 + cc;
            size_t goff = (size_t)(c * 16) * ld + k0;
            gll16(Ag0 + goff, As + c * 512);
            gll16(Bg0 + goff, Bs + c * 512);
            if (TAN) {
                gll16(dqkvb + qoff + (size_t)(q0 + srow) * ld + skel + goff, dAs + c * 512);
                gll16(dqkvb + qoff + D_ + (size_t)(kc0 + srow) * ld + skel + goff, dBs + c * 512);
            }
        }
        __syncthreads();
        bf16x8 af[4], bfv[4];
#pragma unroll
        for (int i = 0; i < 4; i++) af[i] = *(const bf16x8*)(As + aoff[i]);
#pragma unroll
        for (int j = 0; j < 4; j++) bfv[j] = *(const bf16x8*)(Bs + boff[j]);
        if (!TAN) {
#pragma unroll
            for (int i = 0; i < 4; i++)
#pragma unroll
                for (int j = 0; j < 4; j++)
                    acc[i][j] = __builtin_amdgcn_mfma_f32_16x16x32_bf16(af[i], bfv[j], acc[i][j], 0, 0, 0);
        } else {
            bf16x8 daf[4], dbf[4];
#pragma unroll
            for (int i = 0; i < 4; i++) daf[i] = *(const bf16x8*)(dAs + aoff[i]);
#pragma unroll
            for (int j = 0; j < 4; j++) dbf[j] = *(const bf16x8*)(dBs + boff[j]);
#pragma unroll
            for (int i = 0; i < 4; i++)
#pragma unroll
                for (int j = 0; j < 4; j++) {
                    acc[i][j] = __builtin_amdgcn_mfma_f32_16x16x32_bf16(daf[i], bfv[j], acc[i][j], 0, 0, 0);
                    acc[i][j] = __builtin_amdgcn_mfma_f32_16x16x32_bf16(af[i], dbf[j], acc[i][j], 0, 0, 0);
                }
        }
        __syncthreads();
    }

#pragma unroll
    for (int i = 0; i < 4; i++) {
        int rbase = q0 + wr * 64 + i * 16 + (lane >> 4) * 4;
#pragma unroll
        for (int j = 0; j < 4; j++) {
            int c = kc0 + wc * 64 + j * 16 + (lane & 15);
#pragma unroll
            for (int r = 0; r < 4; r++)
                sc[((size_t)bh * S_ + rbase + r) * S_ + c] = f2bf(acc[i][j][r] * SCALE_);
        }
    }
}

// ---------------- MFMA P@V (BK=32): o[q][d] (TAN: dP@V + P@dV), bf16 out ----------------
// 1D grid: work = bh*NT + qx, XCD-chunked
template <bool TAN>
__global__ __launch_bounds__(256) void attn_av_mfma(const ushort* __restrict__ Pb,
                                                    const ushort* __restrict__ dPb,
                                                    const ushort* __restrict__ Vt,
                                                    const ushort* __restrict__ dVt,
                                                    ushort* __restrict__ outp) {
    int work = xcd_swz(blockIdx.x, gridDim.x);
    constexpr int NT = S_ / 128;  // 4
    int bh = work / NT;
    int q0 = (work % NT) * 128;
    int b = bh / H_, hh = bh - b * H_;
    const ushort* Pg = Pb + (size_t)bh * S_ * S_;
    const ushort* Vg = Vt + (size_t)bh * HD_ * S_;
    __shared__ ushort As[128 * 32];
    __shared__ ushort Bs[64 * 32];
    __shared__ ushort dAs[TAN ? 128 * 32 : 1];
    __shared__ ushort dBs[TAN ? 64 * 32 : 1];
    int tid = threadIdx.x;
    int wave = tid >> 6, lane = tid & 63;
    int wr = wave >> 1, wc = wave & 1;

    int srow = (lane >> 2);
    int skel = (lane & 3) * 8;

    int frow = lane & 15, fk = (lane >> 4) * 8;
    int aoff[4], boff[2];
#pragma unroll
    for (int i = 0; i < 4; i++) aoff[i] = (wr * 64 + i * 16 + frow) * 32 + fk;
#pragma unroll
    for (int j = 0; j < 2; j++) boff[j] = (wc * 32 + j * 16 + frow) * 32 + fk;

    f32x4 acc[4][2] = {};

    for (int k0 = 0; k0 < S_; k0 += 32) {
#pragma unroll
        for (int cc = 0; cc < 2; cc++) {
            int c = wave * 2 + cc;
            gll16(Pg + (size_t)(q0 + c * 16 + srow) * S_ + k0 + skel, As + c * 512);
            if (TAN) gll16(dPb + (size_t)bh * S_ * S_ + (size_t)(q0 + c * 16 + srow) * S_ + k0 + skel,
                           dAs + c * 512);
        }
        {
            int c = wave;
            gll16(Vg + (size_t)(c * 16 + srow) * S_ + k0 + skel, Bs + c * 512);
            if (TAN) gll16(dVt + (size_t)bh * HD_ * S_ + (size_t)(c * 16 + srow) * S_ + k0 + skel,
                           dBs + c * 512);
        }
        __syncthreads();
        bf16x8 af[4], bfv[2];
#pragma unroll
        for (int i = 0; i < 4; i++) af[i] = *(const bf16x8*)(As + aoff[i]);
#pragma unroll
        for (int j = 0; j < 2; j++) bfv[j] = *(const bf16x8*)(Bs + boff[j]);
        if (!TAN) {
#pragma unroll
            for (int i = 0; i < 4; i++)
#pragma unroll
                for (int j = 0; j < 2; j++)
                    acc[i][j] = __builtin_amdgcn_mfma_f32_16x16x32_bf16(af[i], bfv[j], acc[i][j], 0, 0, 0);
        } else {
            bf16x8 daf[4], dbf[2];
#pragma unroll
            for (int i = 0; i < 4; i++) daf[i] = *(const bf16x8*)(dAs + aoff[i]);
#pragma unroll
            for (int j = 0; j < 2; j++) dbf[j] = *(const bf16x8*)(dBs + boff[j]);
#pragma unroll
            for (int i = 0; i < 4; i++)
#pragma unroll
                for (int j = 0; j < 2; j++) {
                    acc[i][j] = __builtin_amdgcn_mfma_f32_16x16x32_bf16(daf[i], bfv[j], acc[i][j], 0, 0, 0);
                    acc[i][j] = __builtin_amdgcn_mfma_f32_16x16x32_bf16(af[i], dbf[j], acc[i][j], 0, 0, 0);
                }
        }
        __syncthreads();
    }

#pragma unroll
    for (int i = 0; i < 4; i++) {
        int rbase = q0 + wr * 64 + i * 16 + (lane >> 4) * 4;
#pragma unroll
        for (int j = 0; j < 2; j++) {
            int c = hh * HD_ + wc * 32 + j * 16 + (lane & 15);
#pragma unroll
            for (int r = 0; r < 4; r++)
                outp[(size_t)(b * S_ + rbase + r) * D_ + c] = f2bf(acc[i][j][r]);
        }
    }
}

// ---------------- softmax: bf16 scores -> bf16 probs ----------------
__global__ __launch_bounds__(256) void softmax_rows(const ushort* __restrict__ sc,
                                                    ushort* __restrict__ scb) {
    size_t row = blockIdx.x;
    const ushort* p = sc + row * S_;
    int tid = threadIdx.x;
    ushort2 vu = *(const ushort2*)&p[tid * 2];
    float v0 = bf2f(vu.x), v1 = bf2f(vu.y);
    float mx = block_max(fmaxf(v0, v1));
    float e0 = expf(v0 - mx), e1 = expf(v1 - mx);
    float s = block_sum(e0 + e1);
    float inv = 1.0f / s;
    ushort2 ob; ob.x = f2bf(e0 * inv); ob.y = f2bf(e1 * inv);
    *(ushort2*)&scb[row * S_ + tid * 2] = ob;
}

// ---------------- dattn(bf16) = attn*(dsc - rowsum(attn*dsc)), all bf16 ----------------
__global__ __launch_bounds__(256) void dattn_rows(const ushort* __restrict__ attnb,
                                                  const ushort* __restrict__ dscb,
                                                  ushort* __restrict__ dPb) {
    size_t row = blockIdx.x;
    const ushort* a = attnb + row * S_;
    const ushort* d = dscb + row * S_;
    int tid = threadIdx.x;
    ushort2 au = *(const ushort2*)&a[tid * 2];
    ushort2 du = *(const ushort2*)&d[tid * 2];
    float a0 = bf2f(au.x), a1 = bf2f(au.y);
    float d0 = bf2f(du.x), d1 = bf2f(du.y);
    float s = block_sum(a0 * d0 + a1 * d1);
    ushort2 o;
    o.x = f2bf(a0 * (d0 - s));
    o.y = f2bf(a1 * (d1 - s));
    *(ushort2*)&dPb[row * S_ + tid * 2] = o;
}

// ---------------- host ----------------
extern "C" void kernel_launch(void* const* d_in, const int* in_sizes, int n_in,
                              void* d_out, int out_size, void* d_ws, size_t ws_size,
                              hipStream_t stream) {
    const float* x = (const float*)d_in[0];
    const float* xt = (const float*)d_in[1];
    const float* g1 = (const float*)d_in[2];
    const float* b1 = (const float*)d_in[3];
    const float* Wqkv = (const float*)d_in[4];
    const float* Wproj = (const float*)d_in[5];
    const float* bproj = (const float*)d_in[6];
    const float* g2 = (const float*)d_in[7];
    const float* b2 = (const float*)d_in[8];
    const float* W1 = (const float*)d_in[9];
    const float* bf1 = (const float*)d_in[10];
    const float* W2 = (const float*)d_in[11];
    const float* bf2 = (const float*)d_in[12];
    float* out = (float*)d_out;
    float* out_t = out + BSD_;   // [B,M,S,D]

    char* wp = (char*)d_ws;
    auto alloc = [&](size_t bytes) { void* p = wp; wp += (bytes + 255) & ~(size_t)255; return p; };
    ushort* xhat1 = (ushort*)alloc(BSD_ * 2);
    ushort* hb = (ushort*)alloc(BSD_ * 2);
    ushort* obb = (ushort*)alloc(BSD_ * 2);
    float* x2 = (float*)alloc(BSD_ * 4);
    ushort* xhat2 = (ushort*)alloc(BSD_ * 2);
    ushort* h2b = (ushort*)alloc(BSD_ * 2);
    float* dx2 = (float*)alloc(4 * BSD_ * 4);     // [4*BS][D] f32
    ushort* qkvb = (ushort*)alloc(BS3D_ * 2);
    ushort* Vt = (ushort*)alloc(BSD_ * 2);
    ushort* scb = (ushort*)alloc(ATT_ * 2);       // scores bf16 (primal + per-m tangent)
    ushort* attnb = (ushort*)alloc(ATT_ * 2);     // primal probs bf16
    ushort* dPb = (ushort*)alloc(ATT_ * 2);       // per-m tangent dP bf16
    ushort* gpb = (ushort*)alloc(BSF_ * 2);       // gelu'(u) bf16
    ushort* dob4 = (ushort*)alloc(4 * BSD_ * 2);  // [4*BS][D] bf16
    float* rstd1 = (float*)alloc(BS_ * 4);
    float* rstd2 = (float*)alloc(BS_ * 4);
    ushort* WqkvT = (ushort*)alloc((size_t)D_ * 3 * D_ * 2);
    ushort* WprojT = (ushort*)alloc((size_t)D_ * D_ * 2);
    ushort* W1T = (ushort*)alloc((size_t)DFF_ * D_ * 2);
    ushort* W2T = (ushort*)alloc((size_t)D_ * DFF_ * 2);
    // Region A (50.3 MB): phase1 {dqkvb4 + dVt4}, phase2 {da4}
    char* regA = (char*)alloc(4 * BSF_ * 2);
    ushort* dqkvb4 = (ushort*)regA;                         // [4][B,S,3D]
    ushort* dVt4 = (ushort*)(regA + 4 * BS3D_ * 2);         // [4][bh][HD][S]
    ushort* da4 = (ushort*)regA;                            // [4*BS][DFF]
    // Region B (12.6 MB): {ab} -> {dh4} -> {dh2_4}
    char* regB = (char*)alloc(4 * BSD_ * 2);
    ushort* ab = (ushort*)regB;                             // [BS][DFF] bf16
    ushort* dh4 = (ushort*)regB;                            // [4*BS][D]
    ushort* dh2_4 = (ushort*)regB;                          // [4*BS][D]

    // ---- weights -> bf16 transposed [N][K] ----
    transpose_f2b<<<dim3(3 * D_ / 32, D_ / 32), 256, 0, stream>>>(Wqkv, WqkvT, D_, 3 * D_);
    transpose_f2b<<<dim3(D_ / 32, D_ / 32), 256, 0, stream>>>(Wproj, WprojT, D_, D_);
    transpose_f2b<<<dim3(DFF_ / 32, D_ / 32), 256, 0, stream>>>(W1, W1T, D_, DFF_);
    transpose_f2b<<<dim3(D_ / 32, DFF_ / 32), 256, 0, stream>>>(W2, W2T, DFF_, D_);

    // ---- primal ----
    ln_fwd<<<BS_, 256, 0, stream>>>(x, g1, b1, xhat1, hb, rstd1);
    gemm_mfma<3, false, false><<<dim3(3 * D_ / 128, BS_ / 128), 256, 0, stream>>>(
        hb, WqkvT, nullptr, nullptr, nullptr, qkvb, nullptr, 3 * D_, D_);
    transpose_v<<<dim3(S_ / 32, HD_ / 32, B_ * H_), 256, 0, stream>>>(qkvb, Vt);
    attn_qk_mfma<false><<<(S_ / 128) * (S_ / 128) * B_ * H_, 256, 0, stream>>>(qkvb, nullptr, scb);
    softmax_rows<<<B_ * H_ * S_, 256, 0, stream>>>(scb, attnb);
    attn_av_mfma<false><<<(S_ / 128) * B_ * H_, 256, 0, stream>>>(attnb, nullptr, Vt, nullptr, obb);
    gemm_mfma<0, false, false><<<dim3(D_ / 128, BS_ / 128), 256, 0, stream>>>(
        obb, WprojT, bproj, x, x2, nullptr, nullptr, D_, D_);
    ln_fwd<<<BS_, 256, 0, stream>>>(x2, g2, b2, xhat2, h2b, rstd2);
    gemm_mfma<1, false, false><<<dim3(DFF_ / 128, BS_ / 128), 256, 0, stream>>>(
        h2b, W1T, bf1, nullptr, nullptr, ab, gpb, DFF_, D_);
    gemm_mfma<0, false, false><<<dim3(D_ / 128, BS_ / 128), 256, 0, stream>>>(
        ab, W2T, bf2, x2, out, nullptr, nullptr, D_, DFF_);

    // ---- tangents: batched linear stages (M = 4*BS = 8192), per-m attention ----
    ln_jvp<<<4 * BS_, 256, 0, stream>>>(xt, 0, xhat1, rstd1, g1, dh4);
    gemm_mfma<3, false, false><<<dim3(3 * D_ / 128, 4 * BS_ / 128), 256, 0, stream>>>(
        dh4, WqkvT, nullptr, nullptr, nullptr, dqkvb4, nullptr, 3 * D_, D_);
    transpose_v<<<dim3(S_ / 32, HD_ / 32, 4 * B_ * H_), 256, 0, stream>>>(dqkvb4, dVt4);
    for (int m = 0; m < M_; m++) {
        attn_qk_mfma<true><<<(S_ / 128) * (S_ / 128) * B_ * H_, 256, 0, stream>>>(
            qkvb, dqkvb4 + (size_t)m * BS3D_, scb);
        dattn_rows<<<B_ * H_ * S_, 256, 0, stream>>>(attnb, scb, dPb);
        attn_av_mfma<true><<<(S_ / 128) * B_ * H_, 256, 0, stream>>>(
            attnb, dPb, Vt, dVt4 + (size_t)m * BSD_, dob4 + (size_t)m * BSD_);
    }
    gemm_mfma<0, true, false><<<dim3(D_ / 128, 4 * BS_ / 128), 256, 0, stream>>>(
        dob4, WprojT, nullptr, xt, dx2, nullptr, nullptr, D_, D_);
    ln_jvp<<<4 * BS_, 256, 0, stream>>>(dx2, 1, xhat2, rstd2, g2, dh2_4);
    gemm_mfma<2, false, false><<<dim3(DFF_ / 128, 4 * BS_ / 128), 256, 0, stream>>>(
        dh2_4, W1T, nullptr, nullptr, nullptr, da4, gpb, DFF_, D_);
    gemm_mfma<0, false, true><<<dim3(D_ / 128, 4 * BS_ / 128), 256, 0, stream>>>(
        da4, W2T, nullptr, dx2, out_t, nullptr, nullptr, D_, DFF_);
}

// Round 8
// 545.708 us; speedup vs baseline: 6.2405x; 1.2570x over previous
//
#include <hip/hip_runtime.h>
#include <math.h>

constexpr int B_ = 4, S_ = 512, D_ = 768, H_ = 12, M_ = 4, DFF_ = 3072, HD_ = 64;
constexpr float EPS_ = 1e-6f;
constexpr float SCALE_ = 0.125f;  // HD^-0.5
constexpr int BS_ = B_ * S_;
constexpr int BH_ = B_ * H_;
constexpr long long BSD_ = (long long)BS_ * D_;
constexpr long long BS3D_ = (long long)BS_ * 3 * D_;
constexpr long long ATT_ = (long long)BH_ * S_ * S_;
constexpr long long BSF_ = (long long)BS_ * DFF_;

typedef __attribute__((ext_vector_type(8))) short bf16x8;
typedef __attribute__((ext_vector_type(4))) float f32x4;

__device__ __forceinline__ ushort f2bf(float f) {
    uint32_t u = __float_as_uint(f);
    u += 0x7FFF + ((u >> 16) & 1);
    return (ushort)(u >> 16);
}
__device__ __forceinline__ float bf2f(ushort u) {
    return __uint_as_float((uint32_t)u << 16);
}

__device__ __forceinline__ void gll16(const ushort* g, ushort* l) {
    __builtin_amdgcn_global_load_lds((const __attribute__((address_space(1))) void*)g,
                                     (__attribute__((address_space(3))) void*)l, 16, 0, 0);
}

// XCD-chunked bijective block remap (m204)
__device__ __forceinline__ int xcd_swz(int flat, int nwg) {
    int q = nwg >> 3, r = nwg & 7;
    int x = flat & 7, pos = flat >> 3;
    int base = (x < r) ? x * (q + 1) : r * (q + 1) + (x - r) * q;
    return base + pos;
}

// batched-row (rg in [0,8192)) -> [B,M,S,Nc] offset
__device__ __forceinline__ size_t stroff(int rg, int c, int Nc) {
    int m = rg >> 11;
    int b = (rg >> 9) & (B_ - 1);
    int s = rg & (S_ - 1);
    return ((size_t)((b * M_ + m) * S_ + s)) * Nc + c;
}

// ---------------- block reductions (256 threads = 4 waves) ----------------
__device__ __forceinline__ float block_sum(float v) {
    __shared__ float red[4];
    int tid = threadIdx.x;
#pragma unroll
    for (int off = 32; off > 0; off >>= 1) v += __shfl_down(v, off, 64);
    __syncthreads();
    if ((tid & 63) == 0) red[tid >> 6] = v;
    __syncthreads();
    return red[0] + red[1] + red[2] + red[3];
}

__device__ __forceinline__ float block_max(float v) {
    __shared__ float red[4];
    int tid = threadIdx.x;
#pragma unroll
    for (int off = 32; off > 0; off >>= 1) v = fmaxf(v, __shfl_down(v, off, 64));
    __syncthreads();
    if ((tid & 63) == 0) red[tid >> 6] = v;
    __syncthreads();
    return fmaxf(fmaxf(red[0], red[1]), fmaxf(red[2], red[3]));
}

// ---------------- weight transpose+convert: W[K][N] f32 -> WT[N][K] bf16 ----------------
__global__ __launch_bounds__(256) void transpose_f2b(const float* __restrict__ W,
                                                     ushort* __restrict__ WT,
                                                     int K, int N) {
    __shared__ float t[32][33];
    int n0 = blockIdx.x * 32, k0 = blockIdx.y * 32;
    int tx = threadIdx.x & 31, ty = threadIdx.x >> 5;
#pragma unroll
    for (int i = 0; i < 4; i++)
        t[ty + i * 8][tx] = W[(size_t)(k0 + ty + i * 8) * N + n0 + tx];
    __syncthreads();
#pragma unroll
    for (int i = 0; i < 4; i++)
        WT[(size_t)(n0 + ty + i * 8) * K + k0 + tx] = f2bf(t[tx][ty + i * 8]);
}

// ---------------- V transpose: src[m][B,S,3D] bf16 -> dst[m][bh][HD][S] bf16 ----------------
__global__ __launch_bounds__(256) void transpose_v(const ushort* __restrict__ src0,
                                                   ushort* __restrict__ dst0) {
    int z = blockIdx.z;
    int m = z / BH_, bh = z % BH_;
    const ushort* qkvb = src0 + (size_t)m * BS3D_;
    ushort* Vt = dst0 + (size_t)m * BSD_;
    int b = bh / H_, hh = bh - b * H_;
    int s0 = blockIdx.x * 32, d0 = blockIdx.y * 32;
    __shared__ ushort t[32][33];
    int tx = threadIdx.x & 31, ty = threadIdx.x >> 5;
#pragma unroll
    for (int i = 0; i < 4; i++)
        t[ty + i * 8][tx] = qkvb[(size_t)(b * S_ + s0 + ty + i * 8) * 3 * D_ + 2 * D_ + hh * HD_ + d0 + tx];
    __syncthreads();
#pragma unroll
    for (int i = 0; i < 4; i++)
        Vt[(size_t)bh * HD_ * S_ + (size_t)(d0 + ty + i * 8) * S_ + s0 + tx] = t[tx][ty + i * 8];
}

// ---------------- LayerNorm forward: xhat bf16, h bf16 ----------------
__global__ __launch_bounds__(256) void ln_fwd(const float* __restrict__ x,
                                              const float* __restrict__ g,
                                              const float* __restrict__ bta,
                                              ushort* __restrict__ xhat,
                                              ushort* __restrict__ h,
                                              float* __restrict__ rstd) {
    int row = blockIdx.x;
    const float* xr = x + (size_t)row * D_;
    int tid = threadIdx.x;
    float v[3];
    float s = 0.f;
#pragma unroll
    for (int i = 0; i < 3; i++) { v[i] = xr[tid + i * 256]; s += v[i]; }
    s = block_sum(s);
    float mu = s * (1.0f / D_);
    float vs = 0.f;
#pragma unroll
    for (int i = 0; i < 3; i++) { float c = v[i] - mu; vs += c * c; }
    vs = block_sum(vs);
    float rs = rsqrtf(vs * (1.0f / D_) + EPS_);
#pragma unroll
    for (int i = 0; i < 3; i++) {
        int c = tid + i * 256;
        float xh = (v[i] - mu) * rs;
        xhat[(size_t)row * D_ + c] = f2bf(xh);
        h[(size_t)row * D_ + c] = f2bf(xh * g[c] + bta[c]);
    }
    if (tid == 0) rstd[row] = rs;
}

// ---------------- batched LayerNorm JVP: grid 4*BS_ rows ----------------
// mode 0: tf = x_tangent [B,M,S,D] f32 (strided); mode 1: tb contiguous bf16 [4*BS][D]
__global__ __launch_bounds__(256) void ln_jvp(const float* __restrict__ tf,
                                              const ushort* __restrict__ tb, int mode,
                                              const ushort* __restrict__ xhat,
                                              const float* __restrict__ rstd,
                                              const float* __restrict__ g,
                                              ushort* __restrict__ dh) {
    int rg = blockIdx.x;
    int r = rg & (BS_ - 1);
    size_t pbase = (size_t)r * D_;
    int tid = threadIdx.x;
    float tv[3], xh[3];
    float s1 = 0.f, s2 = 0.f;
    size_t tbase;
    if (mode == 0) {
        int m = rg >> 11;
        int b = r >> 9, s = r & (S_ - 1);
        tbase = ((size_t)((b * M_ + m) * S_ + s)) * D_;
    } else {
        tbase = (size_t)rg * D_;
    }
#pragma unroll
    for (int i = 0; i < 3; i++) {
        int c = tid + i * 256;
        tv[i] = (mode == 0) ? tf[tbase + c] : bf2f(tb[tbase + c]);
        xh[i] = bf2f(xhat[pbase + c]);
        s1 += tv[i];
        s2 += tv[i] * xh[i];
    }
    s1 = block_sum(s1);
    s2 = block_sum(s2);
    float mt = s1 * (1.0f / D_);
    float mx = s2 * (1.0f / D_);
    float rs = rstd[r];
#pragma unroll
    for (int i = 0; i < 3; i++) {
        int c = tid + i * 256;
        dh[(size_t)rg * D_ + c] = f2bf(g[c] * rs * (tv[i] - mt - xh[i] * mx));
    }
}

// ---------------- bf16 MFMA GEMM <BM,BN>, BK=64, XOR-swizzled LDS, XCD-chunked ----------------
// C[M,N] = A[M,K] @ BT[N,K]^T ; 4 waves (2x2), wave tile (BM/2)x(BN/2).
// EPI 0: v = acc + bias? + resf?(RS: strided) + resb?;  Cf?[OS: strided] = v;  Cb? = bf16(v)
// EPI 1: u = acc + bias; Cb = bf16(gelu(u)); aux = bf16(gelu'(u))
// EPI 2: Cb = bf16(acc * bf2f(aux[primal row]))
template <int BM, int BN, int EPI, bool RS, bool OS>
__global__ __launch_bounds__(256) void gemm_mfma(const ushort* __restrict__ A,
                                                 const ushort* __restrict__ BT,
                                                 const float* __restrict__ bias,
                                                 const float* __restrict__ resf,
                                                 const ushort* __restrict__ resb,
                                                 float* __restrict__ Cf,
                                                 ushort* __restrict__ Cb,
                                                 ushort* __restrict__ aux,
                                                 int Nc, int Kd) {
    constexpr int FI = BM / 32, FJ = BN / 32;
    __shared__ ushort As[BM * 64];
    __shared__ ushort Bs[BN * 64];
    int tid = threadIdx.x;
    int wave = tid >> 6, lane = tid & 63;
    int wr = wave >> 1, wc = wave & 1;
    int gx = gridDim.x, nwg = gx * gridDim.y;
    int work = xcd_swz(blockIdx.x + blockIdx.y * gx, nwg);
    int row0 = (work / gx) * BM, col0 = (work % gx) * BN;

    // staging: chunk c = 8 rows (1024B); lane l -> row c*8+(l>>3); pre-swizzled global k
    int srow = lane >> 3;
    int skel = ((lane & 7) ^ (lane >> 3)) * 8;
    const ushort* Ag0 = A + (size_t)(row0 + srow) * Kd + skel;
    const ushort* Bg0 = BT + (size_t)(col0 + srow) * Kd + skel;

    // fragment read offsets: linear elem (fkb+ks*32) -> swizzled ^((row&7)*8)
    int frow = lane & 15, fkb = (lane >> 4) * 8;
    int aoff[2][FI], boff[2][FJ];
#pragma unroll
    for (int ks = 0; ks < 2; ks++) {
        int sw = (fkb + ks * 32) ^ ((frow & 7) * 8);
#pragma unroll
        for (int i = 0; i < FI; i++) aoff[ks][i] = (wr * (BM / 2) + i * 16 + frow) * 64 + sw;
#pragma unroll
        for (int j = 0; j < FJ; j++) boff[ks][j] = (wc * (BN / 2) + j * 16 + frow) * 64 + sw;
    }

    f32x4 acc[FI][FJ] = {};

    for (int k0 = 0; k0 < Kd; k0 += 64) {
#pragma unroll
        for (int cc = 0; cc < BM / 32; cc++) {
            int c = wave * (BM / 32) + cc;
            gll16(Ag0 + (size_t)(c * 8) * Kd + k0, As + c * 512);
        }
#pragma unroll
        for (int cc = 0; cc < BN / 32; cc++) {
            int c = wave * (BN / 32) + cc;
            gll16(Bg0 + (size_t)(c * 8) * Kd + k0, Bs + c * 512);
        }
        __syncthreads();
        bf16x8 af[2][FI], bfv[2][FJ];
#pragma unroll
        for (int ks = 0; ks < 2; ks++) {
#pragma unroll
            for (int i = 0; i < FI; i++) af[ks][i] = *(const bf16x8*)(As + aoff[ks][i]);
#pragma unroll
            for (int j = 0; j < FJ; j++) bfv[ks][j] = *(const bf16x8*)(Bs + boff[ks][j]);
        }
#pragma unroll
        for (int ks = 0; ks < 2; ks++)
#pragma unroll
            for (int i = 0; i < FI; i++)
#pragma unroll
                for (int j = 0; j < FJ; j++)
                    acc[i][j] = __builtin_amdgcn_mfma_f32_16x16x32_bf16(af[ks][i], bfv[ks][j], acc[i][j], 0, 0, 0);
        __syncthreads();
    }

    // C/D layout: col = lane&15, row = (lane>>4)*4 + reg
#pragma unroll
    for (int i = 0; i < FI; i++) {
        int rbase = row0 + wr * (BM / 2) + i * 16 + (lane >> 4) * 4;
#pragma unroll
        for (int j = 0; j < FJ; j++) {
            int c = col0 + wc * (BN / 2) + j * 16 + (lane & 15);
#pragma unroll
            for (int r = 0; r < 4; r++) {
                int rg = rbase + r;
                size_t off = (size_t)rg * Nc + c;
                float v = acc[i][j][r];
                if (EPI == 0) {
                    if (bias) v += bias[c];
                    if (resf) v += resf[RS ? stroff(rg, c, Nc) : off];
                    if (resb) v += bf2f(resb[off]);
                    if (Cf) { if (OS) Cf[stroff(rg, c, Nc)] = v; else Cf[off] = v; }
                    if (Cb) Cb[off] = f2bf(v);
                } else if (EPI == 1) {
                    v += bias[c];
                    float cdf = 0.5f * (1.0f + erff(v * 0.70710678118654752f));
                    Cb[off] = f2bf(v * cdf);
                    aux[off] = f2bf(cdf + v * 0.39894228040143267f * expf(-0.5f * v * v));
                } else {
                    Cb[off] = f2bf(v * bf2f(aux[(size_t)(rg & (BS_ - 1)) * Nc + c]));
                }
            }
        }
    }
}

// ---------------- MFMA QK^T (BK=32): sc[mz] bf16 = scale*(Q.K)  (TAN: dQ.K + Q.dK) ----------------
// 1D grid: work = mz*(BH*16) + bh*16 + qy*4 + kx; TAN pair-batched (mz in {0,1})
template <bool TAN>
__global__ __launch_bounds__(256) void attn_qk_mfma(const ushort* __restrict__ qkvb,
                                                    const ushort* __restrict__ dqkvp,
                                                    ushort* __restrict__ sc) {
    int work = xcd_swz(blockIdx.x, gridDim.x);
    constexpr int NT = S_ / 128;  // 4
    int mz = work / (BH_ * NT * NT);
    int rem = work % (BH_ * NT * NT);
    int bh = rem / (NT * NT);
    int r2 = rem % (NT * NT);
    int q0 = (r2 / NT) * 128, kc0 = (r2 % NT) * 128;
    int b = bh / H_, hh = bh - b * H_;
    const size_t qoff = (size_t)b * S_ * 3 * D_ + hh * HD_;
    const ushort* Q = qkvb + qoff;
    const ushort* Kp = qkvb + qoff + D_;
    const ushort* dqkv = TAN ? dqkvp + (size_t)mz * BS3D_ : nullptr;
    __shared__ ushort As[128 * 32];
    __shared__ ushort Bs[128 * 32];
    __shared__ ushort dAs[TAN ? 128 * 32 : 1];
    __shared__ ushort dBs[TAN ? 128 * 32 : 1];
    int tid = threadIdx.x;
    int wave = tid >> 6, lane = tid & 63;
    int wr = wave >> 1, wc = wave & 1;
    const int ld = 3 * D_;

    int srow = (lane >> 2);
    int skel = (lane & 3) * 8;
    const ushort* Ag0 = Q + (size_t)(q0 + srow) * ld + skel;
    const ushort* Bg0 = Kp + (size_t)(kc0 + srow) * ld + skel;

    int frow = lane & 15, fk = (lane >> 4) * 8;
    int aoff[4], boff[4];
#pragma unroll
    for (int i = 0; i < 4; i++) {
        aoff[i] = (wr * 64 + i * 16 + frow) * 32 + fk;
        boff[i] = (wc * 64 + i * 16 + frow) * 32 + fk;
    }

    f32x4 acc[4][4] = {};

    for (int k0 = 0; k0 < HD_; k0 += 32) {
#pragma unroll
        for (int cc = 0; cc < 2; cc++) {
            int c = wave * 2 + cc;
            size_t goff = (size_t)(c * 16) * ld + k0;
            gll16(Ag0 + goff, As + c * 512);
            gll16(Bg0 + goff, Bs + c * 512);
            if (TAN) {
                gll16(dqkv + qoff + (size_t)(q0 + srow) * ld + skel + goff, dAs + c * 512);
                gll16(dqkv + qoff + D_ + (size_t)(kc0 + srow) * ld + skel + goff, dBs + c * 512);
            }
        }
        __syncthreads();
        bf16x8 af[4], bfv[4];
#pragma unroll
        for (int i = 0; i < 4; i++) af[i] = *(const bf16x8*)(As + aoff[i]);
#pragma unroll
        for (int j = 0; j < 4; j++) bfv[j] = *(const bf16x8*)(Bs + boff[j]);
        if (!TAN) {
#pragma unroll
            for (int i = 0; i < 4; i++)
#pragma unroll
                for (int j = 0; j < 4; j++)
                    acc[i][j] = __builtin_amdgcn_mfma_f32_16x16x32_bf16(af[i], bfv[j], acc[i][j], 0, 0, 0);
        } else {
            bf16x8 daf[4], dbf[4];
#pragma unroll
            for (int i = 0; i < 4; i++) daf[i] = *(const bf16x8*)(dAs + aoff[i]);
#pragma unroll
            for (int j = 0; j < 4; j++) dbf[j] = *(const bf16x8*)(dBs + boff[j]);
#pragma unroll
            for (int i = 0; i < 4; i++)
#pragma unroll
                for (int j = 0; j < 4; j++) {
                    acc[i][j] = __builtin_amdgcn_mfma_f32_16x16x32_bf16(daf[i], bfv[j], acc[i][j], 0, 0, 0);
                    acc[i][j] = __builtin_amdgcn_mfma_f32_16x16x32_bf16(af[i], dbf[j], acc[i][j], 0, 0, 0);
                }
        }
        __syncthreads();
    }

    ushort* scm = sc + (size_t)mz * ATT_;
#pragma unroll
    for (int i = 0; i < 4; i++) {
        int rbase = q0 + wr * 64 + i * 16 + (lane >> 4) * 4;
#pragma unroll
        for (int j = 0; j < 4; j++) {
            int c = kc0 + wc * 64 + j * 16 + (lane & 15);
#pragma unroll
            for (int r = 0; r < 4; r++)
                scm[((size_t)bh * S_ + rbase + r) * S_ + c] = f2bf(acc[i][j][r] * SCALE_);
        }
    }
}

// ---------------- MFMA P@V (BK=32): o[q][d] (TAN: dP@V + P@dV), pair-batched ----------------
// 1D grid: work = mz*(BH*4) + bh*4 + qx
template <bool TAN>
__global__ __launch_bounds__(256) void attn_av_mfma(const ushort* __restrict__ Pb,
                                                    const ushort* __restrict__ dPp,
                                                    const ushort* __restrict__ Vt,
                                                    const ushort* __restrict__ dVtp,
                                                    ushort* __restrict__ outp) {
    int work = xcd_swz(blockIdx.x, gridDim.x);
    constexpr int NT = S_ / 128;  // 4
    int mz = work / (BH_ * NT);
    int rem = work % (BH_ * NT);
    int bh = rem / NT;
    int q0 = (rem % NT) * 128;
    int b = bh / H_, hh = bh - b * H_;
    const ushort* Pg = Pb + (size_t)bh * S_ * S_;
    const ushort* Vg = Vt + (size_t)bh * HD_ * S_;
    const ushort* dPg = TAN ? dPp + (size_t)mz * ATT_ + (size_t)bh * S_ * S_ : nullptr;
    const ushort* dVg = TAN ? dVtp + (size_t)mz * BSD_ + (size_t)bh * HD_ * S_ : nullptr;
    ushort* outm = outp + (size_t)mz * BSD_;
    __shared__ ushort As[128 * 32];
    __shared__ ushort Bs[64 * 32];
    __shared__ ushort dAs[TAN ? 128 * 32 : 1];
    __shared__ ushort dBs[TAN ? 64 * 32 : 1];
    int tid = threadIdx.x;
    int wave = tid >> 6, lane = tid & 63;
    int wr = wave >> 1, wc = wave & 1;

    int srow = (lane >> 2);
    int skel = (lane & 3) * 8;

    int frow = lane & 15, fk = (lane >> 4) * 8;
    int aoff[4], boff[2];
#pragma unroll
    for (int i = 0; i < 4; i++) aoff[i] = (wr * 64 + i * 16 + frow) * 32 + fk;
#pragma unroll
    for (int j = 0; j < 2; j++) boff[j] = (wc * 32 + j * 16 + frow) * 32 + fk;

    f32x4 acc[4][2] = {};

    for (int k0 = 0; k0 < S_; k0 += 32) {
#pragma unroll
        for (int cc = 0; cc < 2; cc++) {
            int c = wave * 2 + cc;
            gll16(Pg + (size_t)(q0 + c * 16 + srow) * S_ + k0 + skel, As + c * 512);
            if (TAN) gll16(dPg + (size_t)(q0 + c * 16 + srow) * S_ + k0 + skel, dAs + c * 512);
        }
        {
            int c = wave;
            gll16(Vg + (size_t)(c * 16 + srow) * S_ + k0 + skel, Bs + c * 512);
            if (TAN) gll16(dVg + (size_t)(c * 16 + srow) * S_ + k0 + skel, dBs + c * 512);
        }
        __syncthreads();
        bf16x8 af[4], bfv[2];
#pragma unroll
        for (int i = 0; i < 4; i++) af[i] = *(const bf16x8*)(As + aoff[i]);
#pragma unroll
        for (int j = 0; j < 2; j++) bfv[j] = *(const bf16x8*)(Bs + boff[j]);
        if (!TAN) {
#pragma unroll
            for (int i = 0; i < 4; i++)
#pragma unroll
                for (int j = 0; j < 2; j++)
                    acc[i][j] = __builtin_amdgcn_mfma_f32_16x16x32_bf16(af[i], bfv[j], acc[i][j], 0, 0, 0);
        } else {
            bf16x8 daf[4], dbf[2];
#pragma unroll
            for (int i = 0; i < 4; i++) daf[i] = *(const bf16x8*)(dAs + aoff[i]);
#pragma unroll
            for (int j = 0; j < 2; j++) dbf[j] = *(const bf16x8*)(dBs + boff[j]);
#pragma unroll
            for (int i = 0; i < 4; i++)
#pragma unroll
                for (int j = 0; j < 2; j++) {
                    acc[i][j] = __builtin_amdgcn_mfma_f32_16x16x32_bf16(daf[i], bfv[j], acc[i][j], 0, 0, 0);
                    acc[i][j] = __builtin_amdgcn_mfma_f32_16x16x32_bf16(af[i], dbf[j], acc[i][j], 0, 0, 0);
                }
        }
        __syncthreads();
    }

#pragma unroll
    for (int i = 0; i < 4; i++) {
        int rbase = q0 + wr * 64 + i * 16 + (lane >> 4) * 4;
#pragma unroll
        for (int j = 0; j < 2; j++) {
            int c = hh * HD_ + wc * 32 + j * 16 + (lane & 15);
#pragma unroll
            for (int r = 0; r < 4; r++)
                outm[(size_t)(b * S_ + rbase + r) * D_ + c] = f2bf(acc[i][j][r]);
        }
    }
}

// ---------------- softmax: bf16 scores -> bf16 probs ----------------
__global__ __launch_bounds__(256) void softmax_rows(const ushort* __restrict__ sc,
                                                    ushort* __restrict__ scb) {
    size_t row = blockIdx.x;
    const ushort* p = sc + row * S_;
    int tid = threadIdx.x;
    ushort2 vu = *(const ushort2*)&p[tid * 2];
    float v0 = bf2f(vu.x), v1 = bf2f(vu.y);
    float mx = block_max(fmaxf(v0, v1));
    float e0 = expf(v0 - mx), e1 = expf(v1 - mx);
    float s = block_sum(e0 + e1);
    float inv = 1.0f / s;
    ushort2 ob; ob.x = f2bf(e0 * inv); ob.y = f2bf(e1 * inv);
    *(ushort2*)&scb[row * S_ + tid * 2] = ob;
}

// ---------------- dattn in-place, pair-batched: d = attn*(d - rowsum(attn*d)) ----------------
__global__ __launch_bounds__(256) void dattn_rows(const ushort* __restrict__ attnb,
                                                  ushort* __restrict__ dscb) {
    size_t row = blockIdx.x;
    const ushort* a = attnb + row * S_;
    ushort* d = dscb + (size_t)blockIdx.y * ATT_ + row * S_;
    int tid = threadIdx.x;
    ushort2 au = *(const ushort2*)&a[tid * 2];
    ushort2 du = *(const ushort2*)&d[tid * 2];
    float a0 = bf2f(au.x), a1 = bf2f(au.y);
    float d0 = bf2f(du.x), d1 = bf2f(du.y);
    float s = block_sum(a0 * d0 + a1 * d1);
    ushort2 o;
    o.x = f2bf(a0 * (d0 - s));
    o.y = f2bf(a1 * (d1 - s));
    *(ushort2*)&d[tid * 2] = o;
}

// ---------------- host ----------------
extern "C" void kernel_launch(void* const* d_in, const int* in_sizes, int n_in,
                              void* d_out, int out_size, void* d_ws, size_t ws_size,
                              hipStream_t stream) {
    const float* x = (const float*)d_in[0];
    const float* xt = (const float*)d_in[1];
    const float* g1 = (const float*)d_in[2];
    const float* b1 = (const float*)d_in[3];
    const float* Wqkv = (const float*)d_in[4];
    const float* Wproj = (const float*)d_in[5];
    const float* bproj = (const float*)d_in[6];
    const float* g2 = (const float*)d_in[7];
    const float* b2 = (const float*)d_in[8];
    const float* W1 = (const float*)d_in[9];
    const float* bf1 = (const float*)d_in[10];
    const float* W2 = (const float*)d_in[11];
    const float* bf2 = (const float*)d_in[12];
    float* out = (float*)d_out;
    float* out_t = out + BSD_;   // [B,M,S,D]

    char* wp = (char*)d_ws;
    auto alloc = [&](size_t bytes) { void* p = wp; wp += (bytes + 255) & ~(size_t)255; return p; };
    ushort* xhat1 = (ushort*)alloc(BSD_ * 2);
    ushort* hb = (ushort*)alloc(BSD_ * 2);
    ushort* obb = (ushort*)alloc(BSD_ * 2);
    float* x2 = (float*)alloc(BSD_ * 4);
    ushort* xhat2 = (ushort*)alloc(BSD_ * 2);
    ushort* h2b = (ushort*)alloc(BSD_ * 2);
    ushort* dx2b = (ushort*)alloc(4 * BSD_ * 2);   // [4*BS][D] bf16
    ushort* qkvb = (ushort*)alloc(BS3D_ * 2);
    ushort* Vt = (ushort*)alloc(BSD_ * 2);
    ushort* dscb2 = (ushort*)alloc(2 * ATT_ * 2);  // [2][BH,S,S]: primal scores in slice 0; tangent pair dsc->dP in-place
    ushort* attnb = (ushort*)alloc(ATT_ * 2);      // primal probs bf16
    ushort* gpb = (ushort*)alloc(BSF_ * 2);        // gelu'(u) bf16
    float* rstd1 = (float*)alloc(BS_ * 4);
    float* rstd2 = (float*)alloc(BS_ * 4);
    ushort* WqkvT = (ushort*)alloc((size_t)D_ * 3 * D_ * 2);
    ushort* WprojT = (ushort*)alloc((size_t)D_ * D_ * 2);
    ushort* W1T = (ushort*)alloc((size_t)DFF_ * D_ * 2);
    ushort* W2T = (ushort*)alloc((size_t)D_ * DFF_ * 2);
    // Region A (50.3 MB): phase1 {dqkvb4 + dVt4}, phase2 {da4}
    char* regA = (char*)alloc(4 * BSF_ * 2);
    ushort* dqkvb4 = (ushort*)regA;                 // [4][B,S,3D]
    ushort* dVt4 = (ushort*)(regA + 4 * BS3D_ * 2); // [4][bh][HD][S]
    ushort* da4 = (ushort*)regA;                    // [4*BS][DFF]
    // Region B (12.6 MB): {ab} -> {dh4} -> {dob4} -> {dh2_4}  (strictly sequential lifetimes)
    char* regB = (char*)alloc(4 * BSD_ * 2);
    ushort* ab = (ushort*)regB;                     // [BS][DFF]
    ushort* dh4 = (ushort*)regB;                    // [4*BS][D]
    ushort* dob4 = (ushort*)regB;                   // [4][B,S,D]
    ushort* dh2_4 = (ushort*)regB;                  // [4*BS][D]

    // ---- weights -> bf16 transposed [N][K] ----
    transpose_f2b<<<dim3(3 * D_ / 32, D_ / 32), 256, 0, stream>>>(Wqkv, WqkvT, D_, 3 * D_);
    transpose_f2b<<<dim3(D_ / 32, D_ / 32), 256, 0, stream>>>(Wproj, WprojT, D_, D_);
    transpose_f2b<<<dim3(DFF_ / 32, D_ / 32), 256, 0, stream>>>(W1, W1T, D_, DFF_);
    transpose_f2b<<<dim3(D_ / 32, DFF_ / 32), 256, 0, stream>>>(W2, W2T, DFF_, D_);

    // ---- primal ----
    ln_fwd<<<BS_, 256, 0, stream>>>(x, g1, b1, xhat1, hb, rstd1);
    gemm_mfma<64, 128, 0, false, false><<<dim3(3 * D_ / 128, BS_ / 64), 256, 0, stream>>>(
        hb, WqkvT, nullptr, nullptr, nullptr, nullptr, qkvb, nullptr, 3 * D_, D_);
    transpose_v<<<dim3(S_ / 32, HD_ / 32, BH_), 256, 0, stream>>>(qkvb, Vt);
    attn_qk_mfma<false><<<(S_ / 128) * (S_ / 128) * BH_, 256, 0, stream>>>(qkvb, nullptr, dscb2);
    softmax_rows<<<BH_ * S_, 256, 0, stream>>>(dscb2, attnb);
    attn_av_mfma<false><<<(S_ / 128) * BH_, 256, 0, stream>>>(attnb, nullptr, Vt, nullptr, obb);
    gemm_mfma<64, 64, 0, false, false><<<dim3(D_ / 64, BS_ / 64), 256, 0, stream>>>(
        obb, WprojT, bproj, x, nullptr, x2, nullptr, nullptr, D_, D_);
    ln_fwd<<<BS_, 256, 0, stream>>>(x2, g2, b2, xhat2, h2b, rstd2);
    gemm_mfma<128, 128, 1, false, false><<<dim3(DFF_ / 128, BS_ / 128), 256, 0, stream>>>(
        h2b, W1T, bf1, nullptr, nullptr, nullptr, ab, gpb, DFF_, D_);
    gemm_mfma<64, 64, 0, false, false><<<dim3(D_ / 64, BS_ / 64), 256, 0, stream>>>(
        ab, W2T, bf2, x2, nullptr, out, nullptr, nullptr, D_, DFF_);

    // ---- tangents: batched linear stages (M = 8192), pair-batched attention ----
    ln_jvp<<<4 * BS_, 256, 0, stream>>>(xt, nullptr, 0, xhat1, rstd1, g1, dh4);
    gemm_mfma<128, 128, 0, false, false><<<dim3(3 * D_ / 128, 4 * BS_ / 128), 256, 0, stream>>>(
        dh4, WqkvT, nullptr, nullptr, nullptr, nullptr, dqkvb4, nullptr, 3 * D_, D_);
    transpose_v<<<dim3(S_ / 32, HD_ / 32, 4 * BH_), 256, 0, stream>>>(dqkvb4, dVt4);
    for (int p = 0; p < 2; p++) {
        attn_qk_mfma<true><<<2 * (S_ / 128) * (S_ / 128) * BH_, 256, 0, stream>>>(
            qkvb, dqkvb4 + (size_t)p * 2 * BS3D_, dscb2);
        dattn_rows<<<dim3(BH_ * S_, 2), 256, 0, stream>>>(attnb, dscb2);
        attn_av_mfma<true><<<2 * (S_ / 128) * BH_, 256, 0, stream>>>(
            attnb, dscb2, Vt, dVt4 + (size_t)p * 2 * BSD_, dob4 + (size_t)p * 2 * BSD_);
    }
    gemm_mfma<128, 64, 0, true, false><<<dim3(D_ / 64, 4 * BS_ / 128), 256, 0, stream>>>(
        dob4, WprojT, nullptr, xt, nullptr, nullptr, dx2b, nullptr, D_, D_);
    ln_jvp<<<4 * BS_, 256, 0, stream>>>(nullptr, dx2b, 1, xhat2, rstd2, g2, dh2_4);
    gemm_mfma<128, 128, 2, false, false><<<dim3(DFF_ / 128, 4 * BS_ / 128), 256, 0, stream>>>(
        dh2_4, W1T, nullptr, nullptr, nullptr, nullptr, da4, gpb, DFF_, D_);
    gemm_mfma<128, 64, 0, false, true><<<dim3(D_ / 64, 4 * BS_ / 128), 256, 0, stream>>>(
        da4, W2T, nullptr, nullptr, dx2b, out_t, nullptr, nullptr, D_, DFF_);
}

// Round 9
// 541.062 us; speedup vs baseline: 6.2941x; 1.0086x over previous
//
#include <hip/hip_runtime.h>
#include <math.h>

constexpr int B_ = 4, S_ = 512, D_ = 768, H_ = 12, M_ = 4, DFF_ = 3072, HD_ = 64;
constexpr float EPS_ = 1e-6f;
constexpr float SCALE_ = 0.125f;  // HD^-0.5
constexpr int BS_ = B_ * S_;
constexpr int BH_ = B_ * H_;
constexpr long long BSD_ = (long long)BS_ * D_;
constexpr long long BS3D_ = (long long)BS_ * 3 * D_;
constexpr long long ATT_ = (long long)BH_ * S_ * S_;
constexpr long long BSF_ = (long long)BS_ * DFF_;

typedef __attribute__((ext_vector_type(8))) short bf16x8;
typedef __attribute__((ext_vector_type(4))) float f32x4;

__device__ __forceinline__ ushort f2bf(float f) {
    uint32_t u = __float_as_uint(f);
    u += 0x7FFF + ((u >> 16) & 1);
    return (ushort)(u >> 16);
}
__device__ __forceinline__ float bf2f(ushort u) {
    return __uint_as_float((uint32_t)u << 16);
}

__device__ __forceinline__ void gll16(const ushort* g, ushort* l) {
    __builtin_amdgcn_global_load_lds((const __attribute__((address_space(1))) void*)g,
                                     (__attribute__((address_space(3))) void*)l, 16, 0, 0);
}

// counted vmcnt wait (literal required in asm)
template <int N> __device__ __forceinline__ void waitcnt_vm() {
    if constexpr (N == 0) asm volatile("s_waitcnt vmcnt(0)" ::: "memory");
    else if constexpr (N == 4) asm volatile("s_waitcnt vmcnt(4)" ::: "memory");
    else if constexpr (N == 6) asm volatile("s_waitcnt vmcnt(6)" ::: "memory");
    else if constexpr (N == 8) asm volatile("s_waitcnt vmcnt(8)" ::: "memory");
    else static_assert(N == 0 || N == 4 || N == 6 || N == 8, "add literal");
}

// XCD-chunked bijective block remap (m204)
__device__ __forceinline__ int xcd_swz(int flat, int nwg) {
    int q = nwg >> 3, r = nwg & 7;
    int x = flat & 7, pos = flat >> 3;
    int base = (x < r) ? x * (q + 1) : r * (q + 1) + (x - r) * q;
    return base + pos;
}

// batched-row (rg in [0,8192)) -> [B,M,S,Nc] offset
__device__ __forceinline__ size_t stroff(int rg, int c, int Nc) {
    int m = rg >> 11;
    int b = (rg >> 9) & (B_ - 1);
    int s = rg & (S_ - 1);
    return ((size_t)((b * M_ + m) * S_ + s)) * Nc + c;
}

// ---------------- block reductions (256 threads = 4 waves) ----------------
__device__ __forceinline__ float block_sum(float v) {
    __shared__ float red[4];
    int tid = threadIdx.x;
#pragma unroll
    for (int off = 32; off > 0; off >>= 1) v += __shfl_down(v, off, 64);
    __syncthreads();
    if ((tid & 63) == 0) red[tid >> 6] = v;
    __syncthreads();
    return red[0] + red[1] + red[2] + red[3];
}

__device__ __forceinline__ float block_max(float v) {
    __shared__ float red[4];
    int tid = threadIdx.x;
#pragma unroll
    for (int off = 32; off > 0; off >>= 1) v = fmaxf(v, __shfl_down(v, off, 64));
    __syncthreads();
    if ((tid & 63) == 0) red[tid >> 6] = v;
    __syncthreads();
    return fmaxf(fmaxf(red[0], red[1]), fmaxf(red[2], red[3]));
}

// ---------------- weight transpose+convert: W[K][N] f32 -> WT[N][K] bf16 ----------------
__global__ __launch_bounds__(256) void transpose_f2b(const float* __restrict__ W,
                                                     ushort* __restrict__ WT,
                                                     int K, int N) {
    __shared__ float t[32][33];
    int n0 = blockIdx.x * 32, k0 = blockIdx.y * 32;
    int tx = threadIdx.x & 31, ty = threadIdx.x >> 5;
#pragma unroll
    for (int i = 0; i < 4; i++)
        t[ty + i * 8][tx] = W[(size_t)(k0 + ty + i * 8) * N + n0 + tx];
    __syncthreads();
#pragma unroll
    for (int i = 0; i < 4; i++)
        WT[(size_t)(n0 + ty + i * 8) * K + k0 + tx] = f2bf(t[tx][ty + i * 8]);
}

// ---------------- V transpose: src[m][B,S,3D] bf16 -> dst[m][bh][HD][S] bf16 ----------------
__global__ __launch_bounds__(256) void transpose_v(const ushort* __restrict__ src0,
                                                   ushort* __restrict__ dst0) {
    int z = blockIdx.z;
    int m = z / BH_, bh = z % BH_;
    const ushort* qkvb = src0 + (size_t)m * BS3D_;
    ushort* Vt = dst0 + (size_t)m * BSD_;
    int b = bh / H_, hh = bh - b * H_;
    int s0 = blockIdx.x * 32, d0 = blockIdx.y * 32;
    __shared__ ushort t[32][33];
    int tx = threadIdx.x & 31, ty = threadIdx.x >> 5;
#pragma unroll
    for (int i = 0; i < 4; i++)
        t[ty + i * 8][tx] = qkvb[(size_t)(b * S_ + s0 + ty + i * 8) * 3 * D_ + 2 * D_ + hh * HD_ + d0 + tx];
    __syncthreads();
#pragma unroll
    for (int i = 0; i < 4; i++)
        Vt[(size_t)bh * HD_ * S_ + (size_t)(d0 + ty + i * 8) * S_ + s0 + tx] = t[tx][ty + i * 8];
}

// ---------------- LayerNorm forward: xhat bf16, h bf16 ----------------
__global__ __launch_bounds__(256) void ln_fwd(const float* __restrict__ x,
                                              const float* __restrict__ g,
                                              const float* __restrict__ bta,
                                              ushort* __restrict__ xhat,
                                              ushort* __restrict__ h,
                                              float* __restrict__ rstd) {
    int row = blockIdx.x;
    const float* xr = x + (size_t)row * D_;
    int tid = threadIdx.x;
    float v[3];
    float s = 0.f;
#pragma unroll
    for (int i = 0; i < 3; i++) { v[i] = xr[tid + i * 256]; s += v[i]; }
    s = block_sum(s);
    float mu = s * (1.0f / D_);
    float vs = 0.f;
#pragma unroll
    for (int i = 0; i < 3; i++) { float c = v[i] - mu; vs += c * c; }
    vs = block_sum(vs);
    float rs = rsqrtf(vs * (1.0f / D_) + EPS_);
#pragma unroll
    for (int i = 0; i < 3; i++) {
        int c = tid + i * 256;
        float xh = (v[i] - mu) * rs;
        xhat[(size_t)row * D_ + c] = f2bf(xh);
        h[(size_t)row * D_ + c] = f2bf(xh * g[c] + bta[c]);
    }
    if (tid == 0) rstd[row] = rs;
}

// ---------------- batched LayerNorm JVP: grid 4*BS_ rows ----------------
// mode 0: tf = x_tangent [B,M,S,D] f32 (strided); mode 1: tb contiguous bf16 [4*BS][D]
__global__ __launch_bounds__(256) void ln_jvp(const float* __restrict__ tf,
                                              const ushort* __restrict__ tb, int mode,
                                              const ushort* __restrict__ xhat,
                                              const float* __restrict__ rstd,
                                              const float* __restrict__ g,
                                              ushort* __restrict__ dh) {
    int rg = blockIdx.x;
    int r = rg & (BS_ - 1);
    size_t pbase = (size_t)r * D_;
    int tid = threadIdx.x;
    float tv[3], xh[3];
    float s1 = 0.f, s2 = 0.f;
    size_t tbase;
    if (mode == 0) {
        int m = rg >> 11;
        int b = r >> 9, s = r & (S_ - 1);
        tbase = ((size_t)((b * M_ + m) * S_ + s)) * D_;
    } else {
        tbase = (size_t)rg * D_;
    }
#pragma unroll
    for (int i = 0; i < 3; i++) {
        int c = tid + i * 256;
        tv[i] = (mode == 0) ? tf[tbase + c] : bf2f(tb[tbase + c]);
        xh[i] = bf2f(xhat[pbase + c]);
        s1 += tv[i];
        s2 += tv[i] * xh[i];
    }
    s1 = block_sum(s1);
    s2 = block_sum(s2);
    float mt = s1 * (1.0f / D_);
    float mx = s2 * (1.0f / D_);
    float rs = rstd[r];
#pragma unroll
    for (int i = 0; i < 3; i++) {
        int c = tid + i * 256;
        dh[(size_t)rg * D_ + c] = f2bf(g[c] * rs * (tv[i] - mt - xh[i] * mx));
    }
}

// ---------------- bf16 MFMA GEMM <BM,BN>, BK=64, 2-deep dbuf pipeline (T3/T4) ----------------
// C[M,N] = A[M,K] @ BT[N,K]^T ; 4 waves (2x2), XOR-swizzled LDS, XCD-chunked.
// K-loop: compute tile t from buf[cur] while tile t+1 loads fly; then stage t+2
// into buf[cur] and wait vmcnt(L) (t+1 complete, t+2 in flight) - never drain to 0.
// EPI 0: v = acc + bias? + resf?(RS: strided) + resb?;  Cf?[OS: strided] = v;  Cb? = bf16(v)
// EPI 1: u = acc + bias; Cb = bf16(gelu(u)); aux = bf16(gelu'(u))
// EPI 2: Cb = bf16(acc * bf2f(aux[primal row]))
template <int BM, int BN, int EPI, bool RS, bool OS>
__global__ __launch_bounds__(256) void gemm_mfma(const ushort* __restrict__ A,
                                                 const ushort* __restrict__ BT,
                                                 const float* __restrict__ bias,
                                                 const float* __restrict__ resf,
                                                 const ushort* __restrict__ resb,
                                                 float* __restrict__ Cf,
                                                 ushort* __restrict__ Cb,
                                                 ushort* __restrict__ aux,
                                                 int Nc, int Kd) {
    constexpr int FI = BM / 32, FJ = BN / 32;
    constexpr int LA = BM / 32, LB = BN / 32, L = LA + LB;  // gll16 per thread per tile
    __shared__ ushort As[2][BM * 64];
    __shared__ ushort Bs[2][BN * 64];
    int tid = threadIdx.x;
    int wave = tid >> 6, lane = tid & 63;
    int wr = wave >> 1, wc = wave & 1;
    int gx = gridDim.x, nwg = gx * gridDim.y;
    int work = xcd_swz(blockIdx.x + blockIdx.y * gx, nwg);
    int row0 = (work / gx) * BM, col0 = (work % gx) * BN;

    // staging: chunk c = 8 rows (1024B); lane l -> row c*8+(l>>3); pre-swizzled global k
    int srow = lane >> 3;
    int skel = ((lane & 7) ^ (lane >> 3)) * 8;
    const ushort* Ag0 = A + (size_t)(row0 + srow) * Kd + skel;
    const ushort* Bg0 = BT + (size_t)(col0 + srow) * Kd + skel;

    auto stage = [&](int bufi, int k0) {
#pragma unroll
        for (int cc = 0; cc < LA; cc++) {
            int c = wave * LA + cc;
            gll16(Ag0 + (size_t)(c * 8) * Kd + k0, As[bufi] + c * 512);
        }
#pragma unroll
        for (int cc = 0; cc < LB; cc++) {
            int c = wave * LB + cc;
            gll16(Bg0 + (size_t)(c * 8) * Kd + k0, Bs[bufi] + c * 512);
        }
    };

    // fragment read offsets: linear elem (fkb+ks*32) -> swizzled ^((row&7)*8)
    int frow = lane & 15, fkb = (lane >> 4) * 8;
    int aoff[2][FI], boff[2][FJ];
#pragma unroll
    for (int ks = 0; ks < 2; ks++) {
        int sw = (fkb + ks * 32) ^ ((frow & 7) * 8);
#pragma unroll
        for (int i = 0; i < FI; i++) aoff[ks][i] = (wr * (BM / 2) + i * 16 + frow) * 64 + sw;
#pragma unroll
        for (int j = 0; j < FJ; j++) boff[ks][j] = (wc * (BN / 2) + j * 16 + frow) * 64 + sw;
    }

    f32x4 acc[FI][FJ] = {};

    int nt = Kd >> 6;
    stage(0, 0);
    if (nt > 1) { stage(1, 64); waitcnt_vm<L>(); }
    else        { waitcnt_vm<0>(); }
    __builtin_amdgcn_s_barrier();
    __builtin_amdgcn_sched_barrier(0);

    int cur = 0;
    for (int t = 0; t < nt; t++) {
        bf16x8 af[2][FI], bfv[2][FJ];
        const ushort* Ab = As[cur];
        const ushort* Bb = Bs[cur];
#pragma unroll
        for (int ks = 0; ks < 2; ks++) {
#pragma unroll
            for (int i = 0; i < FI; i++) af[ks][i] = *(const bf16x8*)(Ab + aoff[ks][i]);
#pragma unroll
            for (int j = 0; j < FJ; j++) bfv[ks][j] = *(const bf16x8*)(Bb + boff[ks][j]);
        }
#pragma unroll
        for (int ks = 0; ks < 2; ks++)
#pragma unroll
            for (int i = 0; i < FI; i++)
#pragma unroll
                for (int j = 0; j < FJ; j++)
                    acc[i][j] = __builtin_amdgcn_mfma_f32_16x16x32_bf16(af[ks][i], bfv[ks][j], acc[i][j], 0, 0, 0);
        __builtin_amdgcn_sched_barrier(0);       // pin ds_read+MFMA above the barrier
        __builtin_amdgcn_s_barrier();            // all waves done reading buf[cur]
        if (t + 2 < nt) {
            stage(cur, (t + 2) << 6);            // L loads issued; 2L in flight
            waitcnt_vm<L>();                     // tile t+1 complete; t+2 stays in flight
        } else if (t + 1 < nt) {
            waitcnt_vm<0>();                     // final prefetched tile complete
        }
        __builtin_amdgcn_s_barrier();            // t+1 data visible to all waves
        __builtin_amdgcn_sched_barrier(0);       // keep next ds_reads below
        cur ^= 1;
    }

    // C/D layout: col = lane&15, row = (lane>>4)*4 + reg
#pragma unroll
    for (int i = 0; i < FI; i++) {
        int rbase = row0 + wr * (BM / 2) + i * 16 + (lane >> 4) * 4;
#pragma unroll
        for (int j = 0; j < FJ; j++) {
            int c = col0 + wc * (BN / 2) + j * 16 + (lane & 15);
#pragma unroll
            for (int r = 0; r < 4; r++) {
                int rg = rbase + r;
                size_t off = (size_t)rg * Nc + c;
                float v = acc[i][j][r];
                if (EPI == 0) {
                    if (bias) v += bias[c];
                    if (resf) v += resf[RS ? stroff(rg, c, Nc) : off];
                    if (resb) v += bf2f(resb[off]);
                    if (Cf) { if (OS) Cf[stroff(rg, c, Nc)] = v; else Cf[off] = v; }
                    if (Cb) Cb[off] = f2bf(v);
                } else if (EPI == 1) {
                    v += bias[c];
                    float cdf = 0.5f * (1.0f + erff(v * 0.70710678118654752f));
                    Cb[off] = f2bf(v * cdf);
                    aux[off] = f2bf(cdf + v * 0.39894228040143267f * expf(-0.5f * v * v));
                } else {
                    Cb[off] = f2bf(v * bf2f(aux[(size_t)(rg & (BS_ - 1)) * Nc + c]));
                }
            }
        }
    }
}

// ---------------- MFMA QK^T (BK=32): sc[mz] bf16 = scale*(Q.K)  (TAN: dQ.K + Q.dK) ----------------
// 1D grid: work = mz*(BH*16) + bh*16 + qy*4 + kx; TAN pair-batched (mz in {0,1})
template <bool TAN>
__global__ __launch_bounds__(256) void attn_qk_mfma(const ushort* __restrict__ qkvb,
                                                    const ushort* __restrict__ dqkvp,
                                                    ushort* __restrict__ sc) {
    int work = xcd_swz(blockIdx.x, gridDim.x);
    constexpr int NT = S_ / 128;  // 4
    int mz = work / (BH_ * NT * NT);
    int rem = work % (BH_ * NT * NT);
    int bh = rem / (NT * NT);
    int r2 = rem % (NT * NT);
    int q0 = (r2 / NT) * 128, kc0 = (r2 % NT) * 128;
    int b = bh / H_, hh = bh - b * H_;
    const size_t qoff = (size_t)b * S_ * 3 * D_ + hh * HD_;
    const ushort* Q = qkvb + qoff;
    const ushort* Kp = qkvb + qoff + D_;
    const ushort* dqkv = TAN ? dqkvp + (size_t)mz * BS3D_ : nullptr;
    __shared__ ushort As[128 * 32];
    __shared__ ushort Bs[128 * 32];
    __shared__ ushort dAs[TAN ? 128 * 32 : 1];
    __shared__ ushort dBs[TAN ? 128 * 32 : 1];
    int tid = threadIdx.x;
    int wave = tid >> 6, lane = tid & 63;
    int wr = wave >> 1, wc = wave & 1;
    const int ld = 3 * D_;

    int srow = (lane >> 2);
    int skel = (lane & 3) * 8;
    const ushort* Ag0 = Q + (size_t)(q0 + srow) * ld + skel;
    const ushort* Bg0 = Kp + (size_t)(kc0 + srow) * ld + skel;

    int frow = lane & 15, fk = (lane >> 4) * 8;
    int aoff[4], boff[4];
#pragma unroll
    for (int i = 0; i < 4; i++) {
        aoff[i] = (wr * 64 + i * 16 + frow) * 32 + fk;
        boff[i] = (wc * 64 + i * 16 + frow) * 32 + fk;
    }

    f32x4 acc[4][4] = {};

    for (int k0 = 0; k0 < HD_; k0 += 32) {
#pragma unroll
        for (int cc = 0; cc < 2; cc++) {
            int c = wave * 2 + cc;
            size_t goff = (size_t)(c * 16) * ld + k0;
            gll16(Ag0 + goff, As + c * 512);
            gll16(Bg0 + goff, Bs + c * 512);
            if (TAN) {
                gll16(dqkv + qoff + (size_t)(q0 + srow) * ld + skel + goff, dAs + c * 512);
                gll16(dqkv + qoff + D_ + (size_t)(kc0 + srow) * ld + skel + goff, dBs + c * 512);
            }
        }
        __syncthreads();
        bf16x8 af[4], bfv[4];
#pragma unroll
        for (int i = 0; i < 4; i++) af[i] = *(const bf16x8*)(As + aoff[i]);
#pragma unroll
        for (int j = 0; j < 4; j++) bfv[j] = *(const bf16x8*)(Bs + boff[j]);
        if (!TAN) {
#pragma unroll
            for (int i = 0; i < 4; i++)
#pragma unroll
                for (int j = 0; j < 4; j++)
                    acc[i][j] = __builtin_amdgcn_mfma_f32_16x16x32_bf16(af[i], bfv[j], acc[i][j], 0, 0, 0);
        } else {
            bf16x8 daf[4], dbf[4];
#pragma unroll
            for (int i = 0; i < 4; i++) daf[i] = *(const bf16x8*)(dAs + aoff[i]);
#pragma unroll
            for (int j = 0; j < 4; j++) dbf[j] = *(const bf16x8*)(dBs + boff[j]);
#pragma unroll
            for (int i = 0; i < 4; i++)
#pragma unroll
                for (int j = 0; j < 4; j++) {
                    acc[i][j] = __builtin_amdgcn_mfma_f32_16x16x32_bf16(daf[i], bfv[j], acc[i][j], 0, 0, 0);
                    acc[i][j] = __builtin_amdgcn_mfma_f32_16x16x32_bf16(af[i], dbf[j], acc[i][j], 0, 0, 0);
                }
        }
        __syncthreads();
    }

    ushort* scm = sc + (size_t)mz * ATT_;
#pragma unroll
    for (int i = 0; i < 4; i++) {
        int rbase = q0 + wr * 64 + i * 16 + (lane >> 4) * 4;
#pragma unroll
        for (int j = 0; j < 4; j++) {
            int c = kc0 + wc * 64 + j * 16 + (lane & 15);
#pragma unroll
            for (int r = 0; r < 4; r++)
                scm[((size_t)bh * S_ + rbase + r) * S_ + c] = f2bf(acc[i][j][r] * SCALE_);
        }
    }
}

// ---------------- MFMA P@V (BK=32): o[q][d] (TAN: dP@V + P@dV), pair-batched ----------------
// 1D grid: work = mz*(BH*4) + bh*4 + qx
template <bool TAN>
__global__ __launch_bounds__(256) void attn_av_mfma(const ushort* __restrict__ Pb,
                                                    const ushort* __restrict__ dPp,
                                                    const ushort* __restrict__ Vt,
                                                    const ushort* __restrict__ dVtp,
                                                    ushort* __restrict__ outp) {
    int work = xcd_swz(blockIdx.x, gridDim.x);
    constexpr int NT = S_ / 128;  // 4
    int mz = work / (BH_ * NT);
    int rem = work % (BH_ * NT);
    int bh = rem / NT;
    int q0 = (rem % NT) * 128;
    int b = bh / H_, hh = bh - b * H_;
    const ushort* Pg = Pb + (size_t)bh * S_ * S_;
    const ushort* Vg = Vt + (size_t)bh * HD_ * S_;
    const ushort* dPg = TAN ? dPp + (size_t)mz * ATT_ + (size_t)bh * S_ * S_ : nullptr;
    const ushort* dVg = TAN ? dVtp + (size_t)mz * BSD_ + (size_t)bh * HD_ * S_ : nullptr;
    ushort* outm = outp + (size_t)mz * BSD_;
    __shared__ ushort As[128 * 32];
    __shared__ ushort Bs[64 * 32];
    __shared__ ushort dAs[TAN ? 128 * 32 : 1];
    __shared__ ushort dBs[TAN ? 64 * 32 : 1];
    int tid = threadIdx.x;
    int wave = tid >> 6, lane = tid & 63;
    int wr = wave >> 1, wc = wave & 1;

    int srow = (lane >> 2);
    int skel = (lane & 3) * 8;

    int frow = lane & 15, fk = (lane >> 4) * 8;
    int aoff[4], boff[2];
#pragma unroll
    for (int i = 0; i < 4; i++) aoff[i] = (wr * 64 + i * 16 + frow) * 32 + fk;
#pragma unroll
    for (int j = 0; j < 2; j++) boff[j] = (wc * 32 + j * 16 + frow) * 32 + fk;

    f32x4 acc[4][2] = {};

    for (int k0 = 0; k0 < S_; k0 += 32) {
#pragma unroll
        for (int cc = 0; cc < 2; cc++) {
            int c = wave * 2 + cc;
            gll16(Pg + (size_t)(q0 + c * 16 + srow) * S_ + k0 + skel, As + c * 512);
            if (TAN) gll16(dPg + (size_t)(q0 + c * 16 + srow) * S_ + k0 + skel, dAs + c * 512);
        }
        {
            int c = wave;
            gll16(Vg + (size_t)(c * 16 + srow) * S_ + k0 + skel, Bs + c * 512);
            if (TAN) gll16(dVg + (size_t)(c * 16 + srow) * S_ + k0 + skel, dBs + c * 512);
        }
        __syncthreads();
        bf16x8 af[4], bfv[2];
#pragma unroll
        for (int i = 0; i < 4; i++) af[i] = *(const bf16x8*)(As + aoff[i]);
#pragma unroll
        for (int j = 0; j < 2; j++) bfv[j] = *(const bf16x8*)(Bs + boff[j]);
        if (!TAN) {
#pragma unroll
            for (int i = 0; i < 4; i++)
#pragma unroll
                for (int j = 0; j < 2; j++)
                    acc[i][j] = __builtin_amdgcn_mfma_f32_16x16x32_bf16(af[i], bfv[j], acc[i][j], 0, 0, 0);
        } else {
            bf16x8 daf[4], dbf[2];
#pragma unroll
            for (int i = 0; i < 4; i++) daf[i] = *(const bf16x8*)(dAs + aoff[i]);
#pragma unroll
            for (int j = 0; j < 2; j++) dbf[j] = *(const bf16x8*)(dBs + boff[j]);
#pragma unroll
            for (int i = 0; i < 4; i++)
#pragma unroll
                for (int j = 0; j < 2; j++) {
                    acc[i][j] = __builtin_amdgcn_mfma_f32_16x16x32_bf16(daf[i], bfv[j], acc[i][j], 0, 0, 0);
                    acc[i][j] = __builtin_amdgcn_mfma_f32_16x16x32_bf16(af[i], dbf[j], acc[i][j], 0, 0, 0);
                }
        }
        __syncthreads();
    }

#pragma unroll
    for (int i = 0; i < 4; i++) {
        int rbase = q0 + wr * 64 + i * 16 + (lane >> 4) * 4;
#pragma unroll
        for (int j = 0; j < 2; j++) {
            int c = hh * HD_ + wc * 32 + j * 16 + (lane & 15);
#pragma unroll
            for (int r = 0; r < 4; r++)
                outm[(size_t)(b * S_ + rbase + r) * D_ + c] = f2bf(acc[i][j][r]);
        }
    }
}

// ---------------- softmax: bf16 scores -> bf16 probs ----------------
__global__ __launch_bounds__(256) void softmax_rows(const ushort* __restrict__ sc,
                                                    ushort* __restrict__ scb) {
    size_t row = blockIdx.x;
    const ushort* p = sc + row * S_;
    int tid = threadIdx.x;
    ushort2 vu = *(const ushort2*)&p[tid * 2];
    float v0 = bf2f(vu.x), v1 = bf2f(vu.y);
    float mx = block_max(fmaxf(v0, v1));
    float e0 = expf(v0 - mx), e1 = expf(v1 - mx);
    float s = block_sum(e0 + e1);
    float inv = 1.0f / s;
    ushort2 ob; ob.x = f2bf(e0 * inv); ob.y = f2bf(e1 * inv);
    *(ushort2*)&scb[row * S_ + tid * 2] = ob;
}

// ---------------- dattn in-place, pair-batched: d = attn*(d - rowsum(attn*d)) ----------------
__global__ __launch_bounds__(256) void dattn_rows(const ushort* __restrict__ attnb,
                                                  ushort* __restrict__ dscb) {
    size_t row = blockIdx.x;
    const ushort* a = attnb + row * S_;
    ushort* d = dscb + (size_t)blockIdx.y * ATT_ + row * S_;
    int tid = threadIdx.x;
    ushort2 au = *(const ushort2*)&a[tid * 2];
    ushort2 du = *(const ushort2*)&d[tid * 2];
    float a0 = bf2f(au.x), a1 = bf2f(au.y);
    float d0 = bf2f(du.x), d1 = bf2f(du.y);
    float s = block_sum(a0 * d0 + a1 * d1);
    ushort2 o;
    o.x = f2bf(a0 * (d0 - s));
    o.y = f2bf(a1 * (d1 - s));
    *(ushort2*)&d[tid * 2] = o;
}

// ---------------- host ----------------
extern "C" void kernel_launch(void* const* d_in, const int* in_sizes, int n_in,
                              void* d_out, int out_size, void* d_ws, size_t ws_size,
                              hipStream_t stream) {
    const float* x = (const float*)d_in[0];
    const float* xt = (const float*)d_in[1];
    const float* g1 = (const float*)d_in[2];
    const float* b1 = (const float*)d_in[3];
    const float* Wqkv = (const float*)d_in[4];
    const float* Wproj = (const float*)d_in[5];
    const float* bproj = (const float*)d_in[6];
    const float* g2 = (const float*)d_in[7];
    const float* b2 = (const float*)d_in[8];
    const float* W1 = (const float*)d_in[9];
    const float* bf1 = (const float*)d_in[10];
    const float* W2 = (const float*)d_in[11];
    const float* bf2 = (const float*)d_in[12];
    float* out = (float*)d_out;
    float* out_t = out + BSD_;   // [B,M,S,D]

    char* wp = (char*)d_ws;
    auto alloc = [&](size_t bytes) { void* p = wp; wp += (bytes + 255) & ~(size_t)255; return p; };
    ushort* xhat1 = (ushort*)alloc(BSD_ * 2);
    ushort* hb = (ushort*)alloc(BSD_ * 2);
    ushort* obb = (ushort*)alloc(BSD_ * 2);
    float* x2 = (float*)alloc(BSD_ * 4);
    ushort* xhat2 = (ushort*)alloc(BSD_ * 2);
    ushort* h2b = (ushort*)alloc(BSD_ * 2);
    ushort* dx2b = (ushort*)alloc(4 * BSD_ * 2);   // [4*BS][D] bf16
    ushort* qkvb = (ushort*)alloc(BS3D_ * 2);
    ushort* Vt = (ushort*)alloc(BSD_ * 2);
    ushort* dscb2 = (ushort*)alloc(2 * ATT_ * 2);  // [2][BH,S,S]
    ushort* attnb = (ushort*)alloc(ATT_ * 2);      // primal probs bf16
    ushort* gpb = (ushort*)alloc(BSF_ * 2);        // gelu'(u) bf16
    float* rstd1 = (float*)alloc(BS_ * 4);
    float* rstd2 = (float*)alloc(BS_ * 4);
    ushort* WqkvT = (ushort*)alloc((size_t)D_ * 3 * D_ * 2);
    ushort* WprojT = (ushort*)alloc((size_t)D_ * D_ * 2);
    ushort* W1T = (ushort*)alloc((size_t)DFF_ * D_ * 2);
    ushort* W2T = (ushort*)alloc((size_t)D_ * DFF_ * 2);
    // Region A (50.3 MB): phase1 {dqkvb4 + dVt4}, phase2 {da4}
    char* regA = (char*)alloc(4 * BSF_ * 2);
    ushort* dqkvb4 = (ushort*)regA;                 // [4][B,S,3D]
    ushort* dVt4 = (ushort*)(regA + 4 * BS3D_ * 2); // [4][bh][HD][S]
    ushort* da4 = (ushort*)regA;                    // [4*BS][DFF]
    // Region B (12.6 MB): {ab} -> {dh4} -> {dob4} -> {dh2_4}  (strictly sequential lifetimes)
    char* regB = (char*)alloc(4 * BSD_ * 2);
    ushort* ab = (ushort*)regB;                     // [BS][DFF]
    ushort* dh4 = (ushort*)regB;                    // [4*BS][D]
    ushort* dob4 = (ushort*)regB;                   // [4][B,S,D]
    ushort* dh2_4 = (ushort*)regB;                  // [4*BS][D]

    // ---- weights -> bf16 transposed [N][K] ----
    transpose_f2b<<<dim3(3 * D_ / 32, D_ / 32), 256, 0, stream>>>(Wqkv, WqkvT, D_, 3 * D_);
    transpose_f2b<<<dim3(D_ / 32, D_ / 32), 256, 0, stream>>>(Wproj, WprojT, D_, D_);
    transpose_f2b<<<dim3(DFF_ / 32, D_ / 32), 256, 0, stream>>>(W1, W1T, D_, DFF_);
    transpose_f2b<<<dim3(D_ / 32, DFF_ / 32), 256, 0, stream>>>(W2, W2T, DFF_, D_);

    // ---- primal ----
    ln_fwd<<<BS_, 256, 0, stream>>>(x, g1, b1, xhat1, hb, rstd1);
    gemm_mfma<64, 128, 0, false, false><<<dim3(3 * D_ / 128, BS_ / 64), 256, 0, stream>>>(
        hb, WqkvT, nullptr, nullptr, nullptr, nullptr, qkvb, nullptr, 3 * D_, D_);
    transpose_v<<<dim3(S_ / 32, HD_ / 32, BH_), 256, 0, stream>>>(qkvb, Vt);
    attn_qk_mfma<false><<<(S_ / 128) * (S_ / 128) * BH_, 256, 0, stream>>>(qkvb, nullptr, dscb2);
    softmax_rows<<<BH_ * S_, 256, 0, stream>>>(dscb2, attnb);
    attn_av_mfma<false><<<(S_ / 128) * BH_, 256, 0, stream>>>(attnb, nullptr, Vt, nullptr, obb);
    gemm_mfma<64, 64, 0, false, false><<<dim3(D_ / 64, BS_ / 64), 256, 0, stream>>>(
        obb, WprojT, bproj, x, nullptr, x2, nullptr, nullptr, D_, D_);
    ln_fwd<<<BS_, 256, 0, stream>>>(x2, g2, b2, xhat2, h2b, rstd2);
    gemm_mfma<128, 128, 1, false, false><<<dim3(DFF_ / 128, BS_ / 128), 256, 0, stream>>>(
        h2b, W1T, bf1, nullptr, nullptr, nullptr, ab, gpb, DFF_, D_);
    gemm_mfma<64, 64, 0, false, false><<<dim3(D_ / 64, BS_ / 64), 256, 0, stream>>>(
        ab, W2T, bf2, x2, nullptr, out, nullptr, nullptr, D_, DFF_);

    // ---- tangents: batched linear stages (M = 8192), pair-batched attention ----
    ln_jvp<<<4 * BS_, 256, 0, stream>>>(xt, nullptr, 0, xhat1, rstd1, g1, dh4);
    gemm_mfma<128, 128, 0, false, false><<<dim3(3 * D_ / 128, 4 * BS_ / 128), 256, 0, stream>>>(
        dh4, WqkvT, nullptr, nullptr, nullptr, nullptr, dqkvb4, nullptr, 3 * D_, D_);
    transpose_v<<<dim3(S_ / 32, HD_ / 32, 4 * BH_), 256, 0, stream>>>(dqkvb4, dVt4);
    for (int p = 0; p < 2; p++) {
        attn_qk_mfma<true><<<2 * (S_ / 128) * (S_ / 128) * BH_, 256, 0, stream>>>(
            qkvb, dqkvb4 + (size_t)p * 2 * BS3D_, dscb2);
        dattn_rows<<<dim3(BH_ * S_, 2), 256, 0, stream>>>(attnb, dscb2);
        attn_av_mfma<true><<<2 * (S_ / 128) * BH_, 256, 0, stream>>>(
            attnb, dscb2, Vt, dVt4 + (size_t)p * 2 * BSD_, dob4 + (size_t)p * 2 * BSD_);
    }
    gemm_mfma<128, 64, 0, true, false><<<dim3(D_ / 64, 4 * BS_ / 128), 256, 0, stream>>>(
        dob4, WprojT, nullptr, xt, nullptr, nullptr, dx2b, nullptr, D_, D_);
    ln_jvp<<<4 * BS_, 256, 0, stream>>>(nullptr, dx2b, 1, xhat2, rstd2, g2, dh2_4);
    gemm_mfma<128, 128, 2, false, false><<<dim3(DFF_ / 128, 4 * BS_ / 128), 256, 0, stream>>>(
        dh2_4, W1T, nullptr, nullptr, nullptr, nullptr, da4, gpb, DFF_, D_);
    gemm_mfma<128, 64, 0, false, true><<<dim3(D_ / 64, 4 * BS_ / 128), 256, 0, stream>>>(
        da4, W2T, nullptr, nullptr, dx2b, out_t, nullptr, nullptr, D_, DFF_);
}

// Round 10
// 506.573 us; speedup vs baseline: 6.7226x; 1.0681x over previous
//
#include <hip/hip_runtime.h>
#include <math.h>

constexpr int B_ = 4, S_ = 512, D_ = 768, H_ = 12, M_ = 4, DFF_ = 3072, HD_ = 64;
constexpr float EPS_ = 1e-6f;
constexpr float SCALE_ = 0.125f;  // HD^-0.5
constexpr int BS_ = B_ * S_;
constexpr int BH_ = B_ * H_;
constexpr long long BSD_ = (long long)BS_ * D_;
constexpr long long BS3D_ = (long long)BS_ * 3 * D_;
constexpr long long ATT_ = (long long)BH_ * S_ * S_;
constexpr long long BSF_ = (long long)BS_ * DFF_;

typedef __attribute__((ext_vector_type(8))) short bf16x8;
typedef __attribute__((ext_vector_type(4))) float f32x4;

__device__ __forceinline__ ushort f2bf(float f) {
    uint32_t u = __float_as_uint(f);
    u += 0x7FFF + ((u >> 16) & 1);
    return (ushort)(u >> 16);
}
__device__ __forceinline__ float bf2f(ushort u) {
    return __uint_as_float((uint32_t)u << 16);
}

__device__ __forceinline__ void gll16(const ushort* g, ushort* l) {
    __builtin_amdgcn_global_load_lds((const __attribute__((address_space(1))) void*)g,
                                     (__attribute__((address_space(3))) void*)l, 16, 0, 0);
}

// counted vmcnt wait (literal required in asm)
template <int N> __device__ __forceinline__ void waitcnt_vm() {
    if constexpr (N == 0) asm volatile("s_waitcnt vmcnt(0)" ::: "memory");
    else if constexpr (N == 4) asm volatile("s_waitcnt vmcnt(4)" ::: "memory");
    else if constexpr (N == 6) asm volatile("s_waitcnt vmcnt(6)" ::: "memory");
    else if constexpr (N == 8) asm volatile("s_waitcnt vmcnt(8)" ::: "memory");
    else static_assert(N == 0 || N == 4 || N == 6 || N == 8, "add literal");
}

// XCD-chunked bijective block remap (m204)
__device__ __forceinline__ int xcd_swz(int flat, int nwg) {
    int q = nwg >> 3, r = nwg & 7;
    int x = flat & 7, pos = flat >> 3;
    int base = (x < r) ? x * (q + 1) : r * (q + 1) + (x - r) * q;
    return base + pos;
}

// batched-row (rg in [0,8192)) -> [B,M,S,Nc] offset
__device__ __forceinline__ size_t stroff(int rg, int c, int Nc) {
    int m = rg >> 11;
    int b = (rg >> 9) & (B_ - 1);
    int s = rg & (S_ - 1);
    return ((size_t)((b * M_ + m) * S_ + s)) * Nc + c;
}

// ---------------- block reductions (256 threads = 4 waves) ----------------
__device__ __forceinline__ float block_sum(float v) {
    __shared__ float red[4];
    int tid = threadIdx.x;
#pragma unroll
    for (int off = 32; off > 0; off >>= 1) v += __shfl_down(v, off, 64);
    __syncthreads();
    if ((tid & 63) == 0) red[tid >> 6] = v;
    __syncthreads();
    return red[0] + red[1] + red[2] + red[3];
}

__device__ __forceinline__ float block_max(float v) {
    __shared__ float red[4];
    int tid = threadIdx.x;
#pragma unroll
    for (int off = 32; off > 0; off >>= 1) v = fmaxf(v, __shfl_down(v, off, 64));
    __syncthreads();
    if ((tid & 63) == 0) red[tid >> 6] = v;
    __syncthreads();
    return fmaxf(fmaxf(red[0], red[1]), fmaxf(red[2], red[3]));
}

// ---------------- weight transpose+convert: W[K][N] f32 -> WT[N][K] bf16 ----------------
__global__ __launch_bounds__(256) void transpose_f2b(const float* __restrict__ W,
                                                     ushort* __restrict__ WT,
                                                     int K, int N) {
    __shared__ float t[32][33];
    int n0 = blockIdx.x * 32, k0 = blockIdx.y * 32;
    int tx = threadIdx.x & 31, ty = threadIdx.x >> 5;
#pragma unroll
    for (int i = 0; i < 4; i++)
        t[ty + i * 8][tx] = W[(size_t)(k0 + ty + i * 8) * N + n0 + tx];
    __syncthreads();
#pragma unroll
    for (int i = 0; i < 4; i++)
        WT[(size_t)(n0 + ty + i * 8) * K + k0 + tx] = f2bf(t[tx][ty + i * 8]);
}

// ---------------- V transpose: src[m][B,S,3D] bf16 -> dst[m][bh][HD][S] bf16 ----------------
__global__ __launch_bounds__(256) void transpose_v(const ushort* __restrict__ src0,
                                                   ushort* __restrict__ dst0) {
    int z = blockIdx.z;
    int m = z / BH_, bh = z % BH_;
    const ushort* qkvb = src0 + (size_t)m * BS3D_;
    ushort* Vt = dst0 + (size_t)m * BSD_;
    int b = bh / H_, hh = bh - b * H_;
    int s0 = blockIdx.x * 32, d0 = blockIdx.y * 32;
    __shared__ ushort t[32][33];
    int tx = threadIdx.x & 31, ty = threadIdx.x >> 5;
#pragma unroll
    for (int i = 0; i < 4; i++)
        t[ty + i * 8][tx] = qkvb[(size_t)(b * S_ + s0 + ty + i * 8) * 3 * D_ + 2 * D_ + hh * HD_ + d0 + tx];
    __syncthreads();
#pragma unroll
    for (int i = 0; i < 4; i++)
        Vt[(size_t)bh * HD_ * S_ + (size_t)(d0 + ty + i * 8) * S_ + s0 + tx] = t[tx][ty + i * 8];
}

// ---------------- LayerNorm forward: xhat bf16, h bf16 ----------------
__global__ __launch_bounds__(256) void ln_fwd(const float* __restrict__ x,
                                              const float* __restrict__ g,
                                              const float* __restrict__ bta,
                                              ushort* __restrict__ xhat,
                                              ushort* __restrict__ h,
                                              float* __restrict__ rstd) {
    int row = blockIdx.x;
    const float* xr = x + (size_t)row * D_;
    int tid = threadIdx.x;
    float v[3];
    float s = 0.f;
#pragma unroll
    for (int i = 0; i < 3; i++) { v[i] = xr[tid + i * 256]; s += v[i]; }
    s = block_sum(s);
    float mu = s * (1.0f / D_);
    float vs = 0.f;
#pragma unroll
    for (int i = 0; i < 3; i++) { float c = v[i] - mu; vs += c * c; }
    vs = block_sum(vs);
    float rs = rsqrtf(vs * (1.0f / D_) + EPS_);
#pragma unroll
    for (int i = 0; i < 3; i++) {
        int c = tid + i * 256;
        float xh = (v[i] - mu) * rs;
        xhat[(size_t)row * D_ + c] = f2bf(xh);
        h[(size_t)row * D_ + c] = f2bf(xh * g[c] + bta[c]);
    }
    if (tid == 0) rstd[row] = rs;
}

// ---------------- batched LayerNorm JVP: grid 4*BS_ rows ----------------
__global__ __launch_bounds__(256) void ln_jvp(const float* __restrict__ tf,
                                              const ushort* __restrict__ tb, int mode,
                                              const ushort* __restrict__ xhat,
                                              const float* __restrict__ rstd,
                                              const float* __restrict__ g,
                                              ushort* __restrict__ dh) {
    int rg = blockIdx.x;
    int r = rg & (BS_ - 1);
    size_t pbase = (size_t)r * D_;
    int tid = threadIdx.x;
    float tv[3], xh[3];
    float s1 = 0.f, s2 = 0.f;
    size_t tbase;
    if (mode == 0) {
        int m = rg >> 11;
        int b = r >> 9, s = r & (S_ - 1);
        tbase = ((size_t)((b * M_ + m) * S_ + s)) * D_;
    } else {
        tbase = (size_t)rg * D_;
    }
#pragma unroll
    for (int i = 0; i < 3; i++) {
        int c = tid + i * 256;
        tv[i] = (mode == 0) ? tf[tbase + c] : bf2f(tb[tbase + c]);
        xh[i] = bf2f(xhat[pbase + c]);
        s1 += tv[i];
        s2 += tv[i] * xh[i];
    }
    s1 = block_sum(s1);
    s2 = block_sum(s2);
    float mt = s1 * (1.0f / D_);
    float mx = s2 * (1.0f / D_);
    float rs = rstd[r];
#pragma unroll
    for (int i = 0; i < 3; i++) {
        int c = tid + i * 256;
        dh[(size_t)rg * D_ + c] = f2bf(g[c] * rs * (tv[i] - mt - xh[i] * mx));
    }
}

// ---------------- bf16 MFMA GEMM <BM,BN>, BK=64, 2-deep dbuf pipeline (T3/T4) ----------------
template <int BM, int BN, int EPI, bool RS, bool OS>
__global__ __launch_bounds__(256) void gemm_mfma(const ushort* __restrict__ A,
                                                 const ushort* __restrict__ BT,
                                                 const float* __restrict__ bias,
                                                 const float* __restrict__ resf,
                                                 const ushort* __restrict__ resb,
                                                 float* __restrict__ Cf,
                                                 ushort* __restrict__ Cb,
                                                 ushort* __restrict__ aux,
                                                 int Nc, int Kd) {
    constexpr int FI = BM / 32, FJ = BN / 32;
    constexpr int LA = BM / 32, LB = BN / 32, L = LA + LB;
    __shared__ ushort As[2][BM * 64];
    __shared__ ushort Bs[2][BN * 64];
    int tid = threadIdx.x;
    int wave = tid >> 6, lane = tid & 63;
    int wr = wave >> 1, wc = wave & 1;
    int gx = gridDim.x, nwg = gx * gridDim.y;
    int work = xcd_swz(blockIdx.x + blockIdx.y * gx, nwg);
    int row0 = (work / gx) * BM, col0 = (work % gx) * BN;

    int srow = lane >> 3;
    int skel = ((lane & 7) ^ (lane >> 3)) * 8;
    const ushort* Ag0 = A + (size_t)(row0 + srow) * Kd + skel;
    const ushort* Bg0 = BT + (size_t)(col0 + srow) * Kd + skel;

    auto stage = [&](int bufi, int k0) {
#pragma unroll
        for (int cc = 0; cc < LA; cc++) {
            int c = wave * LA + cc;
            gll16(Ag0 + (size_t)(c * 8) * Kd + k0, As[bufi] + c * 512);
        }
#pragma unroll
        for (int cc = 0; cc < LB; cc++) {
            int c = wave * LB + cc;
            gll16(Bg0 + (size_t)(c * 8) * Kd + k0, Bs[bufi] + c * 512);
        }
    };

    int frow = lane & 15, fkb = (lane >> 4) * 8;
    int aoff[2][FI], boff[2][FJ];
#pragma unroll
    for (int ks = 0; ks < 2; ks++) {
        int sw = (fkb + ks * 32) ^ ((frow & 7) * 8);
#pragma unroll
        for (int i = 0; i < FI; i++) aoff[ks][i] = (wr * (BM / 2) + i * 16 + frow) * 64 + sw;
#pragma unroll
        for (int j = 0; j < FJ; j++) boff[ks][j] = (wc * (BN / 2) + j * 16 + frow) * 64 + sw;
    }

    f32x4 acc[FI][FJ] = {};

    int nt = Kd >> 6;
    stage(0, 0);
    if (nt > 1) { stage(1, 64); waitcnt_vm<L>(); }
    else        { waitcnt_vm<0>(); }
    __builtin_amdgcn_s_barrier();
    __builtin_amdgcn_sched_barrier(0);

    int cur = 0;
    for (int t = 0; t < nt; t++) {
        bf16x8 af[2][FI], bfv[2][FJ];
        const ushort* Ab = As[cur];
        const ushort* Bb = Bs[cur];
#pragma unroll
        for (int ks = 0; ks < 2; ks++) {
#pragma unroll
            for (int i = 0; i < FI; i++) af[ks][i] = *(const bf16x8*)(Ab + aoff[ks][i]);
#pragma unroll
            for (int j = 0; j < FJ; j++) bfv[ks][j] = *(const bf16x8*)(Bb + boff[ks][j]);
        }
#pragma unroll
        for (int ks = 0; ks < 2; ks++)
#pragma unroll
            for (int i = 0; i < FI; i++)
#pragma unroll
                for (int j = 0; j < FJ; j++)
                    acc[i][j] = __builtin_amdgcn_mfma_f32_16x16x32_bf16(af[ks][i], bfv[ks][j], acc[i][j], 0, 0, 0);
        __builtin_amdgcn_sched_barrier(0);
        __builtin_amdgcn_s_barrier();
        if (t + 2 < nt) {
            stage(cur, (t + 2) << 6);
            waitcnt_vm<L>();
        } else if (t + 1 < nt) {
            waitcnt_vm<0>();
        }
        __builtin_amdgcn_s_barrier();
        __builtin_amdgcn_sched_barrier(0);
        cur ^= 1;
    }

    // C/D layout: col = lane&15, row = (lane>>4)*4 + reg
#pragma unroll
    for (int i = 0; i < FI; i++) {
        int rbase = row0 + wr * (BM / 2) + i * 16 + (lane >> 4) * 4;
#pragma unroll
        for (int j = 0; j < FJ; j++) {
            int c = col0 + wc * (BN / 2) + j * 16 + (lane & 15);
#pragma unroll
            for (int r = 0; r < 4; r++) {
                int rg = rbase + r;
                size_t off = (size_t)rg * Nc + c;
                float v = acc[i][j][r];
                if (EPI == 0) {
                    if (bias) v += bias[c];
                    if (resf) v += resf[RS ? stroff(rg, c, Nc) : off];
                    if (resb) v += bf2f(resb[off]);
                    if (Cf) { if (OS) Cf[stroff(rg, c, Nc)] = v; else Cf[off] = v; }
                    if (Cb) Cb[off] = f2bf(v);
                } else if (EPI == 1) {
                    v += bias[c];
                    float cdf = 0.5f * (1.0f + erff(v * 0.70710678118654752f));
                    Cb[off] = f2bf(v * cdf);
                    aux[off] = f2bf(cdf + v * 0.39894228040143267f * expf(-0.5f * v * v));
                } else {
                    Cb[off] = f2bf(v * bf2f(aux[(size_t)(rg & (BS_ - 1)) * Nc + c]));
                }
            }
        }
    }
}

// ---------------- MFMA QK^T: single-shot BK=64 (K=HD), XOR-swizzled ----------------
// 1D grid: work = mz*(BH*16) + bh*16 + qy*4 + kx; TAN pair-batched (mz in {0,1})
template <bool TAN>
__global__ __launch_bounds__(256) void attn_qk_mfma(const ushort* __restrict__ qkvb,
                                                    const ushort* __restrict__ dqkvp,
                                                    ushort* __restrict__ sc) {
    int work = xcd_swz(blockIdx.x, gridDim.x);
    constexpr int NT = S_ / 128;  // 4
    int mz = work / (BH_ * NT * NT);
    int rem = work % (BH_ * NT * NT);
    int bh = rem / (NT * NT);
    int r2 = rem % (NT * NT);
    int q0 = (r2 / NT) * 128, kc0 = (r2 % NT) * 128;
    int b = bh / H_, hh = bh - b * H_;
    const size_t qoff = (size_t)b * S_ * 3 * D_ + hh * HD_;
    const int ld = 3 * D_;
    const ushort* dqkv = TAN ? dqkvp + (size_t)mz * BS3D_ : nullptr;
    __shared__ ushort As[128 * 64];
    __shared__ ushort Bs[128 * 64];
    __shared__ ushort dAs[TAN ? 128 * 64 : 1];
    __shared__ ushort dBs[TAN ? 128 * 64 : 1];
    int tid = threadIdx.x;
    int wave = tid >> 6, lane = tid & 63;
    int wr = wave >> 1, wc = wave & 1;

    int srow = lane >> 3;
    int skel = ((lane & 7) ^ (lane >> 3)) * 8;
    const ushort* Ag0 = qkvb + qoff + (size_t)(q0 + srow) * ld + skel;
    const ushort* Bg0 = qkvb + qoff + D_ + (size_t)(kc0 + srow) * ld + skel;

#pragma unroll
    for (int cc = 0; cc < 4; cc++) {
        int c = wave * 4 + cc;
        gll16(Ag0 + (size_t)(c * 8) * ld, As + c * 512);
        gll16(Bg0 + (size_t)(c * 8) * ld, Bs + c * 512);
        if (TAN) {
            gll16(dqkv + qoff + (size_t)(q0 + c * 8 + srow) * ld + skel, dAs + c * 512);
            gll16(dqkv + qoff + D_ + (size_t)(kc0 + c * 8 + srow) * ld + skel, dBs + c * 512);
        }
    }
    __syncthreads();

    int frow = lane & 15, fkb = (lane >> 4) * 8;
    f32x4 acc[4][4] = {};
#pragma unroll
    for (int ks = 0; ks < 2; ks++) {
        int sw = (fkb + ks * 32) ^ ((frow & 7) * 8);
        bf16x8 af[4], bfv[4];
#pragma unroll
        for (int i = 0; i < 4; i++) af[i] = *(const bf16x8*)(As + (wr * 64 + i * 16 + frow) * 64 + sw);
#pragma unroll
        for (int j = 0; j < 4; j++) bfv[j] = *(const bf16x8*)(Bs + (wc * 64 + j * 16 + frow) * 64 + sw);
        if (!TAN) {
#pragma unroll
            for (int i = 0; i < 4; i++)
#pragma unroll
                for (int j = 0; j < 4; j++)
                    acc[i][j] = __builtin_amdgcn_mfma_f32_16x16x32_bf16(af[i], bfv[j], acc[i][j], 0, 0, 0);
        } else {
            bf16x8 daf[4], dbf[4];
#pragma unroll
            for (int i = 0; i < 4; i++) daf[i] = *(const bf16x8*)(dAs + (wr * 64 + i * 16 + frow) * 64 + sw);
#pragma unroll
            for (int j = 0; j < 4; j++) dbf[j] = *(const bf16x8*)(dBs + (wc * 64 + j * 16 + frow) * 64 + sw);
#pragma unroll
            for (int i = 0; i < 4; i++)
#pragma unroll
                for (int j = 0; j < 4; j++) {
                    acc[i][j] = __builtin_amdgcn_mfma_f32_16x16x32_bf16(daf[i], bfv[j], acc[i][j], 0, 0, 0);
                    acc[i][j] = __builtin_amdgcn_mfma_f32_16x16x32_bf16(af[i], dbf[j], acc[i][j], 0, 0, 0);
                }
        }
    }

    ushort* scm = sc + (size_t)mz * ATT_;
#pragma unroll
    for (int i = 0; i < 4; i++) {
        int rbase = q0 + wr * 64 + i * 16 + (lane >> 4) * 4;
#pragma unroll
        for (int j = 0; j < 4; j++) {
            int c = kc0 + wc * 64 + j * 16 + (lane & 15);
#pragma unroll
            for (int r = 0; r < 4; r++)
                scm[((size_t)bh * S_ + rbase + r) * S_ + c] = f2bf(acc[i][j][r] * SCALE_);
        }
    }
}

// ---------------- primal P@V: BK=64, XOR-swizzled ----------------
__global__ __launch_bounds__(256) void attn_av_p(const ushort* __restrict__ Pb,
                                                 const ushort* __restrict__ Vt,
                                                 ushort* __restrict__ outp) {
    int work = xcd_swz(blockIdx.x, gridDim.x);
    constexpr int NT = S_ / 128;  // 4
    int bh = work / NT;
    int q0 = (work % NT) * 128;
    int b = bh / H_, hh = bh - b * H_;
    const ushort* Pg = Pb + (size_t)bh * S_ * S_;
    const ushort* Vg = Vt + (size_t)bh * HD_ * S_;
    __shared__ ushort As[128 * 64];
    __shared__ ushort Bs[64 * 64];
    int tid = threadIdx.x;
    int wave = tid >> 6, lane = tid & 63;
    int wr = wave >> 1, wc = wave & 1;
    int srow = lane >> 3;
    int skel = ((lane & 7) ^ (lane >> 3)) * 8;
    int frow = lane & 15, fkb = (lane >> 4) * 8;

    f32x4 acc[4][2] = {};
    for (int k0 = 0; k0 < S_; k0 += 64) {
#pragma unroll
        for (int cc = 0; cc < 4; cc++) {
            int c = wave * 4 + cc;
            gll16(Pg + (size_t)(q0 + c * 8 + srow) * S_ + k0 + skel, As + c * 512);
        }
#pragma unroll
        for (int cc = 0; cc < 2; cc++) {
            int c = wave * 2 + cc;
            gll16(Vg + (size_t)(c * 8 + srow) * S_ + k0 + skel, Bs + c * 512);
        }
        __syncthreads();
#pragma unroll
        for (int ks = 0; ks < 2; ks++) {
            int sw = (fkb + ks * 32) ^ ((frow & 7) * 8);
            bf16x8 af[4], bfv[2];
#pragma unroll
            for (int i = 0; i < 4; i++) af[i] = *(const bf16x8*)(As + (wr * 64 + i * 16 + frow) * 64 + sw);
#pragma unroll
            for (int j = 0; j < 2; j++) bfv[j] = *(const bf16x8*)(Bs + (wc * 32 + j * 16 + frow) * 64 + sw);
#pragma unroll
            for (int i = 0; i < 4; i++)
#pragma unroll
                for (int j = 0; j < 2; j++)
                    acc[i][j] = __builtin_amdgcn_mfma_f32_16x16x32_bf16(af[i], bfv[j], acc[i][j], 0, 0, 0);
        }
        __syncthreads();
    }

#pragma unroll
    for (int i = 0; i < 4; i++) {
        int rbase = q0 + wr * 64 + i * 16 + (lane >> 4) * 4;
#pragma unroll
        for (int j = 0; j < 2; j++) {
            int c = hh * HD_ + wc * 32 + j * 16 + (lane & 15);
#pragma unroll
            for (int r = 0; r < 4; r++)
                outp[(size_t)(b * S_ + rbase + r) * D_ + c] = f2bf(acc[i][j][r]);
        }
    }
}

// ---------------- FUSED tangent P@V: dattn + (dP@V + P@dV), BM=64, BK=64 ----------------
// pass 1: s[row] = rowsum(attn * dsc)  (in-register dot + 4-lane shfl reduce)
// pass 2: dP = attn*(dsc - s) in registers -> MFMA
// 1D grid: work = mz*(BH*8) + bh*8 + qi
__global__ __launch_bounds__(256) void attn_av_tan(const ushort* __restrict__ Pb,
                                                   const ushort* __restrict__ dscp,
                                                   const ushort* __restrict__ Vt,
                                                   const ushort* __restrict__ dVtp,
                                                   ushort* __restrict__ outp) {
    int work = xcd_swz(blockIdx.x, gridDim.x);
    int mz = work / (BH_ * 8);
    int rem = work % (BH_ * 8);
    int bh = rem / 8;
    int q0 = (rem % 8) * 64;
    int b = bh / H_, hh = bh - b * H_;
    const ushort* Pg = Pb + (size_t)bh * S_ * S_;
    const ushort* Dg = dscp + (size_t)mz * ATT_ + (size_t)bh * S_ * S_;
    const ushort* Vg = Vt + (size_t)bh * HD_ * S_;
    const ushort* dVg = dVtp + (size_t)mz * BSD_ + (size_t)bh * HD_ * S_;
    ushort* outm = outp + (size_t)mz * BSD_;
    __shared__ ushort Ps[64 * 64], Ds[64 * 64], Vs[64 * 64], dVs[64 * 64];  // 32 KB
    int tid = threadIdx.x;
    int wave = tid >> 6, lane = tid & 63;
    int wr = wave >> 1, wc = wave & 1;
    int srow = lane >> 3;
    int skel = ((lane & 7) ^ (lane >> 3)) * 8;
    int frow = lane & 15, fkb = (lane >> 4) * 8;
    int aoff[2][2], boff[2][2];
#pragma unroll
    for (int ks = 0; ks < 2; ks++) {
        int sw = (fkb + ks * 32) ^ ((frow & 7) * 8);
#pragma unroll
        for (int i = 0; i < 2; i++) aoff[ks][i] = (wr * 32 + i * 16 + frow) * 64 + sw;
#pragma unroll
        for (int j = 0; j < 2; j++) boff[ks][j] = (wc * 32 + j * 16 + frow) * 64 + sw;
    }

    // ---- pass 1: row sums s[i] for rows wr*32 + i*16 + frow ----
    float s[2] = {0.f, 0.f};
    for (int k0 = 0; k0 < S_; k0 += 64) {
#pragma unroll
        for (int cc = 0; cc < 2; cc++) {
            int c = wave * 2 + cc;
            gll16(Pg + (size_t)(q0 + c * 8 + srow) * S_ + k0 + skel, Ps + c * 512);
            gll16(Dg + (size_t)(q0 + c * 8 + srow) * S_ + k0 + skel, Ds + c * 512);
        }
        __syncthreads();
#pragma unroll
        for (int ks = 0; ks < 2; ks++)
#pragma unroll
            for (int i = 0; i < 2; i++) {
                bf16x8 p8 = *(const bf16x8*)(Ps + aoff[ks][i]);
                bf16x8 d8 = *(const bf16x8*)(Ds + aoff[ks][i]);
#pragma unroll
                for (int e = 0; e < 8; e++)
                    s[i] += bf2f((ushort)p8[e]) * bf2f((ushort)d8[e]);
            }
        __syncthreads();
    }
#pragma unroll
    for (int i = 0; i < 2; i++) {
        s[i] += __shfl_xor(s[i], 16);
        s[i] += __shfl_xor(s[i], 32);
    }

    // ---- pass 2: acc = dP@V + P@dV ----
    f32x4 acc[2][2] = {};
    for (int k0 = 0; k0 < S_; k0 += 64) {
#pragma unroll
        for (int cc = 0; cc < 2; cc++) {
            int c = wave * 2 + cc;
            gll16(Pg + (size_t)(q0 + c * 8 + srow) * S_ + k0 + skel, Ps + c * 512);
            gll16(Dg + (size_t)(q0 + c * 8 + srow) * S_ + k0 + skel, Ds + c * 512);
            gll16(Vg + (size_t)(c * 8 + srow) * S_ + k0 + skel, Vs + c * 512);
            gll16(dVg + (size_t)(c * 8 + srow) * S_ + k0 + skel, dVs + c * 512);
        }
        __syncthreads();
#pragma unroll
        for (int ks = 0; ks < 2; ks++) {
            bf16x8 p8[2], dp8[2], v8[2], dv8[2];
#pragma unroll
            for (int i = 0; i < 2; i++) {
                p8[i] = *(const bf16x8*)(Ps + aoff[ks][i]);
                bf16x8 d8 = *(const bf16x8*)(Ds + aoff[ks][i]);
#pragma unroll
                for (int e = 0; e < 8; e++)
                    dp8[i][e] = (short)f2bf(bf2f((ushort)p8[i][e]) * (bf2f((ushort)d8[e]) - s[i]));
            }
#pragma unroll
            for (int j = 0; j < 2; j++) {
                v8[j] = *(const bf16x8*)(Vs + boff[ks][j]);
                dv8[j] = *(const bf16x8*)(dVs + boff[ks][j]);
            }
#pragma unroll
            for (int i = 0; i < 2; i++)
#pragma unroll
                for (int j = 0; j < 2; j++) {
                    acc[i][j] = __builtin_amdgcn_mfma_f32_16x16x32_bf16(dp8[i], v8[j], acc[i][j], 0, 0, 0);
                    acc[i][j] = __builtin_amdgcn_mfma_f32_16x16x32_bf16(p8[i], dv8[j], acc[i][j], 0, 0, 0);
                }
        }
        __syncthreads();
    }

#pragma unroll
    for (int i = 0; i < 2; i++) {
        int rbase = q0 + wr * 32 + i * 16 + (lane >> 4) * 4;
#pragma unroll
        for (int j = 0; j < 2; j++) {
            int c = hh * HD_ + wc * 32 + j * 16 + (lane & 15);
#pragma unroll
            for (int r = 0; r < 4; r++)
                outm[(size_t)(b * S_ + rbase + r) * D_ + c] = f2bf(acc[i][j][r]);
        }
    }
}

// ---------------- softmax: bf16 scores -> bf16 probs ----------------
__global__ __launch_bounds__(256) void softmax_rows(const ushort* __restrict__ sc,
                                                    ushort* __restrict__ scb) {
    size_t row = blockIdx.x;
    const ushort* p = sc + row * S_;
    int tid = threadIdx.x;
    ushort2 vu = *(const ushort2*)&p[tid * 2];
    float v0 = bf2f(vu.x), v1 = bf2f(vu.y);
    float mx = block_max(fmaxf(v0, v1));
    float e0 = expf(v0 - mx), e1 = expf(v1 - mx);
    float s = block_sum(e0 + e1);
    float inv = 1.0f / s;
    ushort2 ob; ob.x = f2bf(e0 * inv); ob.y = f2bf(e1 * inv);
    *(ushort2*)&scb[row * S_ + tid * 2] = ob;
}

// ---------------- host ----------------
extern "C" void kernel_launch(void* const* d_in, const int* in_sizes, int n_in,
                              void* d_out, int out_size, void* d_ws, size_t ws_size,
                              hipStream_t stream) {
    const float* x = (const float*)d_in[0];
    const float* xt = (const float*)d_in[1];
    const float* g1 = (const float*)d_in[2];
    const float* b1 = (const float*)d_in[3];
    const float* Wqkv = (const float*)d_in[4];
    const float* Wproj = (const float*)d_in[5];
    const float* bproj = (const float*)d_in[6];
    const float* g2 = (const float*)d_in[7];
    const float* b2 = (const float*)d_in[8];
    const float* W1 = (const float*)d_in[9];
    const float* bf1 = (const float*)d_in[10];
    const float* W2 = (const float*)d_in[11];
    const float* bf2 = (const float*)d_in[12];
    float* out = (float*)d_out;
    float* out_t = out + BSD_;   // [B,M,S,D]

    char* wp = (char*)d_ws;
    auto alloc = [&](size_t bytes) { void* p = wp; wp += (bytes + 255) & ~(size_t)255; return p; };
    ushort* xhat1 = (ushort*)alloc(BSD_ * 2);
    ushort* hb = (ushort*)alloc(BSD_ * 2);
    ushort* obb = (ushort*)alloc(BSD_ * 2);
    float* x2 = (float*)alloc(BSD_ * 4);
    ushort* xhat2 = (ushort*)alloc(BSD_ * 2);
    ushort* h2b = (ushort*)alloc(BSD_ * 2);
    ushort* dx2b = (ushort*)alloc(4 * BSD_ * 2);   // [4*BS][D] bf16
    ushort* qkvb = (ushort*)alloc(BS3D_ * 2);
    ushort* Vt = (ushort*)alloc(BSD_ * 2);
    ushort* dscb2 = (ushort*)alloc(2 * ATT_ * 2);  // [2][BH,S,S]: primal scores / tangent-pair dsc
    ushort* attnb = (ushort*)alloc(ATT_ * 2);      // primal probs bf16
    ushort* gpb = (ushort*)alloc(BSF_ * 2);        // gelu'(u) bf16
    float* rstd1 = (float*)alloc(BS_ * 4);
    float* rstd2 = (float*)alloc(BS_ * 4);
    ushort* WqkvT = (ushort*)alloc((size_t)D_ * 3 * D_ * 2);
    ushort* WprojT = (ushort*)alloc((size_t)D_ * D_ * 2);
    ushort* W1T = (ushort*)alloc((size_t)DFF_ * D_ * 2);
    ushort* W2T = (ushort*)alloc((size_t)D_ * DFF_ * 2);
    // Region A (50.3 MB): phase1 {dqkvb4 + dVt4}, phase2 {da4}
    char* regA = (char*)alloc(4 * BSF_ * 2);
    ushort* dqkvb4 = (ushort*)regA;
    ushort* dVt4 = (ushort*)(regA + 4 * BS3D_ * 2);
    ushort* da4 = (ushort*)regA;
    // Region B (12.6 MB): {ab} -> {dh4} -> {dob4} -> {dh2_4}
    char* regB = (char*)alloc(4 * BSD_ * 2);
    ushort* ab = (ushort*)regB;
    ushort* dh4 = (ushort*)regB;
    ushort* dob4 = (ushort*)regB;
    ushort* dh2_4 = (ushort*)regB;

    // ---- weights -> bf16 transposed [N][K] ----
    transpose_f2b<<<dim3(3 * D_ / 32, D_ / 32), 256, 0, stream>>>(Wqkv, WqkvT, D_, 3 * D_);
    transpose_f2b<<<dim3(D_ / 32, D_ / 32), 256, 0, stream>>>(Wproj, WprojT, D_, D_);
    transpose_f2b<<<dim3(DFF_ / 32, D_ / 32), 256, 0, stream>>>(W1, W1T, D_, DFF_);
    transpose_f2b<<<dim3(D_ / 32, DFF_ / 32), 256, 0, stream>>>(W2, W2T, DFF_, D_);

    // ---- primal ----
    ln_fwd<<<BS_, 256, 0, stream>>>(x, g1, b1, xhat1, hb, rstd1);
    gemm_mfma<64, 128, 0, false, false><<<dim3(3 * D_ / 128, BS_ / 64), 256, 0, stream>>>(
        hb, WqkvT, nullptr, nullptr, nullptr, nullptr, qkvb, nullptr, 3 * D_, D_);
    transpose_v<<<dim3(S_ / 32, HD_ / 32, BH_), 256, 0, stream>>>(qkvb, Vt);
    attn_qk_mfma<false><<<(S_ / 128) * (S_ / 128) * BH_, 256, 0, stream>>>(qkvb, nullptr, dscb2);
    softmax_rows<<<BH_ * S_, 256, 0, stream>>>(dscb2, attnb);
    attn_av_p<<<(S_ / 128) * BH_, 256, 0, stream>>>(attnb, Vt, obb);
    gemm_mfma<64, 64, 0, false, false><<<dim3(D_ / 64, BS_ / 64), 256, 0, stream>>>(
        obb, WprojT, bproj, x, nullptr, x2, nullptr, nullptr, D_, D_);
    ln_fwd<<<BS_, 256, 0, stream>>>(x2, g2, b2, xhat2, h2b, rstd2);
    gemm_mfma<128, 128, 1, false, false><<<dim3(DFF_ / 128, BS_ / 128), 256, 0, stream>>>(
        h2b, W1T, bf1, nullptr, nullptr, nullptr, ab, gpb, DFF_, D_);
    gemm_mfma<64, 64, 0, false, false><<<dim3(D_ / 64, BS_ / 64), 256, 0, stream>>>(
        ab, W2T, bf2, x2, nullptr, out, nullptr, nullptr, D_, DFF_);

    // ---- tangents: batched linear stages (M = 8192), pair-batched fused attention ----
    ln_jvp<<<4 * BS_, 256, 0, stream>>>(xt, nullptr, 0, xhat1, rstd1, g1, dh4);
    gemm_mfma<128, 128, 0, false, false><<<dim3(3 * D_ / 128, 4 * BS_ / 128), 256, 0, stream>>>(
        dh4, WqkvT, nullptr, nullptr, nullptr, nullptr, dqkvb4, nullptr, 3 * D_, D_);
    transpose_v<<<dim3(S_ / 32, HD_ / 32, 4 * BH_), 256, 0, stream>>>(dqkvb4, dVt4);
    for (int p = 0; p < 2; p++) {
        attn_qk_mfma<true><<<2 * (S_ / 128) * (S_ / 128) * BH_, 256, 0, stream>>>(
            qkvb, dqkvb4 + (size_t)p * 2 * BS3D_, dscb2);
        attn_av_tan<<<2 * 8 * BH_, 256, 0, stream>>>(
            attnb, dscb2, Vt, dVt4 + (size_t)p * 2 * BSD_, dob4 + (size_t)p * 2 * BSD_);
    }
    gemm_mfma<128, 64, 0, true, false><<<dim3(D_ / 64, 4 * BS_ / 128), 256, 0, stream>>>(
        dob4, WprojT, nullptr, xt, nullptr, nullptr, dx2b, nullptr, D_, D_);
    ln_jvp<<<4 * BS_, 256, 0, stream>>>(nullptr, dx2b, 1, xhat2, rstd2, g2, dh2_4);
    gemm_mfma<128, 128, 2, false, false><<<dim3(DFF_ / 128, 4 * BS_ / 128), 256, 0, stream>>>(
        dh2_4, W1T, nullptr, nullptr, nullptr, nullptr, da4, gpb, DFF_, D_);
    gemm_mfma<128, 64, 0, false, true><<<dim3(D_ / 64, 4 * BS_ / 128), 256, 0, stream>>>(
        da4, W2T, nullptr, nullptr, dx2b, out_t, nullptr, nullptr, D_, DFF_);
}